// Round 15
// 225.730 us; speedup vs baseline: 10.5173x; 1.0452x over previous
//
#include <hip/hip_runtime.h>
#include <math.h>

#define S     1536
#define DM    1024
#define NH    16
#define H2N   32
#define HD    64
#define KVC   256
#define QC    384
#define DFF   4096
#define SPP   384
#define DQK   48
#define CKW   672   /* fused down-proj width: 288 (kv) + 384 (q) */
#define EPS_RMS  1.1920929e-07f
#define ATTN_EPS 1e-5f
#define SCALING  0.14433756729740643f   /* 48^-0.5 */

typedef float f32x4 __attribute__((ext_vector_type(4)));
typedef float f32x16 __attribute__((ext_vector_type(16)));
typedef short bf16x8 __attribute__((ext_vector_type(8)));

__device__ __forceinline__ short cvt_bf16(float f) {
  union { float f; unsigned u; } x; x.f = f;
  unsigned r = x.u + 0x7FFFu + ((x.u >> 16) & 1u);
  return (short)(r >> 16);
}
__device__ __forceinline__ unsigned pk2(float a, float b) { // HW RNE pack
  unsigned r;
  asm("v_cvt_pk_bf16_f32 %0, %1, %2" : "=v"(r) : "v"(a), "v"(b));
  return r;
}
__device__ __forceinline__ bf16x8 cvt8(float4 a, float4 b) {
  union { unsigned u[4]; bf16x8 v; } r;
  r.u[0] = pk2(a.x, a.y); r.u[1] = pk2(a.z, a.w);
  r.u[2] = pk2(b.x, b.y); r.u[3] = pk2(b.z, b.w);
  return r.v;
}
// XCD-aware bijective block swizzle (T1); identity when nwg%8 != 0
__device__ __forceinline__ int swz8(int flat, int nwg) {
  if (nwg & 7) return flat;
  return (flat & 7) * (nwg >> 3) + (flat >> 3);
}

// ---------------- weight fp32 -> bf16 (up to 4 segments, sizes %2048==0) ----
__global__ __launch_bounds__(256) void cvt_w4(const float* __restrict__ s0, int n0,
    const float* __restrict__ s1, int n1, const float* __restrict__ s2, int n2,
    const float* __restrict__ s3, int n3, short* __restrict__ dst) {
  long base = (long)blockIdx.x * 2048 + (long)threadIdx.x * 8;
  const float* src; long off;
  if (base < n0) { src = s0; off = base; }
  else if (base < (long)n0 + n1) { src = s1; off = base - n0; }
  else if (base < (long)n0 + n1 + n2) { src = s2; off = base - n0 - n1; }
  else { src = s3; off = base - n0 - n1 - n2; }
  float4 a = *reinterpret_cast<const float4*>(src + off);
  float4 b = *reinterpret_cast<const float4*>(src + off + 4);
  *reinterpret_cast<bf16x8*>(dst + base) = cvt8(a, b);
}

// ---------------- RMSNorm -> bf16 out ----------------
__global__ __launch_bounds__(256) void rmsnorm_bf(const float* __restrict__ in,
    const float* __restrict__ w, short* __restrict__ out,
    int cols, int ldin, int ldout, float eps) {
  const int row = blockIdx.x;
  const float* xr = in + (size_t)row * ldin;
  short* yr = out + (size_t)row * ldout;
  const int tid = threadIdx.x;
  float ss = 0.f;
  for (int c = tid << 2; c < cols; c += 1024) {
    float4 v = *reinterpret_cast<const float4*>(xr + c);
    ss += v.x*v.x + v.y*v.y + v.z*v.z + v.w*v.w;
  }
#pragma unroll
  for (int mm = 1; mm < 64; mm <<= 1) ss += __shfl_xor(ss, mm, 64);
  __shared__ float red[4];
  if ((tid & 63) == 0) red[tid >> 6] = ss;
  __syncthreads();
  float tot = red[0] + red[1] + red[2] + red[3];
  float scale = rsqrtf(tot / (float)cols + eps);
  for (int c = tid << 2; c < cols; c += 1024) {
    float4 v = *reinterpret_cast<const float4*>(xr + c);
    float4 wv = *reinterpret_cast<const float4*>(w + c);
    uint2 p;
    p.x = pk2(v.x*scale*wv.x, v.y*scale*wv.y);
    p.y = pk2(v.z*scale*wv.z, v.w*scale*wv.w);
    *reinterpret_cast<uint2*>(yr + c) = p;
  }
}

// ---- dual RMSNorm over fused [S][672] buffer: y=0 -> kv(256), y=1 -> q(384) --
__global__ __launch_bounds__(256) void rmsnorm2_bf(const float* __restrict__ comb,
    const float* __restrict__ w0, const float* __restrict__ w1,
    short* __restrict__ o0, short* __restrict__ o1, float eps) {
  const int row = blockIdx.x;
  const int seg = blockIdx.y;
  const float* xr = comb + (size_t)row * CKW + (seg ? 288 : 0);
  const float* w  = seg ? w1 : w0;
  short* yr = seg ? (o1 + (size_t)row * QC) : (o0 + (size_t)row * KVC);
  const int cols = seg ? QC : KVC;
  const int tid = threadIdx.x;
  float ss = 0.f;
  for (int c = tid << 2; c < cols; c += 1024) {
    float4 v = *reinterpret_cast<const float4*>(xr + c);
    ss += v.x*v.x + v.y*v.y + v.z*v.z + v.w*v.w;
  }
#pragma unroll
  for (int mm = 1; mm < 64; mm <<= 1) ss += __shfl_xor(ss, mm, 64);
  __shared__ float red[4];
  if ((tid & 63) == 0) red[tid >> 6] = ss;
  __syncthreads();
  float tot = red[0] + red[1] + red[2] + red[3];
  float scale = rsqrtf(tot / (float)cols + eps);
  for (int c = tid << 2; c < cols; c += 1024) {
    float4 v = *reinterpret_cast<const float4*>(xr + c);
    float4 wv = *reinterpret_cast<const float4*>(w + c);
    uint2 p;
    p.x = pk2(v.x*scale*wv.x, v.y*scale*wv.y);
    p.y = pk2(v.z*scale*wv.z, v.w*scale*wv.w);
    *reinterpret_cast<uint2*>(yr + c) = p;
  }
}

// ------ RMSNorm over (p0+p1+xres), writes residual fp32 AND bf16 norm -------
__global__ __launch_bounds__(256) void rmsnorm_sum_bf(const float* __restrict__ p0,
    const float* __restrict__ p1, const float* __restrict__ xres,
    const float* __restrict__ w, float* __restrict__ outw, short* __restrict__ yb,
    float eps) {
  const int row = blockIdx.x;
  const int c = threadIdx.x << 2;
  const size_t base = (size_t)row * DM + c;
  float4 a = *reinterpret_cast<const float4*>(p0 + base);
  float4 b = *reinterpret_cast<const float4*>(p1 + base);
  float4 xv = *reinterpret_cast<const float4*>(xres + base);
  float4 v = make_float4(a.x+b.x+xv.x, a.y+b.y+xv.y, a.z+b.z+xv.z, a.w+b.w+xv.w);
  *reinterpret_cast<float4*>(outw + base) = v;
  float ss = v.x*v.x + v.y*v.y + v.z*v.z + v.w*v.w;
#pragma unroll
  for (int mm = 1; mm < 64; mm <<= 1) ss += __shfl_xor(ss, mm, 64);
  __shared__ float red[4];
  if ((threadIdx.x & 63) == 0) red[threadIdx.x >> 6] = ss;
  __syncthreads();
  float tot = red[0] + red[1] + red[2] + red[3];
  float scale = rsqrtf(tot * (1.0f / (float)DM) + eps);
  float4 wv = *reinterpret_cast<const float4*>(w + c);
  uint2 p;
  p.x = pk2(v.x*scale*wv.x, v.y*scale*wv.y);
  p.y = pk2(v.z*scale*wv.z, v.w*scale*wv.w);
  *reinterpret_cast<uint2*>(yb + base) = p;
}

// ---------------- out += p0 + p1 (grid: S*DM/1024) ----------------
__global__ __launch_bounds__(256) void fadd2(float* __restrict__ out,
    const float* __restrict__ p0, const float* __restrict__ p1) {
  size_t i = ((size_t)blockIdx.x * 256 + threadIdx.x) << 2;
  float4 o = *reinterpret_cast<float4*>(out + i);
  float4 a = *reinterpret_cast<const float4*>(p0 + i);
  float4 b = *reinterpret_cast<const float4*>(p1 + i);
  o.x += a.x + b.x; o.y += a.y + b.y; o.z += a.z + b.z; o.w += a.w + b.w;
  *reinterpret_cast<float4*>(out + i) = o;
}

// ------------- bf16 MFMA GEMM, BK=64, register-prefetch; A,B bf16 ----------
template<int ADD>
__global__ __launch_bounds__(256) void mgemm_nt(const short* __restrict__ A,
    const short* __restrict__ B, const float* __restrict__ src, float* __restrict__ C,
    int M, int N, int K, int lda, int ldb, int ldc) {
  __shared__ short As[64][72];
  __shared__ short Bs[64][72];
  const int nwg = gridDim.x * gridDim.y;
  const int sfl = swz8(blockIdx.y * gridDim.x + blockIdx.x, nwg);
  const int bxs = sfl % gridDim.x, bys = sfl / gridDim.x;
  const int bm = bys * 64, bn = bxs * 64;
  const int tid = threadIdx.x;
  const int w = tid >> 6, lane = tid & 63;
  const int wr = (w >> 1) << 5, wc = (w & 1) << 5;
  const int srow = tid >> 2, sk = (tid & 3) << 4;
  const int lrow = lane & 15, lk8 = (lane >> 4) << 3;
  const int arow = bm + srow, brow = bn + srow;
  const bool bvalid = brow < N;
  f32x4 acc[2][2];
#pragma unroll
  for (int i = 0; i < 2; ++i)
#pragma unroll
    for (int j = 0; j < 2; ++j) acc[i][j] = (f32x4){0.f, 0.f, 0.f, 0.f};

  bf16x8 rah0, rah1, rbh0, rbh1;
  {
    const short* ap = A + (size_t)arow * lda + sk;
    rah0 = *reinterpret_cast<const bf16x8*>(ap);
    rah1 = *reinterpret_cast<const bf16x8*>(ap + 8);
  }
  rbh0 = (bf16x8){0,0,0,0,0,0,0,0}; rbh1 = rbh0;
  if (bvalid) {
    const short* bp = B + (size_t)brow * ldb + sk;
    rbh0 = *reinterpret_cast<const bf16x8*>(bp);
    rbh1 = *reinterpret_cast<const bf16x8*>(bp + 8);
  }

  for (int k0 = 0; k0 < K; k0 += 64) {
    bf16x8 va0 = rah0, va1 = rah1, vb0 = rbh0, vb1 = rbh1;
    __syncthreads();
    *reinterpret_cast<bf16x8*>(&As[srow][sk])     = va0;
    *reinterpret_cast<bf16x8*>(&As[srow][sk + 8]) = va1;
    *reinterpret_cast<bf16x8*>(&Bs[srow][sk])     = vb0;
    *reinterpret_cast<bf16x8*>(&Bs[srow][sk + 8]) = vb1;
    __syncthreads();
    const int kn = k0 + 64;
    if (kn < K) {
      const short* ap = A + (size_t)arow * lda + kn + sk;
      rah0 = *reinterpret_cast<const bf16x8*>(ap);
      rah1 = *reinterpret_cast<const bf16x8*>(ap + 8);
      if (bvalid) {
        const short* bp = B + (size_t)brow * ldb + kn + sk;
        rbh0 = *reinterpret_cast<const bf16x8*>(bp);
        rbh1 = *reinterpret_cast<const bf16x8*>(bp + 8);
      }
    }
#pragma unroll
    for (int kk = 0; kk < 2; ++kk) {
      bf16x8 af0 = *reinterpret_cast<bf16x8*>(&As[wr + lrow][(kk << 5) + lk8]);
      bf16x8 af1 = *reinterpret_cast<bf16x8*>(&As[wr + 16 + lrow][(kk << 5) + lk8]);
      bf16x8 bf0 = *reinterpret_cast<bf16x8*>(&Bs[wc + lrow][(kk << 5) + lk8]);
      bf16x8 bf1 = *reinterpret_cast<bf16x8*>(&Bs[wc + 16 + lrow][(kk << 5) + lk8]);
      acc[0][0] = __builtin_amdgcn_mfma_f32_16x16x32_bf16(af0, bf0, acc[0][0], 0, 0, 0);
      acc[0][1] = __builtin_amdgcn_mfma_f32_16x16x32_bf16(af0, bf1, acc[0][1], 0, 0, 0);
      acc[1][0] = __builtin_amdgcn_mfma_f32_16x16x32_bf16(af1, bf0, acc[1][0], 0, 0, 0);
      acc[1][1] = __builtin_amdgcn_mfma_f32_16x16x32_bf16(af1, bf1, acc[1][1], 0, 0, 0);
    }
  }
  const int crow0 = bm + wr + ((lane >> 4) << 2);
  const int ccol0 = bn + wc + lrow;
#pragma unroll
  for (int mi = 0; mi < 2; ++mi)
#pragma unroll
    for (int ni = 0; ni < 2; ++ni) {
      int colc = ccol0 + (ni << 4);
      if (colc < N) {
#pragma unroll
        for (int r = 0; r < 4; ++r) {
          int rowc = crow0 + (mi << 4) + r;
          float v = acc[mi][ni][r];
          if (ADD) v += src[(size_t)rowc * ldc + colc];
          C[(size_t)rowc * ldc + colc] = v;
        }
      }
    }
}

// ------- split-K=2 bf16 GEMM: z-half of K -> fp32 partial (P0 or P1) --------
__global__ __launch_bounds__(256) void mgemm_sk(const short* __restrict__ A,
    const short* __restrict__ B, float* __restrict__ P0, float* __restrict__ P1,
    int M, int N, int K2, int lda, int ldb, int ldc) {
  __shared__ short As[64][72];
  __shared__ short Bs[64][72];
  const int nwg = gridDim.x * gridDim.y;
  const int sfl = swz8(blockIdx.y * gridDim.x + blockIdx.x, nwg);
  const int bxs = sfl % gridDim.x, bys = sfl / gridDim.x;
  const int bm = bys * 64, bn = bxs * 64;
  const int koff = blockIdx.z * K2;
  float* C = blockIdx.z ? P1 : P0;
  const int tid = threadIdx.x;
  const int w = tid >> 6, lane = tid & 63;
  const int wr = (w >> 1) << 5, wc = (w & 1) << 5;
  const int srow = tid >> 2, sk = (tid & 3) << 4;
  const int lrow = lane & 15, lk8 = (lane >> 4) << 3;
  const int arow = bm + srow, brow = bn + srow;
  f32x4 acc[2][2];
#pragma unroll
  for (int i = 0; i < 2; ++i)
#pragma unroll
    for (int j = 0; j < 2; ++j) acc[i][j] = (f32x4){0.f, 0.f, 0.f, 0.f};

  bf16x8 rah0, rah1, rbh0, rbh1;
  {
    const short* ap = A + (size_t)arow * lda + koff + sk;
    rah0 = *reinterpret_cast<const bf16x8*>(ap);
    rah1 = *reinterpret_cast<const bf16x8*>(ap + 8);
    const short* bp = B + (size_t)brow * ldb + koff + sk;
    rbh0 = *reinterpret_cast<const bf16x8*>(bp);
    rbh1 = *reinterpret_cast<const bf16x8*>(bp + 8);
  }
  const int kend = koff + K2;
  for (int k0 = koff; k0 < kend; k0 += 64) {
    bf16x8 va0 = rah0, va1 = rah1, vb0 = rbh0, vb1 = rbh1;
    __syncthreads();
    *reinterpret_cast<bf16x8*>(&As[srow][sk])     = va0;
    *reinterpret_cast<bf16x8*>(&As[srow][sk + 8]) = va1;
    *reinterpret_cast<bf16x8*>(&Bs[srow][sk])     = vb0;
    *reinterpret_cast<bf16x8*>(&Bs[srow][sk + 8]) = vb1;
    __syncthreads();
    const int kn = k0 + 64;
    if (kn < kend) {
      const short* ap = A + (size_t)arow * lda + kn + sk;
      rah0 = *reinterpret_cast<const bf16x8*>(ap);
      rah1 = *reinterpret_cast<const bf16x8*>(ap + 8);
      const short* bp = B + (size_t)brow * ldb + kn + sk;
      rbh0 = *reinterpret_cast<const bf16x8*>(bp);
      rbh1 = *reinterpret_cast<const bf16x8*>(bp + 8);
    }
#pragma unroll
    for (int kk = 0; kk < 2; ++kk) {
      bf16x8 af0 = *reinterpret_cast<bf16x8*>(&As[wr + lrow][(kk << 5) + lk8]);
      bf16x8 af1 = *reinterpret_cast<bf16x8*>(&As[wr + 16 + lrow][(kk << 5) + lk8]);
      bf16x8 bf0 = *reinterpret_cast<bf16x8*>(&Bs[wc + lrow][(kk << 5) + lk8]);
      bf16x8 bf1 = *reinterpret_cast<bf16x8*>(&Bs[wc + 16 + lrow][(kk << 5) + lk8]);
      acc[0][0] = __builtin_amdgcn_mfma_f32_16x16x32_bf16(af0, bf0, acc[0][0], 0, 0, 0);
      acc[0][1] = __builtin_amdgcn_mfma_f32_16x16x32_bf16(af0, bf1, acc[0][1], 0, 0, 0);
      acc[1][0] = __builtin_amdgcn_mfma_f32_16x16x32_bf16(af1, bf0, acc[1][0], 0, 0, 0);
      acc[1][1] = __builtin_amdgcn_mfma_f32_16x16x32_bf16(af1, bf1, acc[1][1], 0, 0, 0);
    }
  }
  const int crow0 = bm + wr + ((lane >> 4) << 2);
  const int ccol0 = bn + wc + lrow;
#pragma unroll
  for (int mi = 0; mi < 2; ++mi)
#pragma unroll
    for (int ni = 0; ni < 2; ++ni) {
      int colc = ccol0 + (ni << 4);
#pragma unroll
      for (int r = 0; r < 4; ++r) {
        int rowc = crow0 + (mi << 4) + r;
        C[(size_t)rowc * ldc + colc] = acc[mi][ni][r];
      }
    }
}

// ------- 128(M)x64(N) bf16 SwiGLU GEMM: 4 waves, per-wave 64x32 u AND v -----
__global__ __launch_bounds__(256) void mgemm_glu(const short* __restrict__ A,
    const short* __restrict__ Bw, short* __restrict__ C,
    int M, int N, int K, int lda, int ldb, int ldc) {
  __shared__ short As[128][72];
  __shared__ short Bu[64][72];
  __shared__ short Bv[64][72];
  const int nwg = gridDim.x * gridDim.y;
  const int sfl = swz8(blockIdx.y * gridDim.x + blockIdx.x, nwg);
  const int bxs = sfl % gridDim.x, bys = sfl / gridDim.x;
  const int bm = bys * 128, bn = bxs * 64;
  const int tid = threadIdx.x;
  const int w = tid >> 6, lane = tid & 63;
  const int wr = (w >> 1) << 6, wc = (w & 1) << 5;
  const int arow = bm + (tid >> 1), ac = (tid & 1) << 5;
  const int brow = bn + (tid >> 2), bc = (tid & 3) << 4;
  const int lrow = lane & 15, lk8 = (lane >> 4) << 3;
  f32x4 au[4][2], av[4][2];
#pragma unroll
  for (int i = 0; i < 4; ++i)
#pragma unroll
    for (int j = 0; j < 2; ++j) {
      au[i][j] = (f32x4){0.f, 0.f, 0.f, 0.f};
      av[i][j] = (f32x4){0.f, 0.f, 0.f, 0.f};
    }
  bf16x8 ra[4], ru[2], rv[2];
  {
    const short* ap = A + (size_t)arow * lda + ac;
    const short* up = Bw + (size_t)brow * ldb + bc;
    const short* vp = Bw + (size_t)(N + brow) * ldb + bc;
#pragma unroll
    for (int e = 0; e < 4; ++e) ra[e] = *reinterpret_cast<const bf16x8*>(ap + (e << 3));
    ru[0] = *reinterpret_cast<const bf16x8*>(up);
    ru[1] = *reinterpret_cast<const bf16x8*>(up + 8);
    rv[0] = *reinterpret_cast<const bf16x8*>(vp);
    rv[1] = *reinterpret_cast<const bf16x8*>(vp + 8);
  }
  for (int k0 = 0; k0 < K; k0 += 64) {
    __syncthreads();
#pragma unroll
    for (int e = 0; e < 4; ++e)
      *reinterpret_cast<bf16x8*>(&As[tid >> 1][ac + (e << 3)]) = ra[e];
    *reinterpret_cast<bf16x8*>(&Bu[tid >> 2][bc])     = ru[0];
    *reinterpret_cast<bf16x8*>(&Bu[tid >> 2][bc + 8]) = ru[1];
    *reinterpret_cast<bf16x8*>(&Bv[tid >> 2][bc])     = rv[0];
    *reinterpret_cast<bf16x8*>(&Bv[tid >> 2][bc + 8]) = rv[1];
    __syncthreads();
    const int kn = k0 + 64;
    if (kn < K) {
      const short* ap = A + (size_t)arow * lda + kn + ac;
      const short* up = Bw + (size_t)brow * ldb + kn + bc;
      const short* vp = Bw + (size_t)(N + brow) * ldb + kn + bc;
#pragma unroll
      for (int e = 0; e < 4; ++e) ra[e] = *reinterpret_cast<const bf16x8*>(ap + (e << 3));
      ru[0] = *reinterpret_cast<const bf16x8*>(up);
      ru[1] = *reinterpret_cast<const bf16x8*>(up + 8);
      rv[0] = *reinterpret_cast<const bf16x8*>(vp);
      rv[1] = *reinterpret_cast<const bf16x8*>(vp + 8);
    }
#pragma unroll
    for (int kk = 0; kk < 2; ++kk) {
      bf16x8 af[4], uf[2], vf[2];
#pragma unroll
      for (int i = 0; i < 4; ++i)
        af[i] = *reinterpret_cast<bf16x8*>(&As[wr + (i << 4) + lrow][(kk << 5) + lk8]);
#pragma unroll
      for (int j = 0; j < 2; ++j) {
        uf[j] = *reinterpret_cast<bf16x8*>(&Bu[wc + (j << 4) + lrow][(kk << 5) + lk8]);
        vf[j] = *reinterpret_cast<bf16x8*>(&Bv[wc + (j << 4) + lrow][(kk << 5) + lk8]);
      }
#pragma unroll
      for (int i = 0; i < 4; ++i)
#pragma unroll
        for (int j = 0; j < 2; ++j) {
          au[i][j] = __builtin_amdgcn_mfma_f32_16x16x32_bf16(af[i], uf[j], au[i][j], 0, 0, 0);
          av[i][j] = __builtin_amdgcn_mfma_f32_16x16x32_bf16(af[i], vf[j], av[i][j], 0, 0, 0);
        }
    }
  }
  const int crow0 = bm + wr + ((lane >> 4) << 2);
  const int ccol0 = bn + wc + lrow;
#pragma unroll
  for (int mi = 0; mi < 4; ++mi)
#pragma unroll
    for (int ni = 0; ni < 2; ++ni) {
      int colc = ccol0 + (ni << 4);
#pragma unroll
      for (int r = 0; r < 4; ++r) {
        int rowc = crow0 + (mi << 4) + r;
        float uu = au[mi][ni][r], vg = av[mi][ni][r];
        float sig = 1.0f / (1.0f + __expf(-vg));
        C[(size_t)rowc * ldc + colc] = cvt_bf16(uu * vg * sig);
      }
    }
}

// ---------------- Build Q/K (split heads + RoPE) -> bf16 ----------------
// ckv is the fused [S][672] buffer; rope cols at 256..287.
__global__ __launch_bounds__(256) void build_qk(const float* __restrict__ qf,
    const float* __restrict__ kvb, const float* __restrict__ ckv,
    const float* __restrict__ fc, const float* __restrict__ fs,
    short* __restrict__ Qb, short* __restrict__ Kb) {
  int t = blockIdx.x * 256 + threadIdx.x;
  int h2 = blockIdx.y;
  if (t >= S) return;
  int hh = h2 >> 1, par = h2 & 1;
  const float* qrow = qf + (size_t)t*1536 + hh*96;
  const float* krow = kvb + (size_t)t*2048 + hh*128;
  unsigned qu[24], ku[24];
#pragma unroll
  for (int xq = 0; xq < 8; ++xq) {
    float4 qv = *reinterpret_cast<const float4*>(qrow + par*32 + (xq<<2));
    float4 kv = *reinterpret_cast<const float4*>(krow + par*32 + (xq<<2));
    qu[xq*2]   = pk2(qv.x, qv.y); qu[xq*2+1] = pk2(qv.z, qv.w);
    ku[xq*2]   = pk2(kv.x, kv.y); ku[xq*2+1] = pk2(kv.z, kv.w);
  }
  int p = t >> 2;
  const float* qr = qrow + 64 + par*16;
  const float* kr = ckv + (size_t)t*CKW + 256 + par*16;
#pragma unroll
  for (int mq = 0; mq < 8; ++mq) {
    float c = 1.f, sn = 0.f;
    if (p > 0) { c = fc[(p-1)*8 + mq]; sn = fs[(p-1)*8 + mq]; }
    float q0 = qr[2*mq], q1 = qr[2*mq+1];
    qu[16 + mq] = pk2(q0*c - q1*sn, q0*sn + q1*c);
    float k0 = kr[2*mq], k1 = kr[2*mq+1];
    ku[16 + mq] = pk2(k0*c - k1*sn, k0*sn + k1*c);
  }
  unsigned* qo = (unsigned*)(Qb + ((size_t)h2*S + t)*DQK);
  unsigned* ko = (unsigned*)(Kb + ((size_t)h2*S + t)*DQK);
#pragma unroll
  for (int e = 0; e < 6; ++e) {
    *reinterpret_cast<uint4*>(qo + (e<<2)) = make_uint4(qu[e*4], qu[e*4+1], qu[e*4+2], qu[e*4+3]);
    *reinterpret_cast<uint4*>(ko + (e<<2)) = make_uint4(ku[e*4], ku[e*4+1], ku[e*4+2], ku[e*4+3]);
  }
}

// ---------------- V transpose to bf16: Vt[hh][d][t] ----------------
__global__ __launch_bounds__(256) void vt_build(const float* __restrict__ kvb,
    short* __restrict__ Vt) {
  const int hh = blockIdx.x;
  const int t0 = blockIdx.y << 7;
  __shared__ short Ts[128][74];
  const int tl = threadIdx.x >> 3, dp = (threadIdx.x & 7) << 3;
#pragma unroll
  for (int pass = 0; pass < 4; ++pass) {
    int t = t0 + (pass << 5) + tl;
    const float* vp = kvb + (size_t)t*2048 + hh*128 + 64 + dp;
    float4 a = *reinterpret_cast<const float4*>(vp);
    float4 b = *reinterpret_cast<const float4*>(vp + 4);
    *reinterpret_cast<bf16x8*>(&Ts[(pass << 5) + tl][dp]) = cvt8(a, b);
  }
  __syncthreads();
  for (int idx = threadIdx.x; idx < 1024; idx += 256) {
    int d = idx >> 4, tseg = (idx & 15) << 3;
    bf16x8 v;
#pragma unroll
    for (int e = 0; e < 8; ++e) v[e] = Ts[tseg + e][d];
    *reinterpret_cast<bf16x8*>(Vt + ((size_t)hh*HD + d)*S + t0 + tseg) = v;
  }
}

// ---------------- lambda scalar ----------------
__global__ void compute_lam(const float* __restrict__ lq1, const float* __restrict__ lk1,
                            const float* __restrict__ lq2, const float* __restrict__ lk2,
                            float* __restrict__ lamp) {
  int t = threadIdx.x;
  float a = lq1[t]*lk1[t];
  float b = lq2[t]*lk2[t];
#pragma unroll
  for (int mm = 1; mm < 32; mm <<= 1) { a += __shfl_xor(a, mm, 32); b += __shfl_xor(b, mm, 32); }
  if (t == 0) lamp[0] = expf(a) - expf(b) + 0.2f;
}

// ------- MFMA flash attention: NO-LDS fragments direct from L2 ----------
__global__ __launch_bounds__(256) void flash_mfma(const short* __restrict__ Qb,
    const short* __restrict__ Kb, const short* __restrict__ Vg,
    float* __restrict__ Ob, float* __restrict__ rowm, float* __restrict__ rowl,
    float* __restrict__ Ob1a, float* __restrict__ Ob1b,
    float* __restrict__ rm1, float* __restrict__ rl1) {
  const int h2 = blockIdx.y;
  const int hh = h2 >> 1;
  const int z  = blockIdx.z;
  const int tid = threadIdx.x;
  const int w = tid >> 6, lane = tid & 63;
  const int ql = lane & 31, h = lane >> 5;
  const int cq = blockIdx.x / 3, k = blockIdx.x % 3;
  const int qi = k + 3*w;
  const int qbase = cq*SPP + (qi << 5);
  const int ri0w = qi << 5;

  __shared__ __align__(16) float Ot[4][32][36];

  bf16x8 qf0, qf1, qf2;
  {
    const short* qp = Qb + ((size_t)h2*S + qbase + ql)*DQK + (h << 3);
    qf0 = *reinterpret_cast<const bf16x8*>(qp);
    qf1 = *reinterpret_cast<const bf16x8*>(qp + 16);
    qf2 = *reinterpret_cast<const bf16x8*>(qp + 32);
  }
  const short* Kbase = Kb + (size_t)h2*S*DQK + (h << 3);
  const short* V0 = Vg + ((size_t)hh*HD + ql)*S + (h << 3);
  const short* V1 = Vg + ((size_t)hh*HD + 32 + ql)*S + (h << 3);

  float m = -1e30f, l = 0.f;
  f32x16 o0, o1;
#pragma unroll
  for (int r = 0; r < 16; ++r) { o0[r] = 0.f; o1[r] = 0.f; }

  for (int c = (z << 1); c < (z << 1) + 2; ++c) {
    for (int jr = 0; jr <= ri0w; jr += 32) {
      const int j0 = c*SPP + jr;
      const bool diag = (jr == ri0w);
      const short* kp = Kbase + (size_t)(j0 + ql)*DQK;
      bf16x8 kf0 = *reinterpret_cast<const bf16x8*>(kp);
      bf16x8 kf1 = *reinterpret_cast<const bf16x8*>(kp + 16);
      bf16x8 kf2 = *reinterpret_cast<const bf16x8*>(kp + 32);
      bf16x8 v00 = *reinterpret_cast<const bf16x8*>(V0 + j0);
      bf16x8 v01 = *reinterpret_cast<const bf16x8*>(V0 + j0 + 16);
      bf16x8 v10 = *reinterpret_cast<const bf16x8*>(V1 + j0);
      bf16x8 v11 = *reinterpret_cast<const bf16x8*>(V1 + j0 + 16);

      f32x16 st;
#pragma unroll
      for (int r = 0; r < 16; ++r) st[r] = 0.f;
      st = __builtin_amdgcn_mfma_f32_32x32x16_bf16(kf0, qf0, st, 0, 0, 0);
      st = __builtin_amdgcn_mfma_f32_32x32x16_bf16(kf1, qf1, st, 0, 0, 0);
      st = __builtin_amdgcn_mfma_f32_32x32x16_bf16(kf2, qf2, st, 0, 0, 0);

      if (diag) {
#pragma unroll
        for (int r = 0; r < 16; ++r) {
          int kl = (r & 3) + ((r >> 2) << 3) + (h << 2);
          st[r] = (kl <= ql) ? st[r] * SCALING : -1e30f;
        }
      } else {
#pragma unroll
        for (int r = 0; r < 16; ++r) st[r] *= SCALING;
      }

      float tm = st[0];
#pragma unroll
      for (int r = 1; r < 16; ++r) tm = fmaxf(tm, st[r]);
      tm = fmaxf(tm, __shfl_xor(tm, 32));
      if (__any(tm > m + 8.0f)) {
        float mnew = fmaxf(m, tm);
        float sc = __expf(m - mnew);
        m = mnew;
        l *= sc;
#pragma unroll
        for (int r = 0; r < 16; ++r) { o0[r] *= sc; o1[r] *= sc; }
      }
      float ps = 0.f;
#pragma unroll
      for (int r = 0; r < 16; ++r) { float p = __expf(st[r] - m); st[r] = p; ps += p; }
      ps += __shfl_xor(ps, 32);
      l += ps;

      unsigned A0 = pk2(st[0],  st[1]),  B0 = pk2(st[2],  st[3]);
      unsigned C0 = pk2(st[4],  st[5]),  D0 = pk2(st[6],  st[7]);
      unsigned A1 = pk2(st[8],  st[9]),  B1 = pk2(st[10], st[11]);
      unsigned C1 = pk2(st[12], st[13]), D1 = pk2(st[14], st[15]);
      unsigned xA0 = (unsigned)__shfl_xor((int)A0, 32), xB0 = (unsigned)__shfl_xor((int)B0, 32);
      unsigned xC0 = (unsigned)__shfl_xor((int)C0, 32), xD0 = (unsigned)__shfl_xor((int)D0, 32);
      unsigned xA1 = (unsigned)__shfl_xor((int)A1, 32), xB1 = (unsigned)__shfl_xor((int)B1, 32);
      unsigned xC1 = (unsigned)__shfl_xor((int)C1, 32), xD1 = (unsigned)__shfl_xor((int)D1, 32);
      union { unsigned u[4]; bf16x8 v; } P0, P1;
      P0.u[0] = h ? xC0 : A0;  P0.u[1] = h ? xD0 : B0;
      P0.u[2] = h ? C0 : xA0;  P0.u[3] = h ? D0 : xB0;
      P1.u[0] = h ? xC1 : A1;  P1.u[1] = h ? xD1 : B1;
      P1.u[2] = h ? C1 : xA1;  P1.u[3] = h ? D1 : xB1;

      o0 = __builtin_amdgcn_mfma_f32_32x32x16_bf16(v00, P0.v, o0, 0, 0, 0);
      o0 = __builtin_amdgcn_mfma_f32_32x32x16_bf16(v01, P1.v, o0, 0, 0, 0);
      o1 = __builtin_amdgcn_mfma_f32_32x32x16_bf16(v10, P0.v, o1, 0, 0, 0);
      o1 = __builtin_amdgcn_mfma_f32_32x32x16_bf16(v11, P1.v, o1, 0, 0, 0);
    }
  }

  float* ot = &Ot[w][0][0];
  float* orow;
  if (z == 0) orow = Ob + ((size_t)h2*S + qbase)*HD;
  else orow = (h2 < 16) ? Ob1a + ((size_t)h2*S + qbase)*HD
                        : Ob1b + ((size_t)(h2 - 16)*S + qbase)*HD;
#pragma unroll
  for (int r = 0; r < 16; ++r) {
    int dl = (r & 3) + ((r >> 2) << 3) + (h << 2);
    ot[ql*36 + dl] = o0[r];
  }
#pragma unroll
  for (int it = 0; it < 4; ++it) {
    int idx = lane + (it << 6);
    int row = idx >> 3, c4 = (idx & 7) << 2;
    float4 v = *reinterpret_cast<float4*>(&ot[row*36 + c4]);
    *reinterpret_cast<float4*>(&orow[(size_t)row*HD + c4]) = v;
  }
#pragma unroll
  for (int r = 0; r < 16; ++r) {
    int dl = (r & 3) + ((r >> 2) << 3) + (h << 2);
    ot[ql*36 + dl] = o1[r];
  }
#pragma unroll
  for (int it = 0; it < 4; ++it) {
    int idx = lane + (it << 6);
    int row = idx >> 3, c4 = (idx & 7) << 2;
    float4 v = *reinterpret_cast<float4*>(&ot[row*36 + c4]);
    *reinterpret_cast<float4*>(&orow[(size_t)row*HD + 32 + c4]) = v;
  }
  if (lane < 32) {
    if (z == 0) { rowm[h2*S + qbase + lane] = m; rowl[h2*S + qbase + lane] = l; }
    else        { rm1[h2*S + qbase + lane] = m;  rl1[h2*S + qbase + lane] = l; }
  }
}

// ---------------- merge the two flash partials, normalize ----------------
__global__ __launch_bounds__(256) void merge_flash(float* __restrict__ Ob,
    float* __restrict__ rowm, float* __restrict__ rowl,
    const float* __restrict__ Ob1a, const float* __restrict__ Ob1b,
    const float* __restrict__ rm1, const float* __restrict__ rl1) {
  const int gid = blockIdx.x * 4 + (threadIdx.x >> 6);
  const int d = threadIdx.x & 63;
  const int h2 = gid / S;
  float m0 = rowm[gid], l0 = rowl[gid], m1 = rm1[gid], l1 = rl1[gid];
  float m = fmaxf(m0, m1);
  float w0 = __expf(m0 - m), w1 = __expf(m1 - m);
  float linv = 1.0f / (l0*w0 + l1*w1);
  const float* o1 = (h2 < 16) ? (Ob1a + (size_t)gid*HD)
                              : (Ob1b + ((size_t)gid - (size_t)16*S)*HD);
  float v0 = Ob[(size_t)gid*HD + d];
  float v1 = o1[d];
  Ob[(size_t)gid*HD + d] = (v0*w0 + v1*w1) * linv;
  if (d == 0) { rowm[gid] = m; rowl[gid] = l0*w0 + l1*w1; }
}

// ---------------- colsum via MFMA (bf16 inputs) ----------------
__global__ __launch_bounds__(256) void colsum_mfma(const short* __restrict__ Qb,
    const short* __restrict__ Kb, const float* __restrict__ rowm,
    const float* __restrict__ rowl, float* __restrict__ gcol) {
  const int jt = blockIdx.x;
  const int hh = blockIdx.y, h2 = hh << 1;
  const int cK = jt / 12, jr32 = jt % 12;
  const int jr = jr32 << 5;
  const int j0 = cK*SPP + jr;
  const int tid = threadIdx.x;
  const int w = tid >> 6, lane = tid & 63;
  const int ql = lane & 31, h = lane >> 5;

  bf16x8 kf0, kf1, kf2;
  {
    const short* kp = Kb + ((size_t)h2*S + j0 + ql)*DQK + (h << 3);
    kf0 = *reinterpret_cast<const bf16x8*>(kp);
    kf1 = *reinterpret_cast<const bf16x8*>(kp + 16);
    kf2 = *reinterpret_cast<const bf16x8*>(kp + 32);
  }
  const int nt = 12 - jr32;
  const int T = nt << 2;
  float gs[16];
#pragma unroll
  for (int r = 0; r < 16; ++r) gs[r] = 0.f;

  for (int tt = w; tt < T; tt += 4) {
    int cq = tt / nt, qrem = tt - cq*nt;
    int qi = jr32 + qrem;
    int i0 = cq*SPP + (qi << 5);
    const bool diag = (qrem == 0);
    const short* qp = Qb + ((size_t)h2*S + i0 + ql)*DQK + (h << 3);
    bf16x8 qf0 = *reinterpret_cast<const bf16x8*>(qp);
    bf16x8 qf1 = *reinterpret_cast<const bf16x8*>(qp + 16);
    bf16x8 qf2 = *reinterpret_cast<const bf16x8*>(qp + 32);
    f32x16 st;
#pragma unroll
    for (int r = 0; r < 16; ++r) st[r] = 0.f;
    st = __builtin_amdgcn_mfma_f32_32x32x16_bf16(kf0, qf0, st, 0, 0, 0);
    st = __builtin_amdgcn_mfma_f32_32x32x16_bf16(kf1, qf1, st, 0, 0, 0);
    st = __builtin_amdgcn_mfma_f32_32x32x16_bf16(kf2, qf2, st, 0, 0, 0);
    float Mq = rowm[h2*S + i0 + ql];
    float Lq = 1.0f / rowl[h2*S + i0 + ql];
    if (diag) {
#pragma unroll
      for (int r = 0; r < 16; ++r) {
        int kl = (r & 3) + ((r >> 2) << 3) + (h << 2);
        if (kl <= ql) gs[r] += __expf(st[r]*SCALING - Mq) * Lq;
      }
    } else {
#pragma unroll
      for (int r = 0; r < 16; ++r) gs[r] += __expf(st[r]*SCALING - Mq) * Lq;
    }
  }
  __shared__ float gw[4][32];
#pragma unroll
  for (int r = 0; r < 16; ++r) {
    float v = gs[r];
#pragma unroll
    for (int mm = 1; mm < 32; mm <<= 1) v += __shfl_xor(v, mm, 32);
    if (ql == 0) gw[w][(r & 3) + ((r >> 2) << 3) + (h << 2)] = v;
  }
  __syncthreads();
  if (tid < 32) {
    float s = gw[0][tid] + gw[1][tid] + gw[2][tid] + gw[3][tid];
    gcol[hh*S + j0 + tid] = s * (1.0f / (float)S);
  }
}

// ---------------- Wpre: masked prefix of g-weighted V ----------------
__global__ __launch_bounds__(256) void build_wpre(const float* __restrict__ gcol,
    const float* __restrict__ kvb, float* __restrict__ Wpre) {
  const int hh = blockIdx.x >> 2;
  const int dq = (blockIdx.x & 3) << 4;
  __shared__ float Wt[SPP][16];
  const int tid = threadIdx.x;
  for (int idx = tid; idx < SPP*16; idx += 256) {
    int r = idx >> 4, dd = idx & 15;
    float val = 0.f;
#pragma unroll
    for (int b2 = 0; b2 < 4; ++b2) {
      int j = b2*SPP + r;
      val = fmaf(gcol[hh*S + j], kvb[(size_t)j*2048 + hh*128 + 64 + dq + dd], val);
    }
    Wt[r][dd] = val;
  }
  __syncthreads();
  if (tid < 16) {
    float run = 0.f;
    for (int r = 0; r < SPP; ++r) { run += Wt[r][tid]; Wt[r][tid] = run; }
  }
  __syncthreads();
  for (int idx = tid; idx < SPP*16; idx += 256) {
    int r = idx >> 4, dd = idx & 15;
    Wpre[((size_t)hh*SPP + r)*HD + dq + dd] = Wt[r][dd];
  }
}

// ------- combine (diff-attn) + per-head RMSNorm + scrambled reshape -> bf16 ---
__global__ __launch_bounds__(64) void combine_rms(const float* __restrict__ Ob,
    const float* __restrict__ Wpre, const float* __restrict__ lamp,
    const float* __restrict__ anw, short* __restrict__ attno) {
  const int t = blockIdx.x, h = blockIdx.y, d = threadIdx.x;
  const float lam = lamp[0];
  const float o1 = Ob[((size_t)(2*h)*S + t)*HD + d];
  const float o2 = Ob[((size_t)(2*h+1)*S + t)*HD + d];
  const float w3 = Wpre[((size_t)h*SPP + (t % SPP))*HD + d];
  float val = o1 - lam*o2 + lam*w3;
  float ss = val*val;
#pragma unroll
  for (int mm = 1; mm < 64; mm <<= 1) ss += __shfl_xor(ss, mm, 64);
  float scale = rsqrtf(ss * (1.0f/HD) + ATTN_EPS) * anw[d];
  int tn = h*96 + (t >> 4);
  int cn = ((t & 15) << 6) + d;
  attno[(size_t)tn*DM + cn] = cvt_bf16(val * scale);
}

// =========================== launch ===========================
extern "C" void kernel_launch(void* const* d_in, const int* in_sizes, int n_in,
                              void* d_out, int out_size, void* d_ws, size_t ws_size,
                              hipStream_t stream) {
  (void)in_sizes; (void)n_in; (void)out_size;
  const float* x    = (const float*)d_in[0];
  const float* fc   = (const float*)d_in[1];
  const float* fs   = (const float*)d_in[2];
  const float* n1w  = (const float*)d_in[3];
  const float* n2w  = (const float*)d_in[4];
  const float* kvdw = (const float*)d_in[5];
  const float* qdw  = (const float*)d_in[6];
  const float* kvnw = (const float*)d_in[7];
  const float* qnw  = (const float*)d_in[8];
  const float* kvuw = (const float*)d_in[9];
  const float* quw  = (const float*)d_in[10];
  const float* lq1  = (const float*)d_in[11];
  const float* lk1  = (const float*)d_in[12];
  const float* lq2  = (const float*)d_in[13];
  const float* lk2  = (const float*)d_in[14];
  const float* anw  = (const float*)d_in[15];
  const float* ow   = (const float*)d_in[16];
  const float* ffiw = (const float*)d_in[17];
  const float* ffow = (const float*)d_in[18];
  float* out = (float*)d_out;
  float* ws  = (float*)d_ws;

  float* xin   = ws;
  float* ckv   = xin   + (size_t)S*DM;        // fused [S][672] down-proj output
  float* qmid  = ckv   + (size_t)S*288;       // (part of fused buffer)
  float* kvb   = qmid  + (size_t)S*QC;
  float* qf    = kvb   + (size_t)S*2048;
  float* Qb    = qf    + (size_t)S*1536;
  float* Kb    = Qb    + (size_t)H2N*S*DQK;
  float* Obuf  = Kb    + (size_t)H2N*S*DQK;
  float* rowm  = Obuf  + (size_t)H2N*S*HD;
  float* rowl  = rowm  + (size_t)H2N*S;
  float* gcol  = rowl  + (size_t)H2N*S;
  float* Wpre  = gcol  + (size_t)NH*S;
  float* attno = Wpre  + (size_t)NH*SPP*HD;
  float* lamp  = attno + (size_t)S*DM;
  short* fbufs = (short*)kvb;     // bf16 FFN activation overlays kv region
  float* Ob1a = xin;
  float* Ob1b = qf;
  float* rm1  = qf + (size_t)16*S*HD;
  float* rl1  = rm1 + (size_t)H2N*S;
  short* Qb_bf = (short*)Qb;
  short* Kb_bf = (short*)Kb;
  short* Vt_bf = (short*)Qb + 2359296;
  short* xin_bf  = (short*)xin;
  short* ckv_bf  = (short*)Obuf;
  short* qmid_bf = ckv_bf + (size_t)S*KVC;
  short* h_bf    = (short*)ckv;   // rmsnorm2 out: fused-buffer region (dead by then)
  short* attno_bf = (short*)attno;
  short* kvdw_bf = (short*)attno;
  short* qdw_bf  = kvdw_bf + 294912;        // contiguous with kvdw_bf: fused B (672x1024)
  short* kvuw_bf = qdw_bf  + 393216;
  short* quw_bf  = kvuw_bf + 524288;
  short* ffiw_bf = (short*)Qb;
  short* ow_bf   = ffiw_bf + 8388608;
  short* ffow_bf = (short*)Obuf;
  float* psum0 = xin;             // split-K partials: dead windows at call sites
  float* psum1 = qf;
  if (ws_size < (size_t)18063376 * sizeof(float)) return;

  cvt_w4<<<880, 256, 0, stream>>>(kvdw, 294912, qdw, 393216, kvuw, 524288, quw, 589824, kvdw_bf);
  rmsnorm_bf<<<S, 256, 0, stream>>>(x, n1w, xin_bf, DM, DM, DM, EPS_RMS);
  // fused down-proj: [S][1024] @ [672][1024]^T -> [S][672]
  { dim3 g(11, 24); mgemm_nt<0><<<g, 256, 0, stream>>>(xin_bf, kvdw_bf, nullptr, ckv, S, CKW, DM, DM, DM, CKW); }
  { dim3 g(S, 2);   rmsnorm2_bf<<<g, 256, 0, stream>>>(ckv, kvnw, qnw, ckv_bf, qmid_bf, EPS_RMS); }
  { dim3 g(32, 24); mgemm_nt<0><<<g, 256, 0, stream>>>(ckv_bf,  kvuw_bf, nullptr, kvb, S, 2048, KVC, KVC, KVC, 2048); }
  { dim3 g(24, 24); mgemm_nt<0><<<g, 256, 0, stream>>>(qmid_bf, quw_bf,  nullptr, qf,  S, 1536, QC,  QC,  QC,  1536); }
  { dim3 g(6, 32);  build_qk<<<g, 256, 0, stream>>>(qf, kvb, ckv, fc, fs, Qb_bf, Kb_bf); }
  { dim3 g(16, 12); vt_build<<<g, 256, 0, stream>>>(kvb, Vt_bf); }
  compute_lam<<<1, 32, 0, stream>>>(lq1, lk1, lq2, lk2, lamp);
  { dim3 g(12, 32, 2); flash_mfma<<<g, 256, 0, stream>>>(Qb_bf, Kb_bf, Vt_bf, Obuf, rowm, rowl,
                                                         Ob1a, Ob1b, rm1, rl1); }
  merge_flash<<<(H2N*S)/4, 256, 0, stream>>>(Obuf, rowm, rowl, Ob1a, Ob1b, rm1, rl1);
  { dim3 g(48, 16); colsum_mfma<<<g, 256, 0, stream>>>(Qb_bf, Kb_bf, rowm, rowl, gcol); }
  cvt_w4<<<4608, 256, 0, stream>>>(ffiw, 8388608, ow, 1048576, nullptr, 0, nullptr, 0, ffiw_bf);
  build_wpre<<<64, 256, 0, stream>>>(gcol, kvb, Wpre);
  { dim3 g(S, 16);  combine_rms<<<g, 64, 0, stream>>>(Obuf, Wpre, lamp, anw, attno_bf); }
  cvt_w4<<<2048, 256, 0, stream>>>(ffow, 4194304, nullptr, 0, nullptr, 0, nullptr, 0, ffow_bf);
  { dim3 g(16, 24, 2); mgemm_sk<<<g, 256, 0, stream>>>(attno_bf, ow_bf, psum0, psum1, S, DM, 512, DM, DM, DM); }
  rmsnorm_sum_bf<<<S, 256, 0, stream>>>(psum0, psum1, x, n2w, out, h_bf, EPS_RMS);
  { dim3 g(64, 12); mgemm_glu<<<g, 256, 0, stream>>>(h_bf, ffiw_bf, fbufs, S, DFF, DM, DM, DM, DFF); }
  { dim3 g(16, 24, 2); mgemm_sk<<<g, 256, 0, stream>>>(fbufs, ffow_bf, psum0, psum1, S, DM, 2048, DFF, DFF, DM); }
  fadd2<<<1536, 256, 0, stream>>>(out, psum0, psum1);
}

// Round 16
// 217.898 us; speedup vs baseline: 10.8953x; 1.0359x over previous
//
#include <hip/hip_runtime.h>
#include <math.h>

#define S     1536
#define DM    1024
#define NH    16
#define H2N   32
#define HD    64
#define KVC   256
#define QC    384
#define DFF   4096
#define SPP   384
#define DQK   48
#define CKW   672   /* fused down-proj width: 288 (kv) + 384 (q) */
#define EPS_RMS  1.1920929e-07f
#define ATTN_EPS 1e-5f
#define SCALING  0.14433756729740643f   /* 48^-0.5 */

typedef float f32x4 __attribute__((ext_vector_type(4)));
typedef float f32x16 __attribute__((ext_vector_type(16)));
typedef short bf16x8 __attribute__((ext_vector_type(8)));

__device__ __forceinline__ short cvt_bf16(float f) {
  union { float f; unsigned u; } x; x.f = f;
  unsigned r = x.u + 0x7FFFu + ((x.u >> 16) & 1u);
  return (short)(r >> 16);
}
__device__ __forceinline__ unsigned pk2(float a, float b) { // HW RNE pack
  unsigned r;
  asm("v_cvt_pk_bf16_f32 %0, %1, %2" : "=v"(r) : "v"(a), "v"(b));
  return r;
}
__device__ __forceinline__ bf16x8 cvt8(float4 a, float4 b) {
  union { unsigned u[4]; bf16x8 v; } r;
  r.u[0] = pk2(a.x, a.y); r.u[1] = pk2(a.z, a.w);
  r.u[2] = pk2(b.x, b.y); r.u[3] = pk2(b.z, b.w);
  return r.v;
}
// XCD-aware bijective block swizzle (T1); identity when nwg%8 != 0
__device__ __forceinline__ int swz8(int flat, int nwg) {
  if (nwg & 7) return flat;
  return (flat & 7) * (nwg >> 3) + (flat >> 3);
}

// ---------------- weight fp32 -> bf16 (up to 4 segments, sizes %2048==0) ----
__global__ __launch_bounds__(256) void cvt_w4(const float* __restrict__ s0, int n0,
    const float* __restrict__ s1, int n1, const float* __restrict__ s2, int n2,
    const float* __restrict__ s3, int n3, short* __restrict__ dst) {
  long base = (long)blockIdx.x * 2048 + (long)threadIdx.x * 8;
  const float* src; long off;
  if (base < n0) { src = s0; off = base; }
  else if (base < (long)n0 + n1) { src = s1; off = base - n0; }
  else if (base < (long)n0 + n1 + n2) { src = s2; off = base - n0 - n1; }
  else { src = s3; off = base - n0 - n1 - n2; }
  float4 a = *reinterpret_cast<const float4*>(src + off);
  float4 b = *reinterpret_cast<const float4*>(src + off + 4);
  *reinterpret_cast<bf16x8*>(dst + base) = cvt8(a, b);
}

// ---------------- RMSNorm -> bf16 out ----------------
__global__ __launch_bounds__(256) void rmsnorm_bf(const float* __restrict__ in,
    const float* __restrict__ w, short* __restrict__ out,
    int cols, int ldin, int ldout, float eps) {
  const int row = blockIdx.x;
  const float* xr = in + (size_t)row * ldin;
  short* yr = out + (size_t)row * ldout;
  const int tid = threadIdx.x;
  float ss = 0.f;
  for (int c = tid << 2; c < cols; c += 1024) {
    float4 v = *reinterpret_cast<const float4*>(xr + c);
    ss += v.x*v.x + v.y*v.y + v.z*v.z + v.w*v.w;
  }
#pragma unroll
  for (int mm = 1; mm < 64; mm <<= 1) ss += __shfl_xor(ss, mm, 64);
  __shared__ float red[4];
  if ((tid & 63) == 0) red[tid >> 6] = ss;
  __syncthreads();
  float tot = red[0] + red[1] + red[2] + red[3];
  float scale = rsqrtf(tot / (float)cols + eps);
  for (int c = tid << 2; c < cols; c += 1024) {
    float4 v = *reinterpret_cast<const float4*>(xr + c);
    float4 wv = *reinterpret_cast<const float4*>(w + c);
    uint2 p;
    p.x = pk2(v.x*scale*wv.x, v.y*scale*wv.y);
    p.y = pk2(v.z*scale*wv.z, v.w*scale*wv.w);
    *reinterpret_cast<uint2*>(yr + c) = p;
  }
}

// ---- dual RMSNorm over fused [S][672] buffer: y=0 -> kv(256), y=1 -> q(384) --
__global__ __launch_bounds__(256) void rmsnorm2_bf(const float* __restrict__ comb,
    const float* __restrict__ w0, const float* __restrict__ w1,
    short* __restrict__ o0, short* __restrict__ o1, float eps) {
  const int row = blockIdx.x;
  const int seg = blockIdx.y;
  const float* xr = comb + (size_t)row * CKW + (seg ? 288 : 0);
  const float* w  = seg ? w1 : w0;
  short* yr = seg ? (o1 + (size_t)row * QC) : (o0 + (size_t)row * KVC);
  const int cols = seg ? QC : KVC;
  const int tid = threadIdx.x;
  float ss = 0.f;
  for (int c = tid << 2; c < cols; c += 1024) {
    float4 v = *reinterpret_cast<const float4*>(xr + c);
    ss += v.x*v.x + v.y*v.y + v.z*v.z + v.w*v.w;
  }
#pragma unroll
  for (int mm = 1; mm < 64; mm <<= 1) ss += __shfl_xor(ss, mm, 64);
  __shared__ float red[4];
  if ((tid & 63) == 0) red[tid >> 6] = ss;
  __syncthreads();
  float tot = red[0] + red[1] + red[2] + red[3];
  float scale = rsqrtf(tot / (float)cols + eps);
  for (int c = tid << 2; c < cols; c += 1024) {
    float4 v = *reinterpret_cast<const float4*>(xr + c);
    float4 wv = *reinterpret_cast<const float4*>(w + c);
    uint2 p;
    p.x = pk2(v.x*scale*wv.x, v.y*scale*wv.y);
    p.y = pk2(v.z*scale*wv.z, v.w*scale*wv.w);
    *reinterpret_cast<uint2*>(yr + c) = p;
  }
}

// ------ RMSNorm over (p0+p1+xres), writes residual fp32 AND bf16 norm -------
__global__ __launch_bounds__(256) void rmsnorm_sum_bf(const float* __restrict__ p0,
    const float* __restrict__ p1, const float* __restrict__ xres,
    const float* __restrict__ w, float* __restrict__ outw, short* __restrict__ yb,
    float eps) {
  const int row = blockIdx.x;
  const int c = threadIdx.x << 2;
  const size_t base = (size_t)row * DM + c;
  float4 a = *reinterpret_cast<const float4*>(p0 + base);
  float4 b = *reinterpret_cast<const float4*>(p1 + base);
  float4 xv = *reinterpret_cast<const float4*>(xres + base);
  float4 v = make_float4(a.x+b.x+xv.x, a.y+b.y+xv.y, a.z+b.z+xv.z, a.w+b.w+xv.w);
  *reinterpret_cast<float4*>(outw + base) = v;
  float ss = v.x*v.x + v.y*v.y + v.z*v.z + v.w*v.w;
#pragma unroll
  for (int mm = 1; mm < 64; mm <<= 1) ss += __shfl_xor(ss, mm, 64);
  __shared__ float red[4];
  if ((threadIdx.x & 63) == 0) red[threadIdx.x >> 6] = ss;
  __syncthreads();
  float tot = red[0] + red[1] + red[2] + red[3];
  float scale = rsqrtf(tot * (1.0f / (float)DM) + eps);
  float4 wv = *reinterpret_cast<const float4*>(w + c);
  uint2 p;
  p.x = pk2(v.x*scale*wv.x, v.y*scale*wv.y);
  p.y = pk2(v.z*scale*wv.z, v.w*scale*wv.w);
  *reinterpret_cast<uint2*>(yb + base) = p;
}

// ---------------- out += p0 + p1 (grid: S*DM/1024) ----------------
__global__ __launch_bounds__(256) void fadd2(float* __restrict__ out,
    const float* __restrict__ p0, const float* __restrict__ p1) {
  size_t i = ((size_t)blockIdx.x * 256 + threadIdx.x) << 2;
  float4 o = *reinterpret_cast<float4*>(out + i);
  float4 a = *reinterpret_cast<const float4*>(p0 + i);
  float4 b = *reinterpret_cast<const float4*>(p1 + i);
  o.x += a.x + b.x; o.y += a.y + b.y; o.z += a.z + b.z; o.w += a.w + b.w;
  *reinterpret_cast<float4*>(out + i) = o;
}

// ------------- bf16 MFMA GEMM, BK=64, register-prefetch; A,B bf16 ----------
template<int ADD>
__global__ __launch_bounds__(256) void mgemm_nt(const short* __restrict__ A,
    const short* __restrict__ B, const float* __restrict__ src, float* __restrict__ C,
    int M, int N, int K, int lda, int ldb, int ldc) {
  __shared__ short As[64][72];
  __shared__ short Bs[64][72];
  const int nwg = gridDim.x * gridDim.y;
  const int sfl = swz8(blockIdx.y * gridDim.x + blockIdx.x, nwg);
  const int bxs = sfl % gridDim.x, bys = sfl / gridDim.x;
  const int bm = bys * 64, bn = bxs * 64;
  const int tid = threadIdx.x;
  const int w = tid >> 6, lane = tid & 63;
  const int wr = (w >> 1) << 5, wc = (w & 1) << 5;
  const int srow = tid >> 2, sk = (tid & 3) << 4;
  const int lrow = lane & 15, lk8 = (lane >> 4) << 3;
  const int arow = bm + srow, brow = bn + srow;
  const bool bvalid = brow < N;
  f32x4 acc[2][2];
#pragma unroll
  for (int i = 0; i < 2; ++i)
#pragma unroll
    for (int j = 0; j < 2; ++j) acc[i][j] = (f32x4){0.f, 0.f, 0.f, 0.f};

  bf16x8 rah0, rah1, rbh0, rbh1;
  {
    const short* ap = A + (size_t)arow * lda + sk;
    rah0 = *reinterpret_cast<const bf16x8*>(ap);
    rah1 = *reinterpret_cast<const bf16x8*>(ap + 8);
  }
  rbh0 = (bf16x8){0,0,0,0,0,0,0,0}; rbh1 = rbh0;
  if (bvalid) {
    const short* bp = B + (size_t)brow * ldb + sk;
    rbh0 = *reinterpret_cast<const bf16x8*>(bp);
    rbh1 = *reinterpret_cast<const bf16x8*>(bp + 8);
  }

  for (int k0 = 0; k0 < K; k0 += 64) {
    bf16x8 va0 = rah0, va1 = rah1, vb0 = rbh0, vb1 = rbh1;
    __syncthreads();
    *reinterpret_cast<bf16x8*>(&As[srow][sk])     = va0;
    *reinterpret_cast<bf16x8*>(&As[srow][sk + 8]) = va1;
    *reinterpret_cast<bf16x8*>(&Bs[srow][sk])     = vb0;
    *reinterpret_cast<bf16x8*>(&Bs[srow][sk + 8]) = vb1;
    __syncthreads();
    const int kn = k0 + 64;
    if (kn < K) {
      const short* ap = A + (size_t)arow * lda + kn + sk;
      rah0 = *reinterpret_cast<const bf16x8*>(ap);
      rah1 = *reinterpret_cast<const bf16x8*>(ap + 8);
      if (bvalid) {
        const short* bp = B + (size_t)brow * ldb + kn + sk;
        rbh0 = *reinterpret_cast<const bf16x8*>(bp);
        rbh1 = *reinterpret_cast<const bf16x8*>(bp + 8);
      }
    }
#pragma unroll
    for (int kk = 0; kk < 2; ++kk) {
      bf16x8 af0 = *reinterpret_cast<bf16x8*>(&As[wr + lrow][(kk << 5) + lk8]);
      bf16x8 af1 = *reinterpret_cast<bf16x8*>(&As[wr + 16 + lrow][(kk << 5) + lk8]);
      bf16x8 bf0 = *reinterpret_cast<bf16x8*>(&Bs[wc + lrow][(kk << 5) + lk8]);
      bf16x8 bf1 = *reinterpret_cast<bf16x8*>(&Bs[wc + 16 + lrow][(kk << 5) + lk8]);
      acc[0][0] = __builtin_amdgcn_mfma_f32_16x16x32_bf16(af0, bf0, acc[0][0], 0, 0, 0);
      acc[0][1] = __builtin_amdgcn_mfma_f32_16x16x32_bf16(af0, bf1, acc[0][1], 0, 0, 0);
      acc[1][0] = __builtin_amdgcn_mfma_f32_16x16x32_bf16(af1, bf0, acc[1][0], 0, 0, 0);
      acc[1][1] = __builtin_amdgcn_mfma_f32_16x16x32_bf16(af1, bf1, acc[1][1], 0, 0, 0);
    }
  }
  const int crow0 = bm + wr + ((lane >> 4) << 2);
  const int ccol0 = bn + wc + lrow;
#pragma unroll
  for (int mi = 0; mi < 2; ++mi)
#pragma unroll
    for (int ni = 0; ni < 2; ++ni) {
      int colc = ccol0 + (ni << 4);
      if (colc < N) {
#pragma unroll
        for (int r = 0; r < 4; ++r) {
          int rowc = crow0 + (mi << 4) + r;
          float v = acc[mi][ni][r];
          if (ADD) v += src[(size_t)rowc * ldc + colc];
          C[(size_t)rowc * ldc + colc] = v;
        }
      }
    }
}

// ------- split-K=2 bf16 GEMM: z-half of K -> fp32 partial (P0 or P1) --------
__global__ __launch_bounds__(256) void mgemm_sk(const short* __restrict__ A,
    const short* __restrict__ B, float* __restrict__ P0, float* __restrict__ P1,
    int M, int N, int K2, int lda, int ldb, int ldc) {
  __shared__ short As[64][72];
  __shared__ short Bs[64][72];
  const int nwg = gridDim.x * gridDim.y;
  const int sfl = swz8(blockIdx.y * gridDim.x + blockIdx.x, nwg);
  const int bxs = sfl % gridDim.x, bys = sfl / gridDim.x;
  const int bm = bys * 64, bn = bxs * 64;
  const int koff = blockIdx.z * K2;
  float* C = blockIdx.z ? P1 : P0;
  const int tid = threadIdx.x;
  const int w = tid >> 6, lane = tid & 63;
  const int wr = (w >> 1) << 5, wc = (w & 1) << 5;
  const int srow = tid >> 2, sk = (tid & 3) << 4;
  const int lrow = lane & 15, lk8 = (lane >> 4) << 3;
  const int arow = bm + srow, brow = bn + srow;
  f32x4 acc[2][2];
#pragma unroll
  for (int i = 0; i < 2; ++i)
#pragma unroll
    for (int j = 0; j < 2; ++j) acc[i][j] = (f32x4){0.f, 0.f, 0.f, 0.f};

  bf16x8 rah0, rah1, rbh0, rbh1;
  {
    const short* ap = A + (size_t)arow * lda + koff + sk;
    rah0 = *reinterpret_cast<const bf16x8*>(ap);
    rah1 = *reinterpret_cast<const bf16x8*>(ap + 8);
    const short* bp = B + (size_t)brow * ldb + koff + sk;
    rbh0 = *reinterpret_cast<const bf16x8*>(bp);
    rbh1 = *reinterpret_cast<const bf16x8*>(bp + 8);
  }
  const int kend = koff + K2;
  for (int k0 = koff; k0 < kend; k0 += 64) {
    bf16x8 va0 = rah0, va1 = rah1, vb0 = rbh0, vb1 = rbh1;
    __syncthreads();
    *reinterpret_cast<bf16x8*>(&As[srow][sk])     = va0;
    *reinterpret_cast<bf16x8*>(&As[srow][sk + 8]) = va1;
    *reinterpret_cast<bf16x8*>(&Bs[srow][sk])     = vb0;
    *reinterpret_cast<bf16x8*>(&Bs[srow][sk + 8]) = vb1;
    __syncthreads();
    const int kn = k0 + 64;
    if (kn < kend) {
      const short* ap = A + (size_t)arow * lda + kn + sk;
      rah0 = *reinterpret_cast<const bf16x8*>(ap);
      rah1 = *reinterpret_cast<const bf16x8*>(ap + 8);
      const short* bp = B + (size_t)brow * ldb + kn + sk;
      rbh0 = *reinterpret_cast<const bf16x8*>(bp);
      rbh1 = *reinterpret_cast<const bf16x8*>(bp + 8);
    }
#pragma unroll
    for (int kk = 0; kk < 2; ++kk) {
      bf16x8 af0 = *reinterpret_cast<bf16x8*>(&As[wr + lrow][(kk << 5) + lk8]);
      bf16x8 af1 = *reinterpret_cast<bf16x8*>(&As[wr + 16 + lrow][(kk << 5) + lk8]);
      bf16x8 bf0 = *reinterpret_cast<bf16x8*>(&Bs[wc + lrow][(kk << 5) + lk8]);
      bf16x8 bf1 = *reinterpret_cast<bf16x8*>(&Bs[wc + 16 + lrow][(kk << 5) + lk8]);
      acc[0][0] = __builtin_amdgcn_mfma_f32_16x16x32_bf16(af0, bf0, acc[0][0], 0, 0, 0);
      acc[0][1] = __builtin_amdgcn_mfma_f32_16x16x32_bf16(af0, bf1, acc[0][1], 0, 0, 0);
      acc[1][0] = __builtin_amdgcn_mfma_f32_16x16x32_bf16(af1, bf0, acc[1][0], 0, 0, 0);
      acc[1][1] = __builtin_amdgcn_mfma_f32_16x16x32_bf16(af1, bf1, acc[1][1], 0, 0, 0);
    }
  }
  const int crow0 = bm + wr + ((lane >> 4) << 2);
  const int ccol0 = bn + wc + lrow;
#pragma unroll
  for (int mi = 0; mi < 2; ++mi)
#pragma unroll
    for (int ni = 0; ni < 2; ++ni) {
      int colc = ccol0 + (ni << 4);
#pragma unroll
      for (int r = 0; r < 4; ++r) {
        int rowc = crow0 + (mi << 4) + r;
        C[(size_t)rowc * ldc + colc] = acc[mi][ni][r];
      }
    }
}

// ------- 128(M)x64(N) bf16 SwiGLU GEMM: 4 waves, per-wave 64x32 u AND v -----
__global__ __launch_bounds__(256) void mgemm_glu(const short* __restrict__ A,
    const short* __restrict__ Bw, short* __restrict__ C,
    int M, int N, int K, int lda, int ldb, int ldc) {
  __shared__ short As[128][72];
  __shared__ short Bu[64][72];
  __shared__ short Bv[64][72];
  const int nwg = gridDim.x * gridDim.y;
  const int sfl = swz8(blockIdx.y * gridDim.x + blockIdx.x, nwg);
  const int bxs = sfl % gridDim.x, bys = sfl / gridDim.x;
  const int bm = bys * 128, bn = bxs * 64;
  const int tid = threadIdx.x;
  const int w = tid >> 6, lane = tid & 63;
  const int wr = (w >> 1) << 6, wc = (w & 1) << 5;
  const int arow = bm + (tid >> 1), ac = (tid & 1) << 5;
  const int brow = bn + (tid >> 2), bc = (tid & 3) << 4;
  const int lrow = lane & 15, lk8 = (lane >> 4) << 3;
  f32x4 au[4][2], av[4][2];
#pragma unroll
  for (int i = 0; i < 4; ++i)
#pragma unroll
    for (int j = 0; j < 2; ++j) {
      au[i][j] = (f32x4){0.f, 0.f, 0.f, 0.f};
      av[i][j] = (f32x4){0.f, 0.f, 0.f, 0.f};
    }
  bf16x8 ra[4], ru[2], rv[2];
  {
    const short* ap = A + (size_t)arow * lda + ac;
    const short* up = Bw + (size_t)brow * ldb + bc;
    const short* vp = Bw + (size_t)(N + brow) * ldb + bc;
#pragma unroll
    for (int e = 0; e < 4; ++e) ra[e] = *reinterpret_cast<const bf16x8*>(ap + (e << 3));
    ru[0] = *reinterpret_cast<const bf16x8*>(up);
    ru[1] = *reinterpret_cast<const bf16x8*>(up + 8);
    rv[0] = *reinterpret_cast<const bf16x8*>(vp);
    rv[1] = *reinterpret_cast<const bf16x8*>(vp + 8);
  }
  for (int k0 = 0; k0 < K; k0 += 64) {
    __syncthreads();
#pragma unroll
    for (int e = 0; e < 4; ++e)
      *reinterpret_cast<bf16x8*>(&As[tid >> 1][ac + (e << 3)]) = ra[e];
    *reinterpret_cast<bf16x8*>(&Bu[tid >> 2][bc])     = ru[0];
    *reinterpret_cast<bf16x8*>(&Bu[tid >> 2][bc + 8]) = ru[1];
    *reinterpret_cast<bf16x8*>(&Bv[tid >> 2][bc])     = rv[0];
    *reinterpret_cast<bf16x8*>(&Bv[tid >> 2][bc + 8]) = rv[1];
    __syncthreads();
    const int kn = k0 + 64;
    if (kn < K) {
      const short* ap = A + (size_t)arow * lda + kn + ac;
      const short* up = Bw + (size_t)brow * ldb + kn + bc;
      const short* vp = Bw + (size_t)(N + brow) * ldb + kn + bc;
#pragma unroll
      for (int e = 0; e < 4; ++e) ra[e] = *reinterpret_cast<const bf16x8*>(ap + (e << 3));
      ru[0] = *reinterpret_cast<const bf16x8*>(up);
      ru[1] = *reinterpret_cast<const bf16x8*>(up + 8);
      rv[0] = *reinterpret_cast<const bf16x8*>(vp);
      rv[1] = *reinterpret_cast<const bf16x8*>(vp + 8);
    }
#pragma unroll
    for (int kk = 0; kk < 2; ++kk) {
      bf16x8 af[4], uf[2], vf[2];
#pragma unroll
      for (int i = 0; i < 4; ++i)
        af[i] = *reinterpret_cast<bf16x8*>(&As[wr + (i << 4) + lrow][(kk << 5) + lk8]);
#pragma unroll
      for (int j = 0; j < 2; ++j) {
        uf[j] = *reinterpret_cast<bf16x8*>(&Bu[wc + (j << 4) + lrow][(kk << 5) + lk8]);
        vf[j] = *reinterpret_cast<bf16x8*>(&Bv[wc + (j << 4) + lrow][(kk << 5) + lk8]);
      }
#pragma unroll
      for (int i = 0; i < 4; ++i)
#pragma unroll
        for (int j = 0; j < 2; ++j) {
          au[i][j] = __builtin_amdgcn_mfma_f32_16x16x32_bf16(af[i], uf[j], au[i][j], 0, 0, 0);
          av[i][j] = __builtin_amdgcn_mfma_f32_16x16x32_bf16(af[i], vf[j], av[i][j], 0, 0, 0);
        }
    }
  }
  const int crow0 = bm + wr + ((lane >> 4) << 2);
  const int ccol0 = bn + wc + lrow;
#pragma unroll
  for (int mi = 0; mi < 4; ++mi)
#pragma unroll
    for (int ni = 0; ni < 2; ++ni) {
      int colc = ccol0 + (ni << 4);
#pragma unroll
      for (int r = 0; r < 4; ++r) {
        int rowc = crow0 + (mi << 4) + r;
        float uu = au[mi][ni][r], vg = av[mi][ni][r];
        float sig = 1.0f / (1.0f + __expf(-vg));
        C[(size_t)rowc * ldc + colc] = cvt_bf16(uu * vg * sig);
      }
    }
}

// ---------------- Build Q/K (split heads + RoPE) -> bf16 ----------------
__global__ __launch_bounds__(256) void build_qk(const float* __restrict__ qf,
    const float* __restrict__ kvb, const float* __restrict__ ckv,
    const float* __restrict__ fc, const float* __restrict__ fs,
    short* __restrict__ Qb, short* __restrict__ Kb) {
  int t = blockIdx.x * 256 + threadIdx.x;
  int h2 = blockIdx.y;
  if (t >= S) return;
  int hh = h2 >> 1, par = h2 & 1;
  const float* qrow = qf + (size_t)t*1536 + hh*96;
  const float* krow = kvb + (size_t)t*2048 + hh*128;
  unsigned qu[24], ku[24];
#pragma unroll
  for (int xq = 0; xq < 8; ++xq) {
    float4 qv = *reinterpret_cast<const float4*>(qrow + par*32 + (xq<<2));
    float4 kv = *reinterpret_cast<const float4*>(krow + par*32 + (xq<<2));
    qu[xq*2]   = pk2(qv.x, qv.y); qu[xq*2+1] = pk2(qv.z, qv.w);
    ku[xq*2]   = pk2(kv.x, kv.y); ku[xq*2+1] = pk2(kv.z, kv.w);
  }
  int p = t >> 2;
  const float* qr = qrow + 64 + par*16;
  const float* kr = ckv + (size_t)t*CKW + 256 + par*16;
#pragma unroll
  for (int mq = 0; mq < 8; ++mq) {
    float c = 1.f, sn = 0.f;
    if (p > 0) { c = fc[(p-1)*8 + mq]; sn = fs[(p-1)*8 + mq]; }
    float q0 = qr[2*mq], q1 = qr[2*mq+1];
    qu[16 + mq] = pk2(q0*c - q1*sn, q0*sn + q1*c);
    float k0 = kr[2*mq], k1 = kr[2*mq+1];
    ku[16 + mq] = pk2(k0*c - k1*sn, k0*sn + k1*c);
  }
  unsigned* qo = (unsigned*)(Qb + ((size_t)h2*S + t)*DQK);
  unsigned* ko = (unsigned*)(Kb + ((size_t)h2*S + t)*DQK);
#pragma unroll
  for (int e = 0; e < 6; ++e) {
    *reinterpret_cast<uint4*>(qo + (e<<2)) = make_uint4(qu[e*4], qu[e*4+1], qu[e*4+2], qu[e*4+3]);
    *reinterpret_cast<uint4*>(ko + (e<<2)) = make_uint4(ku[e*4], ku[e*4+1], ku[e*4+2], ku[e*4+3]);
  }
}

// ---------------- V transpose to bf16: Vt[hh][d][t] ----------------
__global__ __launch_bounds__(256) void vt_build(const float* __restrict__ kvb,
    short* __restrict__ Vt) {
  const int hh = blockIdx.x;
  const int t0 = blockIdx.y << 7;
  __shared__ short Ts[128][74];
  const int tl = threadIdx.x >> 3, dp = (threadIdx.x & 7) << 3;
#pragma unroll
  for (int pass = 0; pass < 4; ++pass) {
    int t = t0 + (pass << 5) + tl;
    const float* vp = kvb + (size_t)t*2048 + hh*128 + 64 + dp;
    float4 a = *reinterpret_cast<const float4*>(vp);
    float4 b = *reinterpret_cast<const float4*>(vp + 4);
    *reinterpret_cast<bf16x8*>(&Ts[(pass << 5) + tl][dp]) = cvt8(a, b);
  }
  __syncthreads();
  for (int idx = threadIdx.x; idx < 1024; idx += 256) {
    int d = idx >> 4, tseg = (idx & 15) << 3;
    bf16x8 v;
#pragma unroll
    for (int e = 0; e < 8; ++e) v[e] = Ts[tseg + e][d];
    *reinterpret_cast<bf16x8*>(Vt + ((size_t)hh*HD + d)*S + t0 + tseg) = v;
  }
}

// ---------------- lambda scalar ----------------
__global__ void compute_lam(const float* __restrict__ lq1, const float* __restrict__ lk1,
                            const float* __restrict__ lq2, const float* __restrict__ lk2,
                            float* __restrict__ lamp) {
  int t = threadIdx.x;
  float a = lq1[t]*lk1[t];
  float b = lq2[t]*lk2[t];
#pragma unroll
  for (int mm = 1; mm < 32; mm <<= 1) { a += __shfl_xor(a, mm, 32); b += __shfl_xor(b, mm, 32); }
  if (t == 0) lamp[0] = expf(a) - expf(b) + 0.2f;
}

// ------- MFMA flash attention: NO-LDS fragments direct from L2 ----------
__global__ __launch_bounds__(256) void flash_mfma(const short* __restrict__ Qb,
    const short* __restrict__ Kb, const short* __restrict__ Vg,
    float* __restrict__ Ob, float* __restrict__ rowm, float* __restrict__ rowl,
    float* __restrict__ Ob1a, float* __restrict__ Ob1b,
    float* __restrict__ rm1, float* __restrict__ rl1) {
  const int h2 = blockIdx.y;
  const int hh = h2 >> 1;
  const int z  = blockIdx.z;
  const int tid = threadIdx.x;
  const int w = tid >> 6, lane = tid & 63;
  const int ql = lane & 31, h = lane >> 5;
  const int cq = blockIdx.x / 3, k = blockIdx.x % 3;
  const int qi = k + 3*w;
  const int qbase = cq*SPP + (qi << 5);
  const int ri0w = qi << 5;

  __shared__ __align__(16) float Ot[4][32][36];

  bf16x8 qf0, qf1, qf2;
  {
    const short* qp = Qb + ((size_t)h2*S + qbase + ql)*DQK + (h << 3);
    qf0 = *reinterpret_cast<const bf16x8*>(qp);
    qf1 = *reinterpret_cast<const bf16x8*>(qp + 16);
    qf2 = *reinterpret_cast<const bf16x8*>(qp + 32);
  }
  const short* Kbase = Kb + (size_t)h2*S*DQK + (h << 3);
  const short* V0 = Vg + ((size_t)hh*HD + ql)*S + (h << 3);
  const short* V1 = Vg + ((size_t)hh*HD + 32 + ql)*S + (h << 3);

  float m = -1e30f, l = 0.f;
  f32x16 o0, o1;
#pragma unroll
  for (int r = 0; r < 16; ++r) { o0[r] = 0.f; o1[r] = 0.f; }

  for (int c = (z << 1); c < (z << 1) + 2; ++c) {
    for (int jr = 0; jr <= ri0w; jr += 32) {
      const int j0 = c*SPP + jr;
      const bool diag = (jr == ri0w);
      const short* kp = Kbase + (size_t)(j0 + ql)*DQK;
      bf16x8 kf0 = *reinterpret_cast<const bf16x8*>(kp);
      bf16x8 kf1 = *reinterpret_cast<const bf16x8*>(kp + 16);
      bf16x8 kf2 = *reinterpret_cast<const bf16x8*>(kp + 32);
      bf16x8 v00 = *reinterpret_cast<const bf16x8*>(V0 + j0);
      bf16x8 v01 = *reinterpret_cast<const bf16x8*>(V0 + j0 + 16);
      bf16x8 v10 = *reinterpret_cast<const bf16x8*>(V1 + j0);
      bf16x8 v11 = *reinterpret_cast<const bf16x8*>(V1 + j0 + 16);

      f32x16 st;
#pragma unroll
      for (int r = 0; r < 16; ++r) st[r] = 0.f;
      st = __builtin_amdgcn_mfma_f32_32x32x16_bf16(kf0, qf0, st, 0, 0, 0);
      st = __builtin_amdgcn_mfma_f32_32x32x16_bf16(kf1, qf1, st, 0, 0, 0);
      st = __builtin_amdgcn_mfma_f32_32x32x16_bf16(kf2, qf2, st, 0, 0, 0);

      if (diag) {
#pragma unroll
        for (int r = 0; r < 16; ++r) {
          int kl = (r & 3) + ((r >> 2) << 3) + (h << 2);
          st[r] = (kl <= ql) ? st[r] * SCALING : -1e30f;
        }
      } else {
#pragma unroll
        for (int r = 0; r < 16; ++r) st[r] *= SCALING;
      }

      float tm = st[0];
#pragma unroll
      for (int r = 1; r < 16; ++r) tm = fmaxf(tm, st[r]);
      tm = fmaxf(tm, __shfl_xor(tm, 32));
      if (__any(tm > m + 8.0f)) {
        float mnew = fmaxf(m, tm);
        float sc = __expf(m - mnew);
        m = mnew;
        l *= sc;
#pragma unroll
        for (int r = 0; r < 16; ++r) { o0[r] *= sc; o1[r] *= sc; }
      }
      float ps = 0.f;
#pragma unroll
      for (int r = 0; r < 16; ++r) { float p = __expf(st[r] - m); st[r] = p; ps += p; }
      ps += __shfl_xor(ps, 32);
      l += ps;

      unsigned A0 = pk2(st[0],  st[1]),  B0 = pk2(st[2],  st[3]);
      unsigned C0 = pk2(st[4],  st[5]),  D0 = pk2(st[6],  st[7]);
      unsigned A1 = pk2(st[8],  st[9]),  B1 = pk2(st[10], st[11]);
      unsigned C1 = pk2(st[12], st[13]), D1 = pk2(st[14], st[15]);
      unsigned xA0 = (unsigned)__shfl_xor((int)A0, 32), xB0 = (unsigned)__shfl_xor((int)B0, 32);
      unsigned xC0 = (unsigned)__shfl_xor((int)C0, 32), xD0 = (unsigned)__shfl_xor((int)D0, 32);
      unsigned xA1 = (unsigned)__shfl_xor((int)A1, 32), xB1 = (unsigned)__shfl_xor((int)B1, 32);
      unsigned xC1 = (unsigned)__shfl_xor((int)C1, 32), xD1 = (unsigned)__shfl_xor((int)D1, 32);
      union { unsigned u[4]; bf16x8 v; } P0, P1;
      P0.u[0] = h ? xC0 : A0;  P0.u[1] = h ? xD0 : B0;
      P0.u[2] = h ? C0 : xA0;  P0.u[3] = h ? D0 : xB0;
      P1.u[0] = h ? xC1 : A1;  P1.u[1] = h ? xD1 : B1;
      P1.u[2] = h ? C1 : xA1;  P1.u[3] = h ? D1 : xB1;

      o0 = __builtin_amdgcn_mfma_f32_32x32x16_bf16(v00, P0.v, o0, 0, 0, 0);
      o0 = __builtin_amdgcn_mfma_f32_32x32x16_bf16(v01, P1.v, o0, 0, 0, 0);
      o1 = __builtin_amdgcn_mfma_f32_32x32x16_bf16(v10, P0.v, o1, 0, 0, 0);
      o1 = __builtin_amdgcn_mfma_f32_32x32x16_bf16(v11, P1.v, o1, 0, 0, 0);
    }
  }

  float* ot = &Ot[w][0][0];
  float* orow;
  if (z == 0) orow = Ob + ((size_t)h2*S + qbase)*HD;
  else orow = (h2 < 16) ? Ob1a + ((size_t)h2*S + qbase)*HD
                        : Ob1b + ((size_t)(h2 - 16)*S + qbase)*HD;
#pragma unroll
  for (int r = 0; r < 16; ++r) {
    int dl = (r & 3) + ((r >> 2) << 3) + (h << 2);
    ot[ql*36 + dl] = o0[r];
  }
#pragma unroll
  for (int it = 0; it < 4; ++it) {
    int idx = lane + (it << 6);
    int row = idx >> 3, c4 = (idx & 7) << 2;
    float4 v = *reinterpret_cast<float4*>(&ot[row*36 + c4]);
    *reinterpret_cast<float4*>(&orow[(size_t)row*HD + c4]) = v;
  }
#pragma unroll
  for (int r = 0; r < 16; ++r) {
    int dl = (r & 3) + ((r >> 2) << 3) + (h << 2);
    ot[ql*36 + dl] = o1[r];
  }
#pragma unroll
  for (int it = 0; it < 4; ++it) {
    int idx = lane + (it << 6);
    int row = idx >> 3, c4 = (idx & 7) << 2;
    float4 v = *reinterpret_cast<float4*>(&ot[row*36 + c4]);
    *reinterpret_cast<float4*>(&orow[(size_t)row*HD + 32 + c4]) = v;
  }
  if (lane < 32) {
    if (z == 0) { rowm[h2*S + qbase + lane] = m; rowl[h2*S + qbase + lane] = l; }
    else        { rm1[h2*S + qbase + lane] = m;  rl1[h2*S + qbase + lane] = l; }
  }
}

// ------- merge partial (m,l) -> merged rowm/rowl + per-row weights a0,a1 ----
__global__ __launch_bounds__(256) void merge_ml(float* __restrict__ rowm,
    float* __restrict__ rowl, float* __restrict__ rm1, float* __restrict__ rl1) {
  const int gid = blockIdx.x * 256 + threadIdx.x;   // over H2N*S
  float m0 = rowm[gid], l0 = rowl[gid], m1 = rm1[gid], l1 = rl1[gid];
  float m = fmaxf(m0, m1);
  float w0 = __expf(m0 - m), w1 = __expf(m1 - m);
  float L = l0*w0 + l1*w1;
  float linv = 1.0f / L;
  rowm[gid] = m; rowl[gid] = L;
  rm1[gid] = w0 * linv; rl1[gid] = w1 * linv;
}

// ---------------- colsum via MFMA (bf16 inputs) ----------------
__global__ __launch_bounds__(256) void colsum_mfma(const short* __restrict__ Qb,
    const short* __restrict__ Kb, const float* __restrict__ rowm,
    const float* __restrict__ rowl, float* __restrict__ gcol) {
  const int jt = blockIdx.x;
  const int hh = blockIdx.y, h2 = hh << 1;
  const int cK = jt / 12, jr32 = jt % 12;
  const int jr = jr32 << 5;
  const int j0 = cK*SPP + jr;
  const int tid = threadIdx.x;
  const int w = tid >> 6, lane = tid & 63;
  const int ql = lane & 31, h = lane >> 5;

  bf16x8 kf0, kf1, kf2;
  {
    const short* kp = Kb + ((size_t)h2*S + j0 + ql)*DQK + (h << 3);
    kf0 = *reinterpret_cast<const bf16x8*>(kp);
    kf1 = *reinterpret_cast<const bf16x8*>(kp + 16);
    kf2 = *reinterpret_cast<const bf16x8*>(kp + 32);
  }
  const int nt = 12 - jr32;
  const int T = nt << 2;
  float gs[16];
#pragma unroll
  for (int r = 0; r < 16; ++r) gs[r] = 0.f;

  for (int tt = w; tt < T; tt += 4) {
    int cq = tt / nt, qrem = tt - cq*nt;
    int qi = jr32 + qrem;
    int i0 = cq*SPP + (qi << 5);
    const bool diag = (qrem == 0);
    const short* qp = Qb + ((size_t)h2*S + i0 + ql)*DQK + (h << 3);
    bf16x8 qf0 = *reinterpret_cast<const bf16x8*>(qp);
    bf16x8 qf1 = *reinterpret_cast<const bf16x8*>(qp + 16);
    bf16x8 qf2 = *reinterpret_cast<const bf16x8*>(qp + 32);
    f32x16 st;
#pragma unroll
    for (int r = 0; r < 16; ++r) st[r] = 0.f;
    st = __builtin_amdgcn_mfma_f32_32x32x16_bf16(kf0, qf0, st, 0, 0, 0);
    st = __builtin_amdgcn_mfma_f32_32x32x16_bf16(kf1, qf1, st, 0, 0, 0);
    st = __builtin_amdgcn_mfma_f32_32x32x16_bf16(kf2, qf2, st, 0, 0, 0);
    float Mq = rowm[h2*S + i0 + ql];
    float Lq = 1.0f / rowl[h2*S + i0 + ql];
    if (diag) {
#pragma unroll
      for (int r = 0; r < 16; ++r) {
        int kl = (r & 3) + ((r >> 2) << 3) + (h << 2);
        if (kl <= ql) gs[r] += __expf(st[r]*SCALING - Mq) * Lq;
      }
    } else {
#pragma unroll
      for (int r = 0; r < 16; ++r) gs[r] += __expf(st[r]*SCALING - Mq) * Lq;
    }
  }
  __shared__ float gw[4][32];
#pragma unroll
  for (int r = 0; r < 16; ++r) {
    float v = gs[r];
#pragma unroll
    for (int mm = 1; mm < 32; mm <<= 1) v += __shfl_xor(v, mm, 32);
    if (ql == 0) gw[w][(r & 3) + ((r >> 2) << 3) + (h << 2)] = v;
  }
  __syncthreads();
  if (tid < 32) {
    float s = gw[0][tid] + gw[1][tid] + gw[2][tid] + gw[3][tid];
    gcol[hh*S + j0 + tid] = s * (1.0f / (float)S);
  }
}

// ---------------- Wpre: masked prefix of g-weighted V ----------------
__global__ __launch_bounds__(256) void build_wpre(const float* __restrict__ gcol,
    const float* __restrict__ kvb, float* __restrict__ Wpre) {
  const int hh = blockIdx.x >> 2;
  const int dq = (blockIdx.x & 3) << 4;
  __shared__ float Wt[SPP][16];
  const int tid = threadIdx.x;
  for (int idx = tid; idx < SPP*16; idx += 256) {
    int r = idx >> 4, dd = idx & 15;
    float val = 0.f;
#pragma unroll
    for (int b2 = 0; b2 < 4; ++b2) {
      int j = b2*SPP + r;
      val = fmaf(gcol[hh*S + j], kvb[(size_t)j*2048 + hh*128 + 64 + dq + dd], val);
    }
    Wt[r][dd] = val;
  }
  __syncthreads();
  if (tid < 16) {
    float run = 0.f;
    for (int r = 0; r < SPP; ++r) { run += Wt[r][tid]; Wt[r][tid] = run; }
  }
  __syncthreads();
  for (int idx = tid; idx < SPP*16; idx += 256) {
    int r = idx >> 4, dd = idx & 15;
    Wpre[((size_t)hh*SPP + r)*HD + dq + dd] = Wt[r][dd];
  }
}

// -- combine: merge O partials inline + diff-attn + RMSNorm + reshape -> bf16 --
// grid (S/4, 16), 256 thr: each 64-lane wave handles one (t, h).
__global__ __launch_bounds__(256) void combine_rms(const float* __restrict__ Ob,
    const float* __restrict__ Ob1a, const float* __restrict__ Ob1b,
    const float* __restrict__ a0v, const float* __restrict__ a1v,
    const float* __restrict__ Wpre, const float* __restrict__ lamp,
    const float* __restrict__ anw, short* __restrict__ attno) {
  const int t = blockIdx.x * 4 + (threadIdx.x >> 6);
  const int h = blockIdx.y;
  const int d = threadIdx.x & 63;
  const float lam = lamp[0];
  const int g1 = (2*h)*S + t, g2 = (2*h+1)*S + t;
  const float* p1 = (h < 8) ? (Ob1a + (size_t)g1*HD) : (Ob1b + ((size_t)g1 - (size_t)16*S)*HD);
  const float* p2 = (h < 8) ? (Ob1a + (size_t)g2*HD) : (Ob1b + ((size_t)g2 - (size_t)16*S)*HD);
  float o1 = Ob[(size_t)g1*HD + d] * a0v[g1] + p1[d] * a1v[g1];
  float o2 = Ob[(size_t)g2*HD + d] * a0v[g2] + p2[d] * a1v[g2];
  const float w3 = Wpre[((size_t)h*SPP + (t % SPP))*HD + d];
  float val = o1 - lam*o2 + lam*w3;
  float ss = val*val;
#pragma unroll
  for (int mm = 1; mm < 64; mm <<= 1) ss += __shfl_xor(ss, mm, 64);
  float scale = rsqrtf(ss * (1.0f/HD) + ATTN_EPS) * anw[d];
  int tn = h*96 + (t >> 4);
  int cn = ((t & 15) << 6) + d;
  attno[(size_t)tn*DM + cn] = cvt_bf16(val * scale);
}

// =========================== launch ===========================
extern "C" void kernel_launch(void* const* d_in, const int* in_sizes, int n_in,
                              void* d_out, int out_size, void* d_ws, size_t ws_size,
                              hipStream_t stream) {
  (void)in_sizes; (void)n_in; (void)out_size;
  const float* x    = (const float*)d_in[0];
  const float* fc   = (const float*)d_in[1];
  const float* fs   = (const float*)d_in[2];
  const float* n1w  = (const float*)d_in[3];
  const float* n2w  = (const float*)d_in[4];
  const float* kvdw = (const float*)d_in[5];
  const float* qdw  = (const float*)d_in[6];
  const float* kvnw = (const float*)d_in[7];
  const float* qnw  = (const float*)d_in[8];
  const float* kvuw = (const float*)d_in[9];
  const float* quw  = (const float*)d_in[10];
  const float* lq1  = (const float*)d_in[11];
  const float* lk1  = (const float*)d_in[12];
  const float* lq2  = (const float*)d_in[13];
  const float* lk2  = (const float*)d_in[14];
  const float* anw  = (const float*)d_in[15];
  const float* ow   = (const float*)d_in[16];
  const float* ffiw = (const float*)d_in[17];
  const float* ffow = (const float*)d_in[18];
  float* out = (float*)d_out;
  float* ws  = (float*)d_ws;

  float* xin   = ws;
  float* ckv   = xin   + (size_t)S*DM;        // fused [S][672] down-proj output
  float* qmid  = ckv   + (size_t)S*288;
  float* kvb   = qmid  + (size_t)S*QC;
  float* qf    = kvb   + (size_t)S*2048;
  float* Qb    = qf    + (size_t)S*1536;
  float* Kb    = Qb    + (size_t)H2N*S*DQK;
  float* Obuf  = Kb    + (size_t)H2N*S*DQK;
  float* rowm  = Obuf  + (size_t)H2N*S*HD;
  float* rowl  = rowm  + (size_t)H2N*S;
  float* gcol  = rowl  + (size_t)H2N*S;
  float* Wpre  = gcol  + (size_t)NH*S;
  float* attno = Wpre  + (size_t)NH*SPP*HD;
  float* lamp  = attno + (size_t)S*DM;
  short* fbufs = (short*)kvb;     // bf16 FFN activation overlays kv region
  float* Ob1a = xin;
  float* Ob1b = qf;
  float* rm1  = qf + (size_t)16*S*HD;
  float* rl1  = rm1 + (size_t)H2N*S;
  short* Qb_bf = (short*)Qb;
  short* Kb_bf = (short*)Kb;
  short* Vt_bf = (short*)Qb + 2359296;
  short* xin_bf  = (short*)xin;
  short* ckv_bf  = (short*)Obuf;
  short* qmid_bf = ckv_bf + (size_t)S*KVC;
  short* h_bf    = (short*)ckv;   // rmsnorm2 out: fused-buffer region (dead by then)
  short* attno_bf = (short*)attno;
  short* kvdw_bf = (short*)attno;
  short* qdw_bf  = kvdw_bf + 294912;        // contiguous: fused B (672x1024)
  short* kvuw_bf = qdw_bf  + 393216;
  short* quw_bf  = kvuw_bf + 524288;
  short* ffiw_bf = (short*)Qb;
  short* ow_bf   = ffiw_bf + 8388608;
  short* ffow_bf = (short*)Obuf;
  float* psum0 = xin;             // split-K partials: dead windows at call sites
  float* psum1 = qf;
  if (ws_size < (size_t)18063376 * sizeof(float)) return;

  cvt_w4<<<880, 256, 0, stream>>>(kvdw, 294912, qdw, 393216, kvuw, 524288, quw, 589824, kvdw_bf);
  rmsnorm_bf<<<S, 256, 0, stream>>>(x, n1w, xin_bf, DM, DM, DM, EPS_RMS);
  { dim3 g(11, 24); mgemm_nt<0><<<g, 256, 0, stream>>>(xin_bf, kvdw_bf, nullptr, ckv, S, CKW, DM, DM, DM, CKW); }
  { dim3 g(S, 2);   rmsnorm2_bf<<<g, 256, 0, stream>>>(ckv, kvnw, qnw, ckv_bf, qmid_bf, EPS_RMS); }
  { dim3 g(32, 24); mgemm_nt<0><<<g, 256, 0, stream>>>(ckv_bf,  kvuw_bf, nullptr, kvb, S, 2048, KVC, KVC, KVC, 2048); }
  { dim3 g(24, 24); mgemm_nt<0><<<g, 256, 0, stream>>>(qmid_bf, quw_bf,  nullptr, qf,  S, 1536, QC,  QC,  QC,  1536); }
  { dim3 g(6, 32);  build_qk<<<g, 256, 0, stream>>>(qf, kvb, ckv, fc, fs, Qb_bf, Kb_bf); }
  { dim3 g(16, 12); vt_build<<<g, 256, 0, stream>>>(kvb, Vt_bf); }
  compute_lam<<<1, 32, 0, stream>>>(lq1, lk1, lq2, lk2, lamp);
  { dim3 g(12, 32, 2); flash_mfma<<<g, 256, 0, stream>>>(Qb_bf, Kb_bf, Vt_bf, Obuf, rowm, rowl,
                                                         Ob1a, Ob1b, rm1, rl1); }
  merge_ml<<<(H2N*S)/256, 256, 0, stream>>>(rowm, rowl, rm1, rl1);
  { dim3 g(48, 16); colsum_mfma<<<g, 256, 0, stream>>>(Qb_bf, Kb_bf, rowm, rowl, gcol); }
  cvt_w4<<<4608, 256, 0, stream>>>(ffiw, 8388608, ow, 1048576, nullptr, 0, nullptr, 0, ffiw_bf);
  build_wpre<<<64, 256, 0, stream>>>(gcol, kvb, Wpre);
  { dim3 g(S/4, 16); combine_rms<<<g, 256, 0, stream>>>(Obuf, Ob1a, Ob1b, rm1, rl1,
                                                        Wpre, lamp, anw, attno_bf); }
  cvt_w4<<<2048, 256, 0, stream>>>(ffow, 4194304, nullptr, 0, nullptr, 0, nullptr, 0, ffow_bf);
  { dim3 g(16, 24, 2); mgemm_sk<<<g, 256, 0, stream>>>(attno_bf, ow_bf, psum0, psum1, S, DM, 512, DM, DM, DM); }
  rmsnorm_sum_bf<<<S, 256, 0, stream>>>(psum0, psum1, x, n2w, out, h_bf, EPS_RMS);
  { dim3 g(64, 12); mgemm_glu<<<g, 256, 0, stream>>>(h_bf, ffiw_bf, fbufs, S, DFF, DM, DM, DM, DFF); }
  { dim3 g(16, 24, 2); mgemm_sk<<<g, 256, 0, stream>>>(fbufs, ffow_bf, psum0, psum1, S, DM, 2048, DFF, DFF, DM); }
  fadd2<<<1536, 256, 0, stream>>>(out, psum0, psum1);
}

// Round 17
// 210.773 us; speedup vs baseline: 11.2637x; 1.0338x over previous
//
#include <hip/hip_runtime.h>
#include <math.h>

#define S     1536
#define DM    1024
#define NH    16
#define H2N   32
#define HD    64
#define KVC   256
#define QC    384
#define DFF   4096
#define SPP   384
#define DQK   48
#define CKW   672   /* fused down-proj width: 288 (kv) + 384 (q) */
#define EPS_RMS  1.1920929e-07f
#define ATTN_EPS 1e-5f
#define SCALING  0.14433756729740643f   /* 48^-0.5 */

typedef float f32x4 __attribute__((ext_vector_type(4)));
typedef float f32x16 __attribute__((ext_vector_type(16)));
typedef short bf16x8 __attribute__((ext_vector_type(8)));

__device__ __forceinline__ short cvt_bf16(float f) {
  union { float f; unsigned u; } x; x.f = f;
  unsigned r = x.u + 0x7FFFu + ((x.u >> 16) & 1u);
  return (short)(r >> 16);
}
__device__ __forceinline__ unsigned pk2(float a, float b) { // HW RNE pack
  unsigned r;
  asm("v_cvt_pk_bf16_f32 %0, %1, %2" : "=v"(r) : "v"(a), "v"(b));
  return r;
}
__device__ __forceinline__ bf16x8 cvt8(float4 a, float4 b) {
  union { unsigned u[4]; bf16x8 v; } r;
  r.u[0] = pk2(a.x, a.y); r.u[1] = pk2(a.z, a.w);
  r.u[2] = pk2(b.x, b.y); r.u[3] = pk2(b.z, b.w);
  return r.v;
}
// XCD-aware bijective block swizzle (T1); identity when nwg%8 != 0
__device__ __forceinline__ int swz8(int flat, int nwg) {
  if (nwg & 7) return flat;
  return (flat & 7) * (nwg >> 3) + (flat >> 3);
}

// ---------------- weight fp32 -> bf16 (up to 4 segments, sizes %2048==0) ----
__global__ __launch_bounds__(256) void cvt_w4(const float* __restrict__ s0, int n0,
    const float* __restrict__ s1, int n1, const float* __restrict__ s2, int n2,
    const float* __restrict__ s3, int n3, short* __restrict__ dst) {
  long base = (long)blockIdx.x * 2048 + (long)threadIdx.x * 8;
  const float* src; long off;
  if (base < n0) { src = s0; off = base; }
  else if (base < (long)n0 + n1) { src = s1; off = base - n0; }
  else if (base < (long)n0 + n1 + n2) { src = s2; off = base - n0 - n1; }
  else { src = s3; off = base - n0 - n1 - n2; }
  float4 a = *reinterpret_cast<const float4*>(src + off);
  float4 b = *reinterpret_cast<const float4*>(src + off + 4);
  *reinterpret_cast<bf16x8*>(dst + base) = cvt8(a, b);
}

// ---------------- RMSNorm -> bf16 out ----------------
__global__ __launch_bounds__(256) void rmsnorm_bf(const float* __restrict__ in,
    const float* __restrict__ w, short* __restrict__ out,
    int cols, int ldin, int ldout, float eps) {
  const int row = blockIdx.x;
  const float* xr = in + (size_t)row * ldin;
  short* yr = out + (size_t)row * ldout;
  const int tid = threadIdx.x;
  float ss = 0.f;
  for (int c = tid << 2; c < cols; c += 1024) {
    float4 v = *reinterpret_cast<const float4*>(xr + c);
    ss += v.x*v.x + v.y*v.y + v.z*v.z + v.w*v.w;
  }
#pragma unroll
  for (int mm = 1; mm < 64; mm <<= 1) ss += __shfl_xor(ss, mm, 64);
  __shared__ float red[4];
  if ((tid & 63) == 0) red[tid >> 6] = ss;
  __syncthreads();
  float tot = red[0] + red[1] + red[2] + red[3];
  float scale = rsqrtf(tot / (float)cols + eps);
  for (int c = tid << 2; c < cols; c += 1024) {
    float4 v = *reinterpret_cast<const float4*>(xr + c);
    float4 wv = *reinterpret_cast<const float4*>(w + c);
    uint2 p;
    p.x = pk2(v.x*scale*wv.x, v.y*scale*wv.y);
    p.y = pk2(v.z*scale*wv.z, v.w*scale*wv.w);
    *reinterpret_cast<uint2*>(yr + c) = p;
  }
}

// ---- dual RMSNorm over fused [S][672] buffer: y=0 -> kv(256), y=1 -> q(384) --
__global__ __launch_bounds__(256) void rmsnorm2_bf(const float* __restrict__ comb,
    const float* __restrict__ w0, const float* __restrict__ w1,
    short* __restrict__ o0, short* __restrict__ o1, float eps) {
  const int row = blockIdx.x;
  const int seg = blockIdx.y;
  const float* xr = comb + (size_t)row * CKW + (seg ? 288 : 0);
  const float* w  = seg ? w1 : w0;
  short* yr = seg ? (o1 + (size_t)row * QC) : (o0 + (size_t)row * KVC);
  const int cols = seg ? QC : KVC;
  const int tid = threadIdx.x;
  float ss = 0.f;
  for (int c = tid << 2; c < cols; c += 1024) {
    float4 v = *reinterpret_cast<const float4*>(xr + c);
    ss += v.x*v.x + v.y*v.y + v.z*v.z + v.w*v.w;
  }
#pragma unroll
  for (int mm = 1; mm < 64; mm <<= 1) ss += __shfl_xor(ss, mm, 64);
  __shared__ float red[4];
  if ((tid & 63) == 0) red[tid >> 6] = ss;
  __syncthreads();
  float tot = red[0] + red[1] + red[2] + red[3];
  float scale = rsqrtf(tot / (float)cols + eps);
  for (int c = tid << 2; c < cols; c += 1024) {
    float4 v = *reinterpret_cast<const float4*>(xr + c);
    float4 wv = *reinterpret_cast<const float4*>(w + c);
    uint2 p;
    p.x = pk2(v.x*scale*wv.x, v.y*scale*wv.y);
    p.y = pk2(v.z*scale*wv.z, v.w*scale*wv.w);
    *reinterpret_cast<uint2*>(yr + c) = p;
  }
}

// ------ RMSNorm over (p0+p1+xres), writes residual fp32 AND bf16 norm -------
__global__ __launch_bounds__(256) void rmsnorm_sum_bf(const float* __restrict__ p0,
    const float* __restrict__ p1, const float* __restrict__ xres,
    const float* __restrict__ w, float* __restrict__ outw, short* __restrict__ yb,
    float eps) {
  const int row = blockIdx.x;
  const int c = threadIdx.x << 2;
  const size_t base = (size_t)row * DM + c;
  float4 a = *reinterpret_cast<const float4*>(p0 + base);
  float4 b = *reinterpret_cast<const float4*>(p1 + base);
  float4 xv = *reinterpret_cast<const float4*>(xres + base);
  float4 v = make_float4(a.x+b.x+xv.x, a.y+b.y+xv.y, a.z+b.z+xv.z, a.w+b.w+xv.w);
  *reinterpret_cast<float4*>(outw + base) = v;
  float ss = v.x*v.x + v.y*v.y + v.z*v.z + v.w*v.w;
#pragma unroll
  for (int mm = 1; mm < 64; mm <<= 1) ss += __shfl_xor(ss, mm, 64);
  __shared__ float red[4];
  if ((threadIdx.x & 63) == 0) red[threadIdx.x >> 6] = ss;
  __syncthreads();
  float tot = red[0] + red[1] + red[2] + red[3];
  float scale = rsqrtf(tot * (1.0f / (float)DM) + eps);
  float4 wv = *reinterpret_cast<const float4*>(w + c);
  uint2 p;
  p.x = pk2(v.x*scale*wv.x, v.y*scale*wv.y);
  p.y = pk2(v.z*scale*wv.z, v.w*scale*wv.w);
  *reinterpret_cast<uint2*>(yb + base) = p;
}

// ---------------- out += p0 + p1 (grid: S*DM/1024) ----------------
__global__ __launch_bounds__(256) void fadd2(float* __restrict__ out,
    const float* __restrict__ p0, const float* __restrict__ p1) {
  size_t i = ((size_t)blockIdx.x * 256 + threadIdx.x) << 2;
  float4 o = *reinterpret_cast<float4*>(out + i);
  float4 a = *reinterpret_cast<const float4*>(p0 + i);
  float4 b = *reinterpret_cast<const float4*>(p1 + i);
  o.x += a.x + b.x; o.y += a.y + b.y; o.z += a.z + b.z; o.w += a.w + b.w;
  *reinterpret_cast<float4*>(out + i) = o;
}

// ------------- bf16 MFMA GEMM, BK=64, register-prefetch; A,B bf16 ----------
template<int ADD>
__global__ __launch_bounds__(256) void mgemm_nt(const short* __restrict__ A,
    const short* __restrict__ B, const float* __restrict__ src, float* __restrict__ C,
    int M, int N, int K, int lda, int ldb, int ldc) {
  __shared__ short As[64][72];
  __shared__ short Bs[64][72];
  const int nwg = gridDim.x * gridDim.y;
  const int sfl = swz8(blockIdx.y * gridDim.x + blockIdx.x, nwg);
  const int bxs = sfl % gridDim.x, bys = sfl / gridDim.x;
  const int bm = bys * 64, bn = bxs * 64;
  const int tid = threadIdx.x;
  const int w = tid >> 6, lane = tid & 63;
  const int wr = (w >> 1) << 5, wc = (w & 1) << 5;
  const int srow = tid >> 2, sk = (tid & 3) << 4;
  const int lrow = lane & 15, lk8 = (lane >> 4) << 3;
  const int arow = bm + srow, brow = bn + srow;
  const bool bvalid = brow < N;
  f32x4 acc[2][2];
#pragma unroll
  for (int i = 0; i < 2; ++i)
#pragma unroll
    for (int j = 0; j < 2; ++j) acc[i][j] = (f32x4){0.f, 0.f, 0.f, 0.f};

  bf16x8 rah0, rah1, rbh0, rbh1;
  {
    const short* ap = A + (size_t)arow * lda + sk;
    rah0 = *reinterpret_cast<const bf16x8*>(ap);
    rah1 = *reinterpret_cast<const bf16x8*>(ap + 8);
  }
  rbh0 = (bf16x8){0,0,0,0,0,0,0,0}; rbh1 = rbh0;
  if (bvalid) {
    const short* bp = B + (size_t)brow * ldb + sk;
    rbh0 = *reinterpret_cast<const bf16x8*>(bp);
    rbh1 = *reinterpret_cast<const bf16x8*>(bp + 8);
  }

  for (int k0 = 0; k0 < K; k0 += 64) {
    bf16x8 va0 = rah0, va1 = rah1, vb0 = rbh0, vb1 = rbh1;
    __syncthreads();
    *reinterpret_cast<bf16x8*>(&As[srow][sk])     = va0;
    *reinterpret_cast<bf16x8*>(&As[srow][sk + 8]) = va1;
    *reinterpret_cast<bf16x8*>(&Bs[srow][sk])     = vb0;
    *reinterpret_cast<bf16x8*>(&Bs[srow][sk + 8]) = vb1;
    __syncthreads();
    const int kn = k0 + 64;
    if (kn < K) {
      const short* ap = A + (size_t)arow * lda + kn + sk;
      rah0 = *reinterpret_cast<const bf16x8*>(ap);
      rah1 = *reinterpret_cast<const bf16x8*>(ap + 8);
      if (bvalid) {
        const short* bp = B + (size_t)brow * ldb + kn + sk;
        rbh0 = *reinterpret_cast<const bf16x8*>(bp);
        rbh1 = *reinterpret_cast<const bf16x8*>(bp + 8);
      }
    }
#pragma unroll
    for (int kk = 0; kk < 2; ++kk) {
      bf16x8 af0 = *reinterpret_cast<bf16x8*>(&As[wr + lrow][(kk << 5) + lk8]);
      bf16x8 af1 = *reinterpret_cast<bf16x8*>(&As[wr + 16 + lrow][(kk << 5) + lk8]);
      bf16x8 bf0 = *reinterpret_cast<bf16x8*>(&Bs[wc + lrow][(kk << 5) + lk8]);
      bf16x8 bf1 = *reinterpret_cast<bf16x8*>(&Bs[wc + 16 + lrow][(kk << 5) + lk8]);
      acc[0][0] = __builtin_amdgcn_mfma_f32_16x16x32_bf16(af0, bf0, acc[0][0], 0, 0, 0);
      acc[0][1] = __builtin_amdgcn_mfma_f32_16x16x32_bf16(af0, bf1, acc[0][1], 0, 0, 0);
      acc[1][0] = __builtin_amdgcn_mfma_f32_16x16x32_bf16(af1, bf0, acc[1][0], 0, 0, 0);
      acc[1][1] = __builtin_amdgcn_mfma_f32_16x16x32_bf16(af1, bf1, acc[1][1], 0, 0, 0);
    }
  }
  const int crow0 = bm + wr + ((lane >> 4) << 2);
  const int ccol0 = bn + wc + lrow;
#pragma unroll
  for (int mi = 0; mi < 2; ++mi)
#pragma unroll
    for (int ni = 0; ni < 2; ++ni) {
      int colc = ccol0 + (ni << 4);
      if (colc < N) {
#pragma unroll
        for (int r = 0; r < 4; ++r) {
          int rowc = crow0 + (mi << 4) + r;
          float v = acc[mi][ni][r];
          if (ADD) v += src[(size_t)rowc * ldc + colc];
          C[(size_t)rowc * ldc + colc] = v;
        }
      }
    }
}

// ------ dual GEMM: kv_up (768 tiles) + q_up (576 tiles) in one launch -------
__global__ __launch_bounds__(256) void mgemm_dual(const short* __restrict__ A0,
    const short* __restrict__ B0, float* __restrict__ C0,
    const short* __restrict__ A1, const short* __restrict__ B1, float* __restrict__ C1) {
  __shared__ short As[64][72];
  __shared__ short Bs[64][72];
  const int flat = blockIdx.x;
  const short *A, *B; float* C;
  int K, lda, ldb, ldc, bm, bn;
  if (flat < 768) {      // kv_up: [S][256] @ [2048][256]^T, grid 32x24
    const int sfl = swz8(flat, 768);
    bm = (sfl / 32) * 64; bn = (sfl % 32) * 64;
    A = A0; B = B0; C = C0; K = KVC; lda = KVC; ldb = KVC; ldc = 2048;
  } else {               // q_up: [S][384] @ [1536][384]^T, grid 24x24
    const int sfl = swz8(flat - 768, 576);
    bm = (sfl / 24) * 64; bn = (sfl % 24) * 64;
    A = A1; B = B1; C = C1; K = QC; lda = QC; ldb = QC; ldc = 1536;
  }
  const int tid = threadIdx.x;
  const int w = tid >> 6, lane = tid & 63;
  const int wr = (w >> 1) << 5, wc = (w & 1) << 5;
  const int srow = tid >> 2, sk = (tid & 3) << 4;
  const int lrow = lane & 15, lk8 = (lane >> 4) << 3;
  const int arow = bm + srow, brow = bn + srow;
  f32x4 acc[2][2];
#pragma unroll
  for (int i = 0; i < 2; ++i)
#pragma unroll
    for (int j = 0; j < 2; ++j) acc[i][j] = (f32x4){0.f, 0.f, 0.f, 0.f};

  bf16x8 rah0, rah1, rbh0, rbh1;
  {
    const short* ap = A + (size_t)arow * lda + sk;
    rah0 = *reinterpret_cast<const bf16x8*>(ap);
    rah1 = *reinterpret_cast<const bf16x8*>(ap + 8);
    const short* bp = B + (size_t)brow * ldb + sk;
    rbh0 = *reinterpret_cast<const bf16x8*>(bp);
    rbh1 = *reinterpret_cast<const bf16x8*>(bp + 8);
  }
  for (int k0 = 0; k0 < K; k0 += 64) {
    bf16x8 va0 = rah0, va1 = rah1, vb0 = rbh0, vb1 = rbh1;
    __syncthreads();
    *reinterpret_cast<bf16x8*>(&As[srow][sk])     = va0;
    *reinterpret_cast<bf16x8*>(&As[srow][sk + 8]) = va1;
    *reinterpret_cast<bf16x8*>(&Bs[srow][sk])     = vb0;
    *reinterpret_cast<bf16x8*>(&Bs[srow][sk + 8]) = vb1;
    __syncthreads();
    const int kn = k0 + 64;
    if (kn < K) {
      const short* ap = A + (size_t)arow * lda + kn + sk;
      rah0 = *reinterpret_cast<const bf16x8*>(ap);
      rah1 = *reinterpret_cast<const bf16x8*>(ap + 8);
      const short* bp = B + (size_t)brow * ldb + kn + sk;
      rbh0 = *reinterpret_cast<const bf16x8*>(bp);
      rbh1 = *reinterpret_cast<const bf16x8*>(bp + 8);
    }
#pragma unroll
    for (int kk = 0; kk < 2; ++kk) {
      bf16x8 af0 = *reinterpret_cast<bf16x8*>(&As[wr + lrow][(kk << 5) + lk8]);
      bf16x8 af1 = *reinterpret_cast<bf16x8*>(&As[wr + 16 + lrow][(kk << 5) + lk8]);
      bf16x8 bf0 = *reinterpret_cast<bf16x8*>(&Bs[wc + lrow][(kk << 5) + lk8]);
      bf16x8 bf1 = *reinterpret_cast<bf16x8*>(&Bs[wc + 16 + lrow][(kk << 5) + lk8]);
      acc[0][0] = __builtin_amdgcn_mfma_f32_16x16x32_bf16(af0, bf0, acc[0][0], 0, 0, 0);
      acc[0][1] = __builtin_amdgcn_mfma_f32_16x16x32_bf16(af0, bf1, acc[0][1], 0, 0, 0);
      acc[1][0] = __builtin_amdgcn_mfma_f32_16x16x32_bf16(af1, bf0, acc[1][0], 0, 0, 0);
      acc[1][1] = __builtin_amdgcn_mfma_f32_16x16x32_bf16(af1, bf1, acc[1][1], 0, 0, 0);
    }
  }
  const int crow0 = bm + wr + ((lane >> 4) << 2);
  const int ccol0 = bn + wc + lrow;
#pragma unroll
  for (int mi = 0; mi < 2; ++mi)
#pragma unroll
    for (int ni = 0; ni < 2; ++ni) {
      int colc = ccol0 + (ni << 4);
#pragma unroll
      for (int r = 0; r < 4; ++r) {
        int rowc = crow0 + (mi << 4) + r;
        C[(size_t)rowc * ldc + colc] = acc[mi][ni][r];
      }
    }
}

// ------- split-K=2 bf16 GEMM: z-half of K -> fp32 partial (P0 or P1) --------
__global__ __launch_bounds__(256) void mgemm_sk(const short* __restrict__ A,
    const short* __restrict__ B, float* __restrict__ P0, float* __restrict__ P1,
    int M, int N, int K2, int lda, int ldb, int ldc) {
  __shared__ short As[64][72];
  __shared__ short Bs[64][72];
  const int nwg = gridDim.x * gridDim.y;
  const int sfl = swz8(blockIdx.y * gridDim.x + blockIdx.x, nwg);
  const int bxs = sfl % gridDim.x, bys = sfl / gridDim.x;
  const int bm = bys * 64, bn = bxs * 64;
  const int koff = blockIdx.z * K2;
  float* C = blockIdx.z ? P1 : P0;
  const int tid = threadIdx.x;
  const int w = tid >> 6, lane = tid & 63;
  const int wr = (w >> 1) << 5, wc = (w & 1) << 5;
  const int srow = tid >> 2, sk = (tid & 3) << 4;
  const int lrow = lane & 15, lk8 = (lane >> 4) << 3;
  const int arow = bm + srow, brow = bn + srow;
  f32x4 acc[2][2];
#pragma unroll
  for (int i = 0; i < 2; ++i)
#pragma unroll
    for (int j = 0; j < 2; ++j) acc[i][j] = (f32x4){0.f, 0.f, 0.f, 0.f};

  bf16x8 rah0, rah1, rbh0, rbh1;
  {
    const short* ap = A + (size_t)arow * lda + koff + sk;
    rah0 = *reinterpret_cast<const bf16x8*>(ap);
    rah1 = *reinterpret_cast<const bf16x8*>(ap + 8);
    const short* bp = B + (size_t)brow * ldb + koff + sk;
    rbh0 = *reinterpret_cast<const bf16x8*>(bp);
    rbh1 = *reinterpret_cast<const bf16x8*>(bp + 8);
  }
  const int kend = koff + K2;
  for (int k0 = koff; k0 < kend; k0 += 64) {
    bf16x8 va0 = rah0, va1 = rah1, vb0 = rbh0, vb1 = rbh1;
    __syncthreads();
    *reinterpret_cast<bf16x8*>(&As[srow][sk])     = va0;
    *reinterpret_cast<bf16x8*>(&As[srow][sk + 8]) = va1;
    *reinterpret_cast<bf16x8*>(&Bs[srow][sk])     = vb0;
    *reinterpret_cast<bf16x8*>(&Bs[srow][sk + 8]) = vb1;
    __syncthreads();
    const int kn = k0 + 64;
    if (kn < kend) {
      const short* ap = A + (size_t)arow * lda + kn + sk;
      rah0 = *reinterpret_cast<const bf16x8*>(ap);
      rah1 = *reinterpret_cast<const bf16x8*>(ap + 8);
      const short* bp = B + (size_t)brow * ldb + kn + sk;
      rbh0 = *reinterpret_cast<const bf16x8*>(bp);
      rbh1 = *reinterpret_cast<const bf16x8*>(bp + 8);
    }
#pragma unroll
    for (int kk = 0; kk < 2; ++kk) {
      bf16x8 af0 = *reinterpret_cast<bf16x8*>(&As[wr + lrow][(kk << 5) + lk8]);
      bf16x8 af1 = *reinterpret_cast<bf16x8*>(&As[wr + 16 + lrow][(kk << 5) + lk8]);
      bf16x8 bf0 = *reinterpret_cast<bf16x8*>(&Bs[wc + lrow][(kk << 5) + lk8]);
      bf16x8 bf1 = *reinterpret_cast<bf16x8*>(&Bs[wc + 16 + lrow][(kk << 5) + lk8]);
      acc[0][0] = __builtin_amdgcn_mfma_f32_16x16x32_bf16(af0, bf0, acc[0][0], 0, 0, 0);
      acc[0][1] = __builtin_amdgcn_mfma_f32_16x16x32_bf16(af0, bf1, acc[0][1], 0, 0, 0);
      acc[1][0] = __builtin_amdgcn_mfma_f32_16x16x32_bf16(af1, bf0, acc[1][0], 0, 0, 0);
      acc[1][1] = __builtin_amdgcn_mfma_f32_16x16x32_bf16(af1, bf1, acc[1][1], 0, 0, 0);
    }
  }
  const int crow0 = bm + wr + ((lane >> 4) << 2);
  const int ccol0 = bn + wc + lrow;
#pragma unroll
  for (int mi = 0; mi < 2; ++mi)
#pragma unroll
    for (int ni = 0; ni < 2; ++ni) {
      int colc = ccol0 + (ni << 4);
#pragma unroll
      for (int r = 0; r < 4; ++r) {
        int rowc = crow0 + (mi << 4) + r;
        C[(size_t)rowc * ldc + colc] = acc[mi][ni][r];
      }
    }
}

// ------- 128(M)x64(N) bf16 SwiGLU GEMM: 4 waves, per-wave 64x32 u AND v -----
__global__ __launch_bounds__(256) void mgemm_glu(const short* __restrict__ A,
    const short* __restrict__ Bw, short* __restrict__ C,
    int M, int N, int K, int lda, int ldb, int ldc) {
  __shared__ short As[128][72];
  __shared__ short Bu[64][72];
  __shared__ short Bv[64][72];
  const int nwg = gridDim.x * gridDim.y;
  const int sfl = swz8(blockIdx.y * gridDim.x + blockIdx.x, nwg);
  const int bxs = sfl % gridDim.x, bys = sfl / gridDim.x;
  const int bm = bys * 128, bn = bxs * 64;
  const int tid = threadIdx.x;
  const int w = tid >> 6, lane = tid & 63;
  const int wr = (w >> 1) << 6, wc = (w & 1) << 5;
  const int arow = bm + (tid >> 1), ac = (tid & 1) << 5;
  const int brow = bn + (tid >> 2), bc = (tid & 3) << 4;
  const int lrow = lane & 15, lk8 = (lane >> 4) << 3;
  f32x4 au[4][2], av[4][2];
#pragma unroll
  for (int i = 0; i < 4; ++i)
#pragma unroll
    for (int j = 0; j < 2; ++j) {
      au[i][j] = (f32x4){0.f, 0.f, 0.f, 0.f};
      av[i][j] = (f32x4){0.f, 0.f, 0.f, 0.f};
    }
  bf16x8 ra[4], ru[2], rv[2];
  {
    const short* ap = A + (size_t)arow * lda + ac;
    const short* up = Bw + (size_t)brow * ldb + bc;
    const short* vp = Bw + (size_t)(N + brow) * ldb + bc;
#pragma unroll
    for (int e = 0; e < 4; ++e) ra[e] = *reinterpret_cast<const bf16x8*>(ap + (e << 3));
    ru[0] = *reinterpret_cast<const bf16x8*>(up);
    ru[1] = *reinterpret_cast<const bf16x8*>(up + 8);
    rv[0] = *reinterpret_cast<const bf16x8*>(vp);
    rv[1] = *reinterpret_cast<const bf16x8*>(vp + 8);
  }
  for (int k0 = 0; k0 < K; k0 += 64) {
    __syncthreads();
#pragma unroll
    for (int e = 0; e < 4; ++e)
      *reinterpret_cast<bf16x8*>(&As[tid >> 1][ac + (e << 3)]) = ra[e];
    *reinterpret_cast<bf16x8*>(&Bu[tid >> 2][bc])     = ru[0];
    *reinterpret_cast<bf16x8*>(&Bu[tid >> 2][bc + 8]) = ru[1];
    *reinterpret_cast<bf16x8*>(&Bv[tid >> 2][bc])     = rv[0];
    *reinterpret_cast<bf16x8*>(&Bv[tid >> 2][bc + 8]) = rv[1];
    __syncthreads();
    const int kn = k0 + 64;
    if (kn < K) {
      const short* ap = A + (size_t)arow * lda + kn + ac;
      const short* up = Bw + (size_t)brow * ldb + kn + bc;
      const short* vp = Bw + (size_t)(N + brow) * ldb + kn + bc;
#pragma unroll
      for (int e = 0; e < 4; ++e) ra[e] = *reinterpret_cast<const bf16x8*>(ap + (e << 3));
      ru[0] = *reinterpret_cast<const bf16x8*>(up);
      ru[1] = *reinterpret_cast<const bf16x8*>(up + 8);
      rv[0] = *reinterpret_cast<const bf16x8*>(vp);
      rv[1] = *reinterpret_cast<const bf16x8*>(vp + 8);
    }
#pragma unroll
    for (int kk = 0; kk < 2; ++kk) {
      bf16x8 af[4], uf[2], vf[2];
#pragma unroll
      for (int i = 0; i < 4; ++i)
        af[i] = *reinterpret_cast<bf16x8*>(&As[wr + (i << 4) + lrow][(kk << 5) + lk8]);
#pragma unroll
      for (int j = 0; j < 2; ++j) {
        uf[j] = *reinterpret_cast<bf16x8*>(&Bu[wc + (j << 4) + lrow][(kk << 5) + lk8]);
        vf[j] = *reinterpret_cast<bf16x8*>(&Bv[wc + (j << 4) + lrow][(kk << 5) + lk8]);
      }
#pragma unroll
      for (int i = 0; i < 4; ++i)
#pragma unroll
        for (int j = 0; j < 2; ++j) {
          au[i][j] = __builtin_amdgcn_mfma_f32_16x16x32_bf16(af[i], uf[j], au[i][j], 0, 0, 0);
          av[i][j] = __builtin_amdgcn_mfma_f32_16x16x32_bf16(af[i], vf[j], av[i][j], 0, 0, 0);
        }
    }
  }
  const int crow0 = bm + wr + ((lane >> 4) << 2);
  const int ccol0 = bn + wc + lrow;
#pragma unroll
  for (int mi = 0; mi < 4; ++mi)
#pragma unroll
    for (int ni = 0; ni < 2; ++ni) {
      int colc = ccol0 + (ni << 4);
#pragma unroll
      for (int r = 0; r < 4; ++r) {
        int rowc = crow0 + (mi << 4) + r;
        float uu = au[mi][ni][r], vg = av[mi][ni][r];
        float sig = 1.0f / (1.0f + __expf(-vg));
        C[(size_t)rowc * ldc + colc] = cvt_bf16(uu * vg * sig);
      }
    }
}

// -------- prep_attn: build_qk (blocks 0..191) + V transpose (192..383) ------
__global__ __launch_bounds__(256) void prep_attn(const float* __restrict__ qf,
    const float* __restrict__ kvb, const float* __restrict__ ckv,
    const float* __restrict__ fc, const float* __restrict__ fs,
    short* __restrict__ Qb, short* __restrict__ Kb, short* __restrict__ Vt) {
  __shared__ short Ts[128][74];
  const int bx = blockIdx.x;
  if (bx < 192) {
    // ---- build Q/K ----
    const int t = (bx % 6) * 256 + threadIdx.x;
    const int h2 = bx / 6;
    const int hh = h2 >> 1, par = h2 & 1;
    const float* qrow = qf + (size_t)t*1536 + hh*96;
    const float* krow = kvb + (size_t)t*2048 + hh*128;
    unsigned qu[24], ku[24];
#pragma unroll
    for (int xq = 0; xq < 8; ++xq) {
      float4 qv = *reinterpret_cast<const float4*>(qrow + par*32 + (xq<<2));
      float4 kv = *reinterpret_cast<const float4*>(krow + par*32 + (xq<<2));
      qu[xq*2]   = pk2(qv.x, qv.y); qu[xq*2+1] = pk2(qv.z, qv.w);
      ku[xq*2]   = pk2(kv.x, kv.y); ku[xq*2+1] = pk2(kv.z, kv.w);
    }
    int p = t >> 2;
    const float* qr = qrow + 64 + par*16;
    const float* kr = ckv + (size_t)t*CKW + 256 + par*16;
#pragma unroll
    for (int mq = 0; mq < 8; ++mq) {
      float c = 1.f, sn = 0.f;
      if (p > 0) { c = fc[(p-1)*8 + mq]; sn = fs[(p-1)*8 + mq]; }
      float q0 = qr[2*mq], q1 = qr[2*mq+1];
      qu[16 + mq] = pk2(q0*c - q1*sn, q0*sn + q1*c);
      float k0 = kr[2*mq], k1 = kr[2*mq+1];
      ku[16 + mq] = pk2(k0*c - k1*sn, k0*sn + k1*c);
    }
    unsigned* qo = (unsigned*)(Qb + ((size_t)h2*S + t)*DQK);
    unsigned* ko = (unsigned*)(Kb + ((size_t)h2*S + t)*DQK);
#pragma unroll
    for (int e = 0; e < 6; ++e) {
      *reinterpret_cast<uint4*>(qo + (e<<2)) = make_uint4(qu[e*4], qu[e*4+1], qu[e*4+2], qu[e*4+3]);
      *reinterpret_cast<uint4*>(ko + (e<<2)) = make_uint4(ku[e*4], ku[e*4+1], ku[e*4+2], ku[e*4+3]);
    }
  } else {
    // ---- V transpose: Vt[hh][d][t] ----
    const int f2 = bx - 192;
    const int hh = f2 % 16;
    const int t0 = (f2 / 16) << 7;
    const int tl = threadIdx.x >> 3, dp = (threadIdx.x & 7) << 3;
#pragma unroll
    for (int pass = 0; pass < 4; ++pass) {
      int t = t0 + (pass << 5) + tl;
      const float* vp = kvb + (size_t)t*2048 + hh*128 + 64 + dp;
      float4 a = *reinterpret_cast<const float4*>(vp);
      float4 b = *reinterpret_cast<const float4*>(vp + 4);
      *reinterpret_cast<bf16x8*>(&Ts[(pass << 5) + tl][dp]) = cvt8(a, b);
    }
    __syncthreads();
    for (int idx = threadIdx.x; idx < 1024; idx += 256) {
      int d = idx >> 4, tseg = (idx & 15) << 3;
      bf16x8 v;
#pragma unroll
      for (int e = 0; e < 8; ++e) v[e] = Ts[tseg + e][d];
      *reinterpret_cast<bf16x8*>(Vt + ((size_t)hh*HD + d)*S + t0 + tseg) = v;
    }
  }
}

// ------- MFMA flash attention: NO-LDS fragments direct from L2 ----------
__global__ __launch_bounds__(256) void flash_mfma(const short* __restrict__ Qb,
    const short* __restrict__ Kb, const short* __restrict__ Vg,
    float* __restrict__ Ob, float* __restrict__ rowm, float* __restrict__ rowl,
    float* __restrict__ Ob1a, float* __restrict__ Ob1b,
    float* __restrict__ rm1, float* __restrict__ rl1) {
  const int h2 = blockIdx.y;
  const int hh = h2 >> 1;
  const int z  = blockIdx.z;
  const int tid = threadIdx.x;
  const int w = tid >> 6, lane = tid & 63;
  const int ql = lane & 31, h = lane >> 5;
  const int cq = blockIdx.x / 3, k = blockIdx.x % 3;
  const int qi = k + 3*w;
  const int qbase = cq*SPP + (qi << 5);
  const int ri0w = qi << 5;

  __shared__ __align__(16) float Ot[4][32][36];

  bf16x8 qf0, qf1, qf2;
  {
    const short* qp = Qb + ((size_t)h2*S + qbase + ql)*DQK + (h << 3);
    qf0 = *reinterpret_cast<const bf16x8*>(qp);
    qf1 = *reinterpret_cast<const bf16x8*>(qp + 16);
    qf2 = *reinterpret_cast<const bf16x8*>(qp + 32);
  }
  const short* Kbase = Kb + (size_t)h2*S*DQK + (h << 3);
  const short* V0 = Vg + ((size_t)hh*HD + ql)*S + (h << 3);
  const short* V1 = Vg + ((size_t)hh*HD + 32 + ql)*S + (h << 3);

  float m = -1e30f, l = 0.f;
  f32x16 o0, o1;
#pragma unroll
  for (int r = 0; r < 16; ++r) { o0[r] = 0.f; o1[r] = 0.f; }

  for (int c = (z << 1); c < (z << 1) + 2; ++c) {
    for (int jr = 0; jr <= ri0w; jr += 32) {
      const int j0 = c*SPP + jr;
      const bool diag = (jr == ri0w);
      const short* kp = Kbase + (size_t)(j0 + ql)*DQK;
      bf16x8 kf0 = *reinterpret_cast<const bf16x8*>(kp);
      bf16x8 kf1 = *reinterpret_cast<const bf16x8*>(kp + 16);
      bf16x8 kf2 = *reinterpret_cast<const bf16x8*>(kp + 32);
      bf16x8 v00 = *reinterpret_cast<const bf16x8*>(V0 + j0);
      bf16x8 v01 = *reinterpret_cast<const bf16x8*>(V0 + j0 + 16);
      bf16x8 v10 = *reinterpret_cast<const bf16x8*>(V1 + j0);
      bf16x8 v11 = *reinterpret_cast<const bf16x8*>(V1 + j0 + 16);

      f32x16 st;
#pragma unroll
      for (int r = 0; r < 16; ++r) st[r] = 0.f;
      st = __builtin_amdgcn_mfma_f32_32x32x16_bf16(kf0, qf0, st, 0, 0, 0);
      st = __builtin_amdgcn_mfma_f32_32x32x16_bf16(kf1, qf1, st, 0, 0, 0);
      st = __builtin_amdgcn_mfma_f32_32x32x16_bf16(kf2, qf2, st, 0, 0, 0);

      if (diag) {
#pragma unroll
        for (int r = 0; r < 16; ++r) {
          int kl = (r & 3) + ((r >> 2) << 3) + (h << 2);
          st[r] = (kl <= ql) ? st[r] * SCALING : -1e30f;
        }
      } else {
#pragma unroll
        for (int r = 0; r < 16; ++r) st[r] *= SCALING;
      }

      float tm = st[0];
#pragma unroll
      for (int r = 1; r < 16; ++r) tm = fmaxf(tm, st[r]);
      tm = fmaxf(tm, __shfl_xor(tm, 32));
      if (__any(tm > m + 8.0f)) {
        float mnew = fmaxf(m, tm);
        float sc = __expf(m - mnew);
        m = mnew;
        l *= sc;
#pragma unroll
        for (int r = 0; r < 16; ++r) { o0[r] *= sc; o1[r] *= sc; }
      }
      float ps = 0.f;
#pragma unroll
      for (int r = 0; r < 16; ++r) { float p = __expf(st[r] - m); st[r] = p; ps += p; }
      ps += __shfl_xor(ps, 32);
      l += ps;

      unsigned A0 = pk2(st[0],  st[1]),  B0 = pk2(st[2],  st[3]);
      unsigned C0 = pk2(st[4],  st[5]),  D0 = pk2(st[6],  st[7]);
      unsigned A1 = pk2(st[8],  st[9]),  B1 = pk2(st[10], st[11]);
      unsigned C1 = pk2(st[12], st[13]), D1 = pk2(st[14], st[15]);
      unsigned xA0 = (unsigned)__shfl_xor((int)A0, 32), xB0 = (unsigned)__shfl_xor((int)B0, 32);
      unsigned xC0 = (unsigned)__shfl_xor((int)C0, 32), xD0 = (unsigned)__shfl_xor((int)D0, 32);
      unsigned xA1 = (unsigned)__shfl_xor((int)A1, 32), xB1 = (unsigned)__shfl_xor((int)B1, 32);
      unsigned xC1 = (unsigned)__shfl_xor((int)C1, 32), xD1 = (unsigned)__shfl_xor((int)D1, 32);
      union { unsigned u[4]; bf16x8 v; } P0, P1;
      P0.u[0] = h ? xC0 : A0;  P0.u[1] = h ? xD0 : B0;
      P0.u[2] = h ? C0 : xA0;  P0.u[3] = h ? D0 : xB0;
      P1.u[0] = h ? xC1 : A1;  P1.u[1] = h ? xD1 : B1;
      P1.u[2] = h ? C1 : xA1;  P1.u[3] = h ? D1 : xB1;

      o0 = __builtin_amdgcn_mfma_f32_32x32x16_bf16(v00, P0.v, o0, 0, 0, 0);
      o0 = __builtin_amdgcn_mfma_f32_32x32x16_bf16(v01, P1.v, o0, 0, 0, 0);
      o1 = __builtin_amdgcn_mfma_f32_32x32x16_bf16(v10, P0.v, o1, 0, 0, 0);
      o1 = __builtin_amdgcn_mfma_f32_32x32x16_bf16(v11, P1.v, o1, 0, 0, 0);
    }
  }

  float* ot = &Ot[w][0][0];
  float* orow;
  if (z == 0) orow = Ob + ((size_t)h2*S + qbase)*HD;
  else orow = (h2 < 16) ? Ob1a + ((size_t)h2*S + qbase)*HD
                        : Ob1b + ((size_t)(h2 - 16)*S + qbase)*HD;
#pragma unroll
  for (int r = 0; r < 16; ++r) {
    int dl = (r & 3) + ((r >> 2) << 3) + (h << 2);
    ot[ql*36 + dl] = o0[r];
  }
#pragma unroll
  for (int it = 0; it < 4; ++it) {
    int idx = lane + (it << 6);
    int row = idx >> 3, c4 = (idx & 7) << 2;
    float4 v = *reinterpret_cast<float4*>(&ot[row*36 + c4]);
    *reinterpret_cast<float4*>(&orow[(size_t)row*HD + c4]) = v;
  }
#pragma unroll
  for (int r = 0; r < 16; ++r) {
    int dl = (r & 3) + ((r >> 2) << 3) + (h << 2);
    ot[ql*36 + dl] = o1[r];
  }
#pragma unroll
  for (int it = 0; it < 4; ++it) {
    int idx = lane + (it << 6);
    int row = idx >> 3, c4 = (idx & 7) << 2;
    float4 v = *reinterpret_cast<float4*>(&ot[row*36 + c4]);
    *reinterpret_cast<float4*>(&orow[(size_t)row*HD + 32 + c4]) = v;
  }
  if (lane < 32) {
    if (z == 0) { rowm[h2*S + qbase + lane] = m; rowl[h2*S + qbase + lane] = l; }
    else        { rm1[h2*S + qbase + lane] = m;  rl1[h2*S + qbase + lane] = l; }
  }
}

// -- merge partial (m,l) -> merged rowm/rowl + weights a0,a1; block0: lambda --
__global__ __launch_bounds__(256) void merge_ml(float* __restrict__ rowm,
    float* __restrict__ rowl, float* __restrict__ rm1, float* __restrict__ rl1,
    const float* __restrict__ lq1, const float* __restrict__ lk1,
    const float* __restrict__ lq2, const float* __restrict__ lk2,
    float* __restrict__ lamp) {
  const int gid = blockIdx.x * 256 + threadIdx.x;   // over H2N*S
  float m0 = rowm[gid], l0 = rowl[gid], m1 = rm1[gid], l1 = rl1[gid];
  float m = fmaxf(m0, m1);
  float w0 = __expf(m0 - m), w1 = __expf(m1 - m);
  float L = l0*w0 + l1*w1;
  float linv = 1.0f / L;
  rowm[gid] = m; rowl[gid] = L;
  rm1[gid] = w0 * linv; rl1[gid] = w1 * linv;
  if (blockIdx.x == 0 && threadIdx.x < 32) {
    int t = threadIdx.x;
    float a = lq1[t]*lk1[t];
    float b = lq2[t]*lk2[t];
#pragma unroll
    for (int mm = 1; mm < 32; mm <<= 1) { a += __shfl_xor(a, mm, 32); b += __shfl_xor(b, mm, 32); }
    if (t == 0) lamp[0] = expf(a) - expf(b) + 0.2f;
  }
}

// ---------------- colsum via MFMA (bf16 inputs) ----------------
__global__ __launch_bounds__(256) void colsum_mfma(const short* __restrict__ Qb,
    const short* __restrict__ Kb, const float* __restrict__ rowm,
    const float* __restrict__ rowl, float* __restrict__ gcol) {
  const int jt = blockIdx.x;
  const int hh = blockIdx.y, h2 = hh << 1;
  const int cK = jt / 12, jr32 = jt % 12;
  const int jr = jr32 << 5;
  const int j0 = cK*SPP + jr;
  const int tid = threadIdx.x;
  const int w = tid >> 6, lane = tid & 63;
  const int ql = lane & 31, h = lane >> 5;

  bf16x8 kf0, kf1, kf2;
  {
    const short* kp = Kb + ((size_t)h2*S + j0 + ql)*DQK + (h << 3);
    kf0 = *reinterpret_cast<const bf16x8*>(kp);
    kf1 = *reinterpret_cast<const bf16x8*>(kp + 16);
    kf2 = *reinterpret_cast<const bf16x8*>(kp + 32);
  }
  const int nt = 12 - jr32;
  const int T = nt << 2;
  float gs[16];
#pragma unroll
  for (int r = 0; r < 16; ++r) gs[r] = 0.f;

  for (int tt = w; tt < T; tt += 4) {
    int cq = tt / nt, qrem = tt - cq*nt;
    int qi = jr32 + qrem;
    int i0 = cq*SPP + (qi << 5);
    const bool diag = (qrem == 0);
    const short* qp = Qb + ((size_t)h2*S + i0 + ql)*DQK + (h << 3);
    bf16x8 qf0 = *reinterpret_cast<const bf16x8*>(qp);
    bf16x8 qf1 = *reinterpret_cast<const bf16x8*>(qp + 16);
    bf16x8 qf2 = *reinterpret_cast<const bf16x8*>(qp + 32);
    f32x16 st;
#pragma unroll
    for (int r = 0; r < 16; ++r) st[r] = 0.f;
    st = __builtin_amdgcn_mfma_f32_32x32x16_bf16(kf0, qf0, st, 0, 0, 0);
    st = __builtin_amdgcn_mfma_f32_32x32x16_bf16(kf1, qf1, st, 0, 0, 0);
    st = __builtin_amdgcn_mfma_f32_32x32x16_bf16(kf2, qf2, st, 0, 0, 0);
    float Mq = rowm[h2*S + i0 + ql];
    float Lq = 1.0f / rowl[h2*S + i0 + ql];
    if (diag) {
#pragma unroll
      for (int r = 0; r < 16; ++r) {
        int kl = (r & 3) + ((r >> 2) << 3) + (h << 2);
        if (kl <= ql) gs[r] += __expf(st[r]*SCALING - Mq) * Lq;
      }
    } else {
#pragma unroll
      for (int r = 0; r < 16; ++r) gs[r] += __expf(st[r]*SCALING - Mq) * Lq;
    }
  }
  __shared__ float gw[4][32];
#pragma unroll
  for (int r = 0; r < 16; ++r) {
    float v = gs[r];
#pragma unroll
    for (int mm = 1; mm < 32; mm <<= 1) v += __shfl_xor(v, mm, 32);
    if (ql == 0) gw[w][(r & 3) + ((r >> 2) << 3) + (h << 2)] = v;
  }
  __syncthreads();
  if (tid < 32) {
    float s = gw[0][tid] + gw[1][tid] + gw[2][tid] + gw[3][tid];
    gcol[hh*S + j0 + tid] = s * (1.0f / (float)S);
  }
}

// ---------------- Wpre: masked prefix of g-weighted V ----------------
__global__ __launch_bounds__(256) void build_wpre(const float* __restrict__ gcol,
    const float* __restrict__ kvb, float* __restrict__ Wpre) {
  const int hh = blockIdx.x >> 2;
  const int dq = (blockIdx.x & 3) << 4;
  __shared__ float Wt[SPP][16];
  const int tid = threadIdx.x;
  for (int idx = tid; idx < SPP*16; idx += 256) {
    int r = idx >> 4, dd = idx & 15;
    float val = 0.f;
#pragma unroll
    for (int b2 = 0; b2 < 4; ++b2) {
      int j = b2*SPP + r;
      val = fmaf(gcol[hh*S + j], kvb[(size_t)j*2048 + hh*128 + 64 + dq + dd], val);
    }
    Wt[r][dd] = val;
  }
  __syncthreads();
  if (tid < 16) {
    float run = 0.f;
    for (int r = 0; r < SPP; ++r) { run += Wt[r][tid]; Wt[r][tid] = run; }
  }
  __syncthreads();
  for (int idx = tid; idx < SPP*16; idx += 256) {
    int r = idx >> 4, dd = idx & 15;
    Wpre[((size_t)hh*SPP + r)*HD + dq + dd] = Wt[r][dd];
  }
}

// -- combine: merge O partials inline + diff-attn + RMSNorm + reshape -> bf16 --
__global__ __launch_bounds__(256) void combine_rms(const float* __restrict__ Ob,
    const float* __restrict__ Ob1a, const float* __restrict__ Ob1b,
    const float* __restrict__ a0v, const float* __restrict__ a1v,
    const float* __restrict__ Wpre, const float* __restrict__ lamp,
    const float* __restrict__ anw, short* __restrict__ attno) {
  const int t = blockIdx.x * 4 + (threadIdx.x >> 6);
  const int h = blockIdx.y;
  const int d = threadIdx.x & 63;
  const float lam = lamp[0];
  const int g1 = (2*h)*S + t, g2 = (2*h+1)*S + t;
  const float* p1 = (h < 8) ? (Ob1a + (size_t)g1*HD) : (Ob1b + ((size_t)g1 - (size_t)16*S)*HD);
  const float* p2 = (h < 8) ? (Ob1a + (size_t)g2*HD) : (Ob1b + ((size_t)g2 - (size_t)16*S)*HD);
  float o1 = Ob[(size_t)g1*HD + d] * a0v[g1] + p1[d] * a1v[g1];
  float o2 = Ob[(size_t)g2*HD + d] * a0v[g2] + p2[d] * a1v[g2];
  const float w3 = Wpre[((size_t)h*SPP + (t % SPP))*HD + d];
  float val = o1 - lam*o2 + lam*w3;
  float ss = val*val;
#pragma unroll
  for (int mm = 1; mm < 64; mm <<= 1) ss += __shfl_xor(ss, mm, 64);
  float scale = rsqrtf(ss * (1.0f/HD) + ATTN_EPS) * anw[d];
  int tn = h*96 + (t >> 4);
  int cn = ((t & 15) << 6) + d;
  attno[(size_t)tn*DM + cn] = cvt_bf16(val * scale);
}

// =========================== launch ===========================
extern "C" void kernel_launch(void* const* d_in, const int* in_sizes, int n_in,
                              void* d_out, int out_size, void* d_ws, size_t ws_size,
                              hipStream_t stream) {
  (void)in_sizes; (void)n_in; (void)out_size;
  const float* x    = (const float*)d_in[0];
  const float* fc   = (const float*)d_in[1];
  const float* fs   = (const float*)d_in[2];
  const float* n1w  = (const float*)d_in[3];
  const float* n2w  = (const float*)d_in[4];
  const float* kvdw = (const float*)d_in[5];
  const float* qdw  = (const float*)d_in[6];
  const float* kvnw = (const float*)d_in[7];
  const float* qnw  = (const float*)d_in[8];
  const float* kvuw = (const float*)d_in[9];
  const float* quw  = (const float*)d_in[10];
  const float* lq1  = (const float*)d_in[11];
  const float* lk1  = (const float*)d_in[12];
  const float* lq2  = (const float*)d_in[13];
  const float* lk2  = (const float*)d_in[14];
  const float* anw  = (const float*)d_in[15];
  const float* ow   = (const float*)d_in[16];
  const float* ffiw = (const float*)d_in[17];
  const float* ffow = (const float*)d_in[18];
  float* out = (float*)d_out;
  float* ws  = (float*)d_ws;

  float* xin   = ws;
  float* ckv   = xin   + (size_t)S*DM;        // fused [S][672] down-proj output
  float* qmid  = ckv   + (size_t)S*288;
  float* kvb   = qmid  + (size_t)S*QC;
  float* qf    = kvb   + (size_t)S*2048;
  float* Qb    = qf    + (size_t)S*1536;
  float* Kb    = Qb    + (size_t)H2N*S*DQK;
  float* Obuf  = Kb    + (size_t)H2N*S*DQK;
  float* rowm  = Obuf  + (size_t)H2N*S*HD;
  float* rowl  = rowm  + (size_t)H2N*S;
  float* gcol  = rowl  + (size_t)H2N*S;
  float* Wpre  = gcol  + (size_t)NH*S;
  float* attno = Wpre  + (size_t)NH*SPP*HD;
  float* lamp  = attno + (size_t)S*DM;
  short* fbufs = (short*)kvb;     // bf16 FFN activation overlays kv region
  float* Ob1a = xin;
  float* Ob1b = qf;
  float* rm1  = qf + (size_t)16*S*HD;
  float* rl1  = rm1 + (size_t)H2N*S;
  short* Qb_bf = (short*)Qb;
  short* Kb_bf = (short*)Kb;
  short* Vt_bf = (short*)Qb + 2359296;
  short* xin_bf  = (short*)xin;
  short* ckv_bf  = (short*)Obuf;
  short* qmid_bf = ckv_bf + (size_t)S*KVC;
  short* h_bf    = (short*)ckv;   // rmsnorm2 out: fused-buffer region (dead by then)
  short* attno_bf = (short*)attno;
  short* kvdw_bf = (short*)attno;
  short* qdw_bf  = kvdw_bf + 294912;        // contiguous: fused B (672x1024)
  short* kvuw_bf = qdw_bf  + 393216;
  short* quw_bf  = kvuw_bf + 524288;
  short* ffiw_bf = (short*)Qb;
  short* ow_bf   = ffiw_bf + 8388608;
  short* ffow_bf = (short*)Obuf;
  float* psum0 = xin;             // split-K partials: dead windows at call sites
  float* psum1 = qf;
  if (ws_size < (size_t)18063376 * sizeof(float)) return;

  cvt_w4<<<880, 256, 0, stream>>>(kvdw, 294912, qdw, 393216, kvuw, 524288, quw, 589824, kvdw_bf);
  rmsnorm_bf<<<S, 256, 0, stream>>>(x, n1w, xin_bf, DM, DM, DM, EPS_RMS);
  { dim3 g(11, 24); mgemm_nt<0><<<g, 256, 0, stream>>>(xin_bf, kvdw_bf, nullptr, ckv, S, CKW, DM, DM, DM, CKW); }
  { dim3 g(S, 2);   rmsnorm2_bf<<<g, 256, 0, stream>>>(ckv, kvnw, qnw, ckv_bf, qmid_bf, EPS_RMS); }
  mgemm_dual<<<1344, 256, 0, stream>>>(ckv_bf, kvuw_bf, kvb, qmid_bf, quw_bf, qf);
  prep_attn<<<384, 256, 0, stream>>>(qf, kvb, ckv, fc, fs, Qb_bf, Kb_bf, Vt_bf);
  { dim3 g(12, 32, 2); flash_mfma<<<g, 256, 0, stream>>>(Qb_bf, Kb_bf, Vt_bf, Obuf, rowm, rowl,
                                                         Ob1a, Ob1b, rm1, rl1); }
  merge_ml<<<(H2N*S)/256, 256, 0, stream>>>(rowm, rowl, rm1, rl1, lq1, lk1, lq2, lk2, lamp);
  { dim3 g(48, 16); colsum_mfma<<<g, 256, 0, stream>>>(Qb_bf, Kb_bf, rowm, rowl, gcol); }
  cvt_w4<<<4608, 256, 0, stream>>>(ffiw, 8388608, ow, 1048576, nullptr, 0, nullptr, 0, ffiw_bf);
  build_wpre<<<64, 256, 0, stream>>>(gcol, kvb, Wpre);
  { dim3 g(S/4, 16); combine_rms<<<g, 256, 0, stream>>>(Obuf, Ob1a, Ob1b, rm1, rl1,
                                                        Wpre, lamp, anw, attno_bf); }
  cvt_w4<<<2048, 256, 0, stream>>>(ffow, 4194304, nullptr, 0, nullptr, 0, nullptr, 0, ffow_bf);
  { dim3 g(16, 24, 2); mgemm_sk<<<g, 256, 0, stream>>>(attno_bf, ow_bf, psum0, psum1, S, DM, 512, DM, DM, DM); }
  rmsnorm_sum_bf<<<S, 256, 0, stream>>>(psum0, psum1, x, n2w, out, h_bf, EPS_RMS);
  { dim3 g(64, 12); mgemm_glu<<<g, 256, 0, stream>>>(h_bf, ffiw_bf, fbufs, S, DFF, DM, DM, DM, DFF); }
  { dim3 g(16, 24, 2); mgemm_sk<<<g, 256, 0, stream>>>(fbufs, ffow_bf, psum0, psum1, S, DM, 2048, DFF, DFF, DM); }
  fadd2<<<1536, 256, 0, stream>>>(out, psum0, psum1);
}

// Round 18
// 202.641 us; speedup vs baseline: 11.7156x; 1.0401x over previous
//
#include <hip/hip_runtime.h>
#include <math.h>

#define S     1536
#define DM    1024
#define NH    16
#define H2N   32
#define HD    64
#define KVC   256
#define QC    384
#define DFF   4096
#define SPP   384
#define DQK   48
#define CKW   672   /* fused down-proj width: 288 (kv) + 384 (q) */
#define EPS_RMS  1.1920929e-07f
#define ATTN_EPS 1e-5f
#define SCALING  0.14433756729740643f   /* 48^-0.5 */

typedef float f32x4 __attribute__((ext_vector_type(4)));
typedef float f32x16 __attribute__((ext_vector_type(16)));
typedef short bf16x8 __attribute__((ext_vector_type(8)));

__device__ __forceinline__ short cvt_bf16(float f) {
  union { float f; unsigned u; } x; x.f = f;
  unsigned r = x.u + 0x7FFFu + ((x.u >> 16) & 1u);
  return (short)(r >> 16);
}
__device__ __forceinline__ unsigned pk2(float a, float b) { // HW RNE pack
  unsigned r;
  asm("v_cvt_pk_bf16_f32 %0, %1, %2" : "=v"(r) : "v"(a), "v"(b));
  return r;
}
__device__ __forceinline__ bf16x8 cvt8(float4 a, float4 b) {
  union { unsigned u[4]; bf16x8 v; } r;
  r.u[0] = pk2(a.x, a.y); r.u[1] = pk2(a.z, a.w);
  r.u[2] = pk2(b.x, b.y); r.u[3] = pk2(b.z, b.w);
  return r.v;
}
// XCD-aware bijective block swizzle (T1); identity when nwg%8 != 0
__device__ __forceinline__ int swz8(int flat, int nwg) {
  if (nwg & 7) return flat;
  return (flat & 7) * (nwg >> 3) + (flat >> 3);
}

// ---------------- RMSNorm -> bf16 out ----------------
__device__ __forceinline__ void rms_body(const float* xr, const float* w,
    short* yr, int cols, float eps) {
  const int tid = threadIdx.x;
  float ss = 0.f;
  for (int c = tid << 2; c < cols; c += 1024) {
    float4 v = *reinterpret_cast<const float4*>(xr + c);
    ss += v.x*v.x + v.y*v.y + v.z*v.z + v.w*v.w;
  }
#pragma unroll
  for (int mm = 1; mm < 64; mm <<= 1) ss += __shfl_xor(ss, mm, 64);
  __shared__ float red[4];
  if ((tid & 63) == 0) red[tid >> 6] = ss;
  __syncthreads();
  float tot = red[0] + red[1] + red[2] + red[3];
  float scale = rsqrtf(tot / (float)cols + eps);
  for (int c = tid << 2; c < cols; c += 1024) {
    float4 v = *reinterpret_cast<const float4*>(xr + c);
    float4 wv = *reinterpret_cast<const float4*>(w + c);
    uint2 p;
    p.x = pk2(v.x*scale*wv.x, v.y*scale*wv.y);
    p.y = pk2(v.z*scale*wv.z, v.w*scale*wv.w);
    *reinterpret_cast<uint2*>(yr + c) = p;
  }
}

// ---- rms1_cvt: blocks 0..1535 rmsnorm1; 1536..2415 early-weight cvt -------
__global__ __launch_bounds__(256) void rms1_cvt(const float* __restrict__ x,
    const float* __restrict__ n1w, short* __restrict__ xin_bf,
    const float* __restrict__ s0, int n0, const float* __restrict__ s1, int n1,
    const float* __restrict__ s2, int n2, const float* __restrict__ s3,
    short* __restrict__ dst) {
  const int bx = blockIdx.x;
  if (bx < S) {
    rms_body(x + (size_t)bx * DM, n1w, xin_bf + (size_t)bx * DM, DM, EPS_RMS);
  } else {
    long base = (long)(bx - S) * 2048 + (long)threadIdx.x * 8;
    const float* src; long off;
    if (base < n0) { src = s0; off = base; }
    else if (base < (long)n0 + n1) { src = s1; off = base - n0; }
    else if (base < (long)n0 + n1 + n2) { src = s2; off = base - n0 - n1; }
    else { src = s3; off = base - n0 - n1 - n2; }
    float4 a = *reinterpret_cast<const float4*>(src + off);
    float4 b = *reinterpret_cast<const float4*>(src + off + 4);
    *reinterpret_cast<bf16x8*>(dst + base) = cvt8(a, b);
  }
}

// ---- dual RMSNorm over fused [S][672] buffer: y=0 -> kv(256), y=1 -> q(384) --
__global__ __launch_bounds__(256) void rmsnorm2_bf(const float* __restrict__ comb,
    const float* __restrict__ w0, const float* __restrict__ w1,
    short* __restrict__ o0, short* __restrict__ o1, float eps) {
  const int row = blockIdx.x;
  const int seg = blockIdx.y;
  const float* xr = comb + (size_t)row * CKW + (seg ? 288 : 0);
  rms_body(xr, seg ? w1 : w0,
           seg ? (o1 + (size_t)row * QC) : (o0 + (size_t)row * KVC),
           seg ? QC : KVC, eps);
}

// ------ RMSNorm over (p0+p1+xres), writes residual fp32 AND bf16 norm -------
__global__ __launch_bounds__(256) void rmsnorm_sum_bf(const float* __restrict__ p0,
    const float* __restrict__ p1, const float* __restrict__ xres,
    const float* __restrict__ w, float* __restrict__ outw, short* __restrict__ yb,
    float eps) {
  const int row = blockIdx.x;
  const int c = threadIdx.x << 2;
  const size_t base = (size_t)row * DM + c;
  float4 a = *reinterpret_cast<const float4*>(p0 + base);
  float4 b = *reinterpret_cast<const float4*>(p1 + base);
  float4 xv = *reinterpret_cast<const float4*>(xres + base);
  float4 v = make_float4(a.x+b.x+xv.x, a.y+b.y+xv.y, a.z+b.z+xv.z, a.w+b.w+xv.w);
  *reinterpret_cast<float4*>(outw + base) = v;
  float ss = v.x*v.x + v.y*v.y + v.z*v.z + v.w*v.w;
#pragma unroll
  for (int mm = 1; mm < 64; mm <<= 1) ss += __shfl_xor(ss, mm, 64);
  __shared__ float red[4];
  if ((threadIdx.x & 63) == 0) red[threadIdx.x >> 6] = ss;
  __syncthreads();
  float tot = red[0] + red[1] + red[2] + red[3];
  float scale = rsqrtf(tot * (1.0f / (float)DM) + eps);
  float4 wv = *reinterpret_cast<const float4*>(w + c);
  uint2 p;
  p.x = pk2(v.x*scale*wv.x, v.y*scale*wv.y);
  p.y = pk2(v.z*scale*wv.z, v.w*scale*wv.w);
  *reinterpret_cast<uint2*>(yb + base) = p;
}

// ---------------- out += p0 + p1 (grid: S*DM/1024) ----------------
__global__ __launch_bounds__(256) void fadd2(float* __restrict__ out,
    const float* __restrict__ p0, const float* __restrict__ p1) {
  size_t i = ((size_t)blockIdx.x * 256 + threadIdx.x) << 2;
  float4 o = *reinterpret_cast<float4*>(out + i);
  float4 a = *reinterpret_cast<const float4*>(p0 + i);
  float4 b = *reinterpret_cast<const float4*>(p1 + i);
  o.x += a.x + b.x; o.y += a.y + b.y; o.z += a.z + b.z; o.w += a.w + b.w;
  *reinterpret_cast<float4*>(out + i) = o;
}

// ------------- bf16 MFMA GEMM, BK=64, register-prefetch; A,B bf16 ----------
template<int ADD>
__global__ __launch_bounds__(256) void mgemm_nt(const short* __restrict__ A,
    const short* __restrict__ B, const float* __restrict__ src, float* __restrict__ C,
    int M, int N, int K, int lda, int ldb, int ldc) {
  __shared__ short As[64][72];
  __shared__ short Bs[64][72];
  const int nwg = gridDim.x * gridDim.y;
  const int sfl = swz8(blockIdx.y * gridDim.x + blockIdx.x, nwg);
  const int bxs = sfl % gridDim.x, bys = sfl / gridDim.x;
  const int bm = bys * 64, bn = bxs * 64;
  const int tid = threadIdx.x;
  const int w = tid >> 6, lane = tid & 63;
  const int wr = (w >> 1) << 5, wc = (w & 1) << 5;
  const int srow = tid >> 2, sk = (tid & 3) << 4;
  const int lrow = lane & 15, lk8 = (lane >> 4) << 3;
  const int arow = bm + srow, brow = bn + srow;
  const bool bvalid = brow < N;
  f32x4 acc[2][2];
#pragma unroll
  for (int i = 0; i < 2; ++i)
#pragma unroll
    for (int j = 0; j < 2; ++j) acc[i][j] = (f32x4){0.f, 0.f, 0.f, 0.f};

  bf16x8 rah0, rah1, rbh0, rbh1;
  {
    const short* ap = A + (size_t)arow * lda + sk;
    rah0 = *reinterpret_cast<const bf16x8*>(ap);
    rah1 = *reinterpret_cast<const bf16x8*>(ap + 8);
  }
  rbh0 = (bf16x8){0,0,0,0,0,0,0,0}; rbh1 = rbh0;
  if (bvalid) {
    const short* bp = B + (size_t)brow * ldb + sk;
    rbh0 = *reinterpret_cast<const bf16x8*>(bp);
    rbh1 = *reinterpret_cast<const bf16x8*>(bp + 8);
  }

  for (int k0 = 0; k0 < K; k0 += 64) {
    bf16x8 va0 = rah0, va1 = rah1, vb0 = rbh0, vb1 = rbh1;
    __syncthreads();
    *reinterpret_cast<bf16x8*>(&As[srow][sk])     = va0;
    *reinterpret_cast<bf16x8*>(&As[srow][sk + 8]) = va1;
    *reinterpret_cast<bf16x8*>(&Bs[srow][sk])     = vb0;
    *reinterpret_cast<bf16x8*>(&Bs[srow][sk + 8]) = vb1;
    __syncthreads();
    const int kn = k0 + 64;
    if (kn < K) {
      const short* ap = A + (size_t)arow * lda + kn + sk;
      rah0 = *reinterpret_cast<const bf16x8*>(ap);
      rah1 = *reinterpret_cast<const bf16x8*>(ap + 8);
      if (bvalid) {
        const short* bp = B + (size_t)brow * ldb + kn + sk;
        rbh0 = *reinterpret_cast<const bf16x8*>(bp);
        rbh1 = *reinterpret_cast<const bf16x8*>(bp + 8);
      }
    }
#pragma unroll
    for (int kk = 0; kk < 2; ++kk) {
      bf16x8 af0 = *reinterpret_cast<bf16x8*>(&As[wr + lrow][(kk << 5) + lk8]);
      bf16x8 af1 = *reinterpret_cast<bf16x8*>(&As[wr + 16 + lrow][(kk << 5) + lk8]);
      bf16x8 bf0 = *reinterpret_cast<bf16x8*>(&Bs[wc + lrow][(kk << 5) + lk8]);
      bf16x8 bf1 = *reinterpret_cast<bf16x8*>(&Bs[wc + 16 + lrow][(kk << 5) + lk8]);
      acc[0][0] = __builtin_amdgcn_mfma_f32_16x16x32_bf16(af0, bf0, acc[0][0], 0, 0, 0);
      acc[0][1] = __builtin_amdgcn_mfma_f32_16x16x32_bf16(af0, bf1, acc[0][1], 0, 0, 0);
      acc[1][0] = __builtin_amdgcn_mfma_f32_16x16x32_bf16(af1, bf0, acc[1][0], 0, 0, 0);
      acc[1][1] = __builtin_amdgcn_mfma_f32_16x16x32_bf16(af1, bf1, acc[1][1], 0, 0, 0);
    }
  }
  const int crow0 = bm + wr + ((lane >> 4) << 2);
  const int ccol0 = bn + wc + lrow;
#pragma unroll
  for (int mi = 0; mi < 2; ++mi)
#pragma unroll
    for (int ni = 0; ni < 2; ++ni) {
      int colc = ccol0 + (ni << 4);
      if (colc < N) {
#pragma unroll
        for (int r = 0; r < 4; ++r) {
          int rowc = crow0 + (mi << 4) + r;
          float v = acc[mi][ni][r];
          if (ADD) v += src[(size_t)rowc * ldc + colc];
          C[(size_t)rowc * ldc + colc] = v;
        }
      }
    }
}

// ------ dual GEMM: kv_up (768 tiles) + q_up (576 tiles) in one launch -------
__global__ __launch_bounds__(256) void mgemm_dual(const short* __restrict__ A0,
    const short* __restrict__ B0, float* __restrict__ C0,
    const short* __restrict__ A1, const short* __restrict__ B1, float* __restrict__ C1) {
  __shared__ short As[64][72];
  __shared__ short Bs[64][72];
  const int flat = blockIdx.x;
  const short *A, *B; float* C;
  int K, lda, ldb, ldc, bm, bn;
  if (flat < 768) {
    const int sfl = swz8(flat, 768);
    bm = (sfl / 32) * 64; bn = (sfl % 32) * 64;
    A = A0; B = B0; C = C0; K = KVC; lda = KVC; ldb = KVC; ldc = 2048;
  } else {
    const int sfl = swz8(flat - 768, 576);
    bm = (sfl / 24) * 64; bn = (sfl % 24) * 64;
    A = A1; B = B1; C = C1; K = QC; lda = QC; ldb = QC; ldc = 1536;
  }
  const int tid = threadIdx.x;
  const int w = tid >> 6, lane = tid & 63;
  const int wr = (w >> 1) << 5, wc = (w & 1) << 5;
  const int srow = tid >> 2, sk = (tid & 3) << 4;
  const int lrow = lane & 15, lk8 = (lane >> 4) << 3;
  const int arow = bm + srow, brow = bn + srow;
  f32x4 acc[2][2];
#pragma unroll
  for (int i = 0; i < 2; ++i)
#pragma unroll
    for (int j = 0; j < 2; ++j) acc[i][j] = (f32x4){0.f, 0.f, 0.f, 0.f};

  bf16x8 rah0, rah1, rbh0, rbh1;
  {
    const short* ap = A + (size_t)arow * lda + sk;
    rah0 = *reinterpret_cast<const bf16x8*>(ap);
    rah1 = *reinterpret_cast<const bf16x8*>(ap + 8);
    const short* bp = B + (size_t)brow * ldb + sk;
    rbh0 = *reinterpret_cast<const bf16x8*>(bp);
    rbh1 = *reinterpret_cast<const bf16x8*>(bp + 8);
  }
  for (int k0 = 0; k0 < K; k0 += 64) {
    bf16x8 va0 = rah0, va1 = rah1, vb0 = rbh0, vb1 = rbh1;
    __syncthreads();
    *reinterpret_cast<bf16x8*>(&As[srow][sk])     = va0;
    *reinterpret_cast<bf16x8*>(&As[srow][sk + 8]) = va1;
    *reinterpret_cast<bf16x8*>(&Bs[srow][sk])     = vb0;
    *reinterpret_cast<bf16x8*>(&Bs[srow][sk + 8]) = vb1;
    __syncthreads();
    const int kn = k0 + 64;
    if (kn < K) {
      const short* ap = A + (size_t)arow * lda + kn + sk;
      rah0 = *reinterpret_cast<const bf16x8*>(ap);
      rah1 = *reinterpret_cast<const bf16x8*>(ap + 8);
      const short* bp = B + (size_t)brow * ldb + kn + sk;
      rbh0 = *reinterpret_cast<const bf16x8*>(bp);
      rbh1 = *reinterpret_cast<const bf16x8*>(bp + 8);
    }
#pragma unroll
    for (int kk = 0; kk < 2; ++kk) {
      bf16x8 af0 = *reinterpret_cast<bf16x8*>(&As[wr + lrow][(kk << 5) + lk8]);
      bf16x8 af1 = *reinterpret_cast<bf16x8*>(&As[wr + 16 + lrow][(kk << 5) + lk8]);
      bf16x8 bf0 = *reinterpret_cast<bf16x8*>(&Bs[wc + lrow][(kk << 5) + lk8]);
      bf16x8 bf1 = *reinterpret_cast<bf16x8*>(&Bs[wc + 16 + lrow][(kk << 5) + lk8]);
      acc[0][0] = __builtin_amdgcn_mfma_f32_16x16x32_bf16(af0, bf0, acc[0][0], 0, 0, 0);
      acc[0][1] = __builtin_amdgcn_mfma_f32_16x16x32_bf16(af0, bf1, acc[0][1], 0, 0, 0);
      acc[1][0] = __builtin_amdgcn_mfma_f32_16x16x32_bf16(af1, bf0, acc[1][0], 0, 0, 0);
      acc[1][1] = __builtin_amdgcn_mfma_f32_16x16x32_bf16(af1, bf1, acc[1][1], 0, 0, 0);
    }
  }
  const int crow0 = bm + wr + ((lane >> 4) << 2);
  const int ccol0 = bn + wc + lrow;
#pragma unroll
  for (int mi = 0; mi < 2; ++mi)
#pragma unroll
    for (int ni = 0; ni < 2; ++ni) {
      int colc = ccol0 + (ni << 4);
#pragma unroll
      for (int r = 0; r < 4; ++r) {
        int rowc = crow0 + (mi << 4) + r;
        C[(size_t)rowc * ldc + colc] = acc[mi][ni][r];
      }
    }
}

// ---- split-K=2 GEMM body (bm,bn,koff given) -> fp32 partial ----
__device__ __forceinline__ void sk_body(const short* __restrict__ A,
    const short* __restrict__ B, float* __restrict__ C,
    int bm, int bn, int koff, int K2, int lda, int ldb, int ldc) {
  __shared__ short As[64][72];
  __shared__ short Bs[64][72];
  const int tid = threadIdx.x;
  const int w = tid >> 6, lane = tid & 63;
  const int wr = (w >> 1) << 5, wc = (w & 1) << 5;
  const int srow = tid >> 2, sk = (tid & 3) << 4;
  const int lrow = lane & 15, lk8 = (lane >> 4) << 3;
  const int arow = bm + srow, brow = bn + srow;
  f32x4 acc[2][2];
#pragma unroll
  for (int i = 0; i < 2; ++i)
#pragma unroll
    for (int j = 0; j < 2; ++j) acc[i][j] = (f32x4){0.f, 0.f, 0.f, 0.f};

  bf16x8 rah0, rah1, rbh0, rbh1;
  {
    const short* ap = A + (size_t)arow * lda + koff + sk;
    rah0 = *reinterpret_cast<const bf16x8*>(ap);
    rah1 = *reinterpret_cast<const bf16x8*>(ap + 8);
    const short* bp = B + (size_t)brow * ldb + koff + sk;
    rbh0 = *reinterpret_cast<const bf16x8*>(bp);
    rbh1 = *reinterpret_cast<const bf16x8*>(bp + 8);
  }
  const int kend = koff + K2;
  for (int k0 = koff; k0 < kend; k0 += 64) {
    bf16x8 va0 = rah0, va1 = rah1, vb0 = rbh0, vb1 = rbh1;
    __syncthreads();
    *reinterpret_cast<bf16x8*>(&As[srow][sk])     = va0;
    *reinterpret_cast<bf16x8*>(&As[srow][sk + 8]) = va1;
    *reinterpret_cast<bf16x8*>(&Bs[srow][sk])     = vb0;
    *reinterpret_cast<bf16x8*>(&Bs[srow][sk + 8]) = vb1;
    __syncthreads();
    const int kn = k0 + 64;
    if (kn < kend) {
      const short* ap = A + (size_t)arow * lda + kn + sk;
      rah0 = *reinterpret_cast<const bf16x8*>(ap);
      rah1 = *reinterpret_cast<const bf16x8*>(ap + 8);
      const short* bp = B + (size_t)brow * ldb + kn + sk;
      rbh0 = *reinterpret_cast<const bf16x8*>(bp);
      rbh1 = *reinterpret_cast<const bf16x8*>(bp + 8);
    }
#pragma unroll
    for (int kk = 0; kk < 2; ++kk) {
      bf16x8 af0 = *reinterpret_cast<bf16x8*>(&As[wr + lrow][(kk << 5) + lk8]);
      bf16x8 af1 = *reinterpret_cast<bf16x8*>(&As[wr + 16 + lrow][(kk << 5) + lk8]);
      bf16x8 bf0 = *reinterpret_cast<bf16x8*>(&Bs[wc + lrow][(kk << 5) + lk8]);
      bf16x8 bf1 = *reinterpret_cast<bf16x8*>(&Bs[wc + 16 + lrow][(kk << 5) + lk8]);
      acc[0][0] = __builtin_amdgcn_mfma_f32_16x16x32_bf16(af0, bf0, acc[0][0], 0, 0, 0);
      acc[0][1] = __builtin_amdgcn_mfma_f32_16x16x32_bf16(af0, bf1, acc[0][1], 0, 0, 0);
      acc[1][0] = __builtin_amdgcn_mfma_f32_16x16x32_bf16(af1, bf0, acc[1][0], 0, 0, 0);
      acc[1][1] = __builtin_amdgcn_mfma_f32_16x16x32_bf16(af1, bf1, acc[1][1], 0, 0, 0);
    }
  }
  const int crow0 = bm + wr + ((lane >> 4) << 2);
  const int ccol0 = bn + wc + lrow;
#pragma unroll
  for (int mi = 0; mi < 2; ++mi)
#pragma unroll
    for (int ni = 0; ni < 2; ++ni) {
      int colc = ccol0 + (ni << 4);
#pragma unroll
      for (int r = 0; r < 4; ++r) {
        int rowc = crow0 + (mi << 4) + r;
        C[(size_t)rowc * ldc + colc] = acc[mi][ni][r];
      }
    }
}

// ------- split-K=2 bf16 GEMM (ff_out): z-half of K -> fp32 partial ----------
__global__ __launch_bounds__(256) void mgemm_sk(const short* __restrict__ A,
    const short* __restrict__ B, float* __restrict__ P0, float* __restrict__ P1,
    int M, int N, int K2, int lda, int ldb, int ldc) {
  const int nwg = gridDim.x * gridDim.y;
  const int sfl = swz8(blockIdx.y * gridDim.x + blockIdx.x, nwg);
  sk_body(A, B, blockIdx.z ? P1 : P0, (sfl / gridDim.x) * 64,
          (sfl % gridDim.x) * 64, blockIdx.z * K2, K2, lda, ldb, ldc);
}

// -- oproj_cvt: blocks 0..767 o-proj split-K; 768..2815 ffow cvt ------------
__global__ __launch_bounds__(256) void oproj_cvt(const short* __restrict__ A,
    const short* __restrict__ B, float* __restrict__ P0, float* __restrict__ P1,
    const float* __restrict__ ffow, short* __restrict__ ffow_bf) {
  const int bx = blockIdx.x;
  if (bx < 768) {
    const int z = bx >= 384;
    const int sfl = swz8(bx - (z ? 384 : 0), 384);
    sk_body(A, B, z ? P1 : P0, (sfl / 16) * 64, (sfl % 16) * 64,
            z * 512, 512, DM, DM, DM);
  } else {
    long base = (long)(bx - 768) * 2048 + (long)threadIdx.x * 8;
    float4 a = *reinterpret_cast<const float4*>(ffow + base);
    float4 b = *reinterpret_cast<const float4*>(ffow + base + 4);
    *reinterpret_cast<bf16x8*>(ffow_bf + base) = cvt8(a, b);
  }
}

// ------- 128(M)x64(N) bf16 SwiGLU GEMM: 4 waves, per-wave 64x32 u AND v -----
__global__ __launch_bounds__(256) void mgemm_glu(const short* __restrict__ A,
    const short* __restrict__ Bw, short* __restrict__ C,
    int M, int N, int K, int lda, int ldb, int ldc) {
  __shared__ short As[128][72];
  __shared__ short Bu[64][72];
  __shared__ short Bv[64][72];
  const int nwg = gridDim.x * gridDim.y;
  const int sfl = swz8(blockIdx.y * gridDim.x + blockIdx.x, nwg);
  const int bxs = sfl % gridDim.x, bys = sfl / gridDim.x;
  const int bm = bys * 128, bn = bxs * 64;
  const int tid = threadIdx.x;
  const int w = tid >> 6, lane = tid & 63;
  const int wr = (w >> 1) << 6, wc = (w & 1) << 5;
  const int arow = bm + (tid >> 1), ac = (tid & 1) << 5;
  const int brow = bn + (tid >> 2), bc = (tid & 3) << 4;
  const int lrow = lane & 15, lk8 = (lane >> 4) << 3;
  f32x4 au[4][2], av[4][2];
#pragma unroll
  for (int i = 0; i < 4; ++i)
#pragma unroll
    for (int j = 0; j < 2; ++j) {
      au[i][j] = (f32x4){0.f, 0.f, 0.f, 0.f};
      av[i][j] = (f32x4){0.f, 0.f, 0.f, 0.f};
    }
  bf16x8 ra[4], ru[2], rv[2];
  {
    const short* ap = A + (size_t)arow * lda + ac;
    const short* up = Bw + (size_t)brow * ldb + bc;
    const short* vp = Bw + (size_t)(N + brow) * ldb + bc;
#pragma unroll
    for (int e = 0; e < 4; ++e) ra[e] = *reinterpret_cast<const bf16x8*>(ap + (e << 3));
    ru[0] = *reinterpret_cast<const bf16x8*>(up);
    ru[1] = *reinterpret_cast<const bf16x8*>(up + 8);
    rv[0] = *reinterpret_cast<const bf16x8*>(vp);
    rv[1] = *reinterpret_cast<const bf16x8*>(vp + 8);
  }
  for (int k0 = 0; k0 < K; k0 += 64) {
    __syncthreads();
#pragma unroll
    for (int e = 0; e < 4; ++e)
      *reinterpret_cast<bf16x8*>(&As[tid >> 1][ac + (e << 3)]) = ra[e];
    *reinterpret_cast<bf16x8*>(&Bu[tid >> 2][bc])     = ru[0];
    *reinterpret_cast<bf16x8*>(&Bu[tid >> 2][bc + 8]) = ru[1];
    *reinterpret_cast<bf16x8*>(&Bv[tid >> 2][bc])     = rv[0];
    *reinterpret_cast<bf16x8*>(&Bv[tid >> 2][bc + 8]) = rv[1];
    __syncthreads();
    const int kn = k0 + 64;
    if (kn < K) {
      const short* ap = A + (size_t)arow * lda + kn + ac;
      const short* up = Bw + (size_t)brow * ldb + kn + bc;
      const short* vp = Bw + (size_t)(N + brow) * ldb + kn + bc;
#pragma unroll
      for (int e = 0; e < 4; ++e) ra[e] = *reinterpret_cast<const bf16x8*>(ap + (e << 3));
      ru[0] = *reinterpret_cast<const bf16x8*>(up);
      ru[1] = *reinterpret_cast<const bf16x8*>(up + 8);
      rv[0] = *reinterpret_cast<const bf16x8*>(vp);
      rv[1] = *reinterpret_cast<const bf16x8*>(vp + 8);
    }
#pragma unroll
    for (int kk = 0; kk < 2; ++kk) {
      bf16x8 af[4], uf[2], vf[2];
#pragma unroll
      for (int i = 0; i < 4; ++i)
        af[i] = *reinterpret_cast<bf16x8*>(&As[wr + (i << 4) + lrow][(kk << 5) + lk8]);
#pragma unroll
      for (int j = 0; j < 2; ++j) {
        uf[j] = *reinterpret_cast<bf16x8*>(&Bu[wc + (j << 4) + lrow][(kk << 5) + lk8]);
        vf[j] = *reinterpret_cast<bf16x8*>(&Bv[wc + (j << 4) + lrow][(kk << 5) + lk8]);
      }
      __builtin_amdgcn_s_setprio(1);
#pragma unroll
      for (int i = 0; i < 4; ++i)
#pragma unroll
        for (int j = 0; j < 2; ++j) {
          au[i][j] = __builtin_amdgcn_mfma_f32_16x16x32_bf16(af[i], uf[j], au[i][j], 0, 0, 0);
          av[i][j] = __builtin_amdgcn_mfma_f32_16x16x32_bf16(af[i], vf[j], av[i][j], 0, 0, 0);
        }
      __builtin_amdgcn_s_setprio(0);
    }
  }
  const int crow0 = bm + wr + ((lane >> 4) << 2);
  const int ccol0 = bn + wc + lrow;
#pragma unroll
  for (int mi = 0; mi < 4; ++mi)
#pragma unroll
    for (int ni = 0; ni < 2; ++ni) {
      int colc = ccol0 + (ni << 4);
#pragma unroll
      for (int r = 0; r < 4; ++r) {
        int rowc = crow0 + (mi << 4) + r;
        float uu = au[mi][ni][r], vg = av[mi][ni][r];
        float sig = 1.0f / (1.0f + __expf(-vg));
        C[(size_t)rowc * ldc + colc] = cvt_bf16(uu * vg * sig);
      }
    }
}

// -------- prep_attn: build_qk (blocks 0..191) + V transpose (192..383) ------
__global__ __launch_bounds__(256) void prep_attn(const float* __restrict__ qf,
    const float* __restrict__ kvb, const float* __restrict__ ckv,
    const float* __restrict__ fc, const float* __restrict__ fs,
    short* __restrict__ Qb, short* __restrict__ Kb, short* __restrict__ Vt) {
  __shared__ short Ts[128][74];
  const int bx = blockIdx.x;
  if (bx < 192) {
    const int t = (bx % 6) * 256 + threadIdx.x;
    const int h2 = bx / 6;
    const int hh = h2 >> 1, par = h2 & 1;
    const float* qrow = qf + (size_t)t*1536 + hh*96;
    const float* krow = kvb + (size_t)t*2048 + hh*128;
    unsigned qu[24], ku[24];
#pragma unroll
    for (int xq = 0; xq < 8; ++xq) {
      float4 qv = *reinterpret_cast<const float4*>(qrow + par*32 + (xq<<2));
      float4 kv = *reinterpret_cast<const float4*>(krow + par*32 + (xq<<2));
      qu[xq*2]   = pk2(qv.x, qv.y); qu[xq*2+1] = pk2(qv.z, qv.w);
      ku[xq*2]   = pk2(kv.x, kv.y); ku[xq*2+1] = pk2(kv.z, kv.w);
    }
    int p = t >> 2;
    const float* qr = qrow + 64 + par*16;
    const float* kr = ckv + (size_t)t*CKW + 256 + par*16;
#pragma unroll
    for (int mq = 0; mq < 8; ++mq) {
      float c = 1.f, sn = 0.f;
      if (p > 0) { c = fc[(p-1)*8 + mq]; sn = fs[(p-1)*8 + mq]; }
      float q0 = qr[2*mq], q1 = qr[2*mq+1];
      qu[16 + mq] = pk2(q0*c - q1*sn, q0*sn + q1*c);
      float k0 = kr[2*mq], k1 = kr[2*mq+1];
      ku[16 + mq] = pk2(k0*c - k1*sn, k0*sn + k1*c);
    }
    unsigned* qo = (unsigned*)(Qb + ((size_t)h2*S + t)*DQK);
    unsigned* ko = (unsigned*)(Kb + ((size_t)h2*S + t)*DQK);
#pragma unroll
    for (int e = 0; e < 6; ++e) {
      *reinterpret_cast<uint4*>(qo + (e<<2)) = make_uint4(qu[e*4], qu[e*4+1], qu[e*4+2], qu[e*4+3]);
      *reinterpret_cast<uint4*>(ko + (e<<2)) = make_uint4(ku[e*4], ku[e*4+1], ku[e*4+2], ku[e*4+3]);
    }
  } else {
    const int f2 = bx - 192;
    const int hh = f2 % 16;
    const int t0 = (f2 / 16) << 7;
    const int tl = threadIdx.x >> 3, dp = (threadIdx.x & 7) << 3;
#pragma unroll
    for (int pass = 0; pass < 4; ++pass) {
      int t = t0 + (pass << 5) + tl;
      const float* vp = kvb + (size_t)t*2048 + hh*128 + 64 + dp;
      float4 a = *reinterpret_cast<const float4*>(vp);
      float4 b = *reinterpret_cast<const float4*>(vp + 4);
      *reinterpret_cast<bf16x8*>(&Ts[(pass << 5) + tl][dp]) = cvt8(a, b);
    }
    __syncthreads();
    for (int idx = threadIdx.x; idx < 1024; idx += 256) {
      int d = idx >> 4, tseg = (idx & 15) << 3;
      bf16x8 v;
#pragma unroll
      for (int e = 0; e < 8; ++e) v[e] = Ts[tseg + e][d];
      *reinterpret_cast<bf16x8*>(Vt + ((size_t)hh*HD + d)*S + t0 + tseg) = v;
    }
  }
}

// ------- MFMA flash attention: NO-LDS fragments direct from L2 ----------
__global__ __launch_bounds__(256) void flash_mfma(const short* __restrict__ Qb,
    const short* __restrict__ Kb, const short* __restrict__ Vg,
    float* __restrict__ Ob, float* __restrict__ rowm, float* __restrict__ rowl,
    float* __restrict__ Ob1a, float* __restrict__ Ob1b,
    float* __restrict__ rm1, float* __restrict__ rl1) {
  const int h2 = blockIdx.y;
  const int hh = h2 >> 1;
  const int z  = blockIdx.z;
  const int tid = threadIdx.x;
  const int w = tid >> 6, lane = tid & 63;
  const int ql = lane & 31, h = lane >> 5;
  const int cq = blockIdx.x / 3, k = blockIdx.x % 3;
  const int qi = k + 3*w;
  const int qbase = cq*SPP + (qi << 5);
  const int ri0w = qi << 5;

  __shared__ __align__(16) float Ot[4][32][36];

  bf16x8 qf0, qf1, qf2;
  {
    const short* qp = Qb + ((size_t)h2*S + qbase + ql)*DQK + (h << 3);
    qf0 = *reinterpret_cast<const bf16x8*>(qp);
    qf1 = *reinterpret_cast<const bf16x8*>(qp + 16);
    qf2 = *reinterpret_cast<const bf16x8*>(qp + 32);
  }
  const short* Kbase = Kb + (size_t)h2*S*DQK + (h << 3);
  const short* V0 = Vg + ((size_t)hh*HD + ql)*S + (h << 3);
  const short* V1 = Vg + ((size_t)hh*HD + 32 + ql)*S + (h << 3);

  float m = -1e30f, l = 0.f;
  f32x16 o0, o1;
#pragma unroll
  for (int r = 0; r < 16; ++r) { o0[r] = 0.f; o1[r] = 0.f; }

  for (int c = (z << 1); c < (z << 1) + 2; ++c) {
    for (int jr = 0; jr <= ri0w; jr += 32) {
      const int j0 = c*SPP + jr;
      const bool diag = (jr == ri0w);
      const short* kp = Kbase + (size_t)(j0 + ql)*DQK;
      bf16x8 kf0 = *reinterpret_cast<const bf16x8*>(kp);
      bf16x8 kf1 = *reinterpret_cast<const bf16x8*>(kp + 16);
      bf16x8 kf2 = *reinterpret_cast<const bf16x8*>(kp + 32);
      bf16x8 v00 = *reinterpret_cast<const bf16x8*>(V0 + j0);
      bf16x8 v01 = *reinterpret_cast<const bf16x8*>(V0 + j0 + 16);
      bf16x8 v10 = *reinterpret_cast<const bf16x8*>(V1 + j0);
      bf16x8 v11 = *reinterpret_cast<const bf16x8*>(V1 + j0 + 16);

      f32x16 st;
#pragma unroll
      for (int r = 0; r < 16; ++r) st[r] = 0.f;
      __builtin_amdgcn_s_setprio(1);
      st = __builtin_amdgcn_mfma_f32_32x32x16_bf16(kf0, qf0, st, 0, 0, 0);
      st = __builtin_amdgcn_mfma_f32_32x32x16_bf16(kf1, qf1, st, 0, 0, 0);
      st = __builtin_amdgcn_mfma_f32_32x32x16_bf16(kf2, qf2, st, 0, 0, 0);
      __builtin_amdgcn_s_setprio(0);

      if (diag) {
#pragma unroll
        for (int r = 0; r < 16; ++r) {
          int kl = (r & 3) + ((r >> 2) << 3) + (h << 2);
          st[r] = (kl <= ql) ? st[r] * SCALING : -1e30f;
        }
      } else {
#pragma unroll
        for (int r = 0; r < 16; ++r) st[r] *= SCALING;
      }

      float tm = st[0];
#pragma unroll
      for (int r = 1; r < 16; ++r) tm = fmaxf(tm, st[r]);
      tm = fmaxf(tm, __shfl_xor(tm, 32));
      if (__any(tm > m + 8.0f)) {
        float mnew = fmaxf(m, tm);
        float sc = __expf(m - mnew);
        m = mnew;
        l *= sc;
#pragma unroll
        for (int r = 0; r < 16; ++r) { o0[r] *= sc; o1[r] *= sc; }
      }
      float ps = 0.f;
#pragma unroll
      for (int r = 0; r < 16; ++r) { float p = __expf(st[r] - m); st[r] = p; ps += p; }
      ps += __shfl_xor(ps, 32);
      l += ps;

      unsigned A0 = pk2(st[0],  st[1]),  B0 = pk2(st[2],  st[3]);
      unsigned C0 = pk2(st[4],  st[5]),  D0 = pk2(st[6],  st[7]);
      unsigned A1 = pk2(st[8],  st[9]),  B1 = pk2(st[10], st[11]);
      unsigned C1 = pk2(st[12], st[13]), D1 = pk2(st[14], st[15]);
      unsigned xA0 = (unsigned)__shfl_xor((int)A0, 32), xB0 = (unsigned)__shfl_xor((int)B0, 32);
      unsigned xC0 = (unsigned)__shfl_xor((int)C0, 32), xD0 = (unsigned)__shfl_xor((int)D0, 32);
      unsigned xA1 = (unsigned)__shfl_xor((int)A1, 32), xB1 = (unsigned)__shfl_xor((int)B1, 32);
      unsigned xC1 = (unsigned)__shfl_xor((int)C1, 32), xD1 = (unsigned)__shfl_xor((int)D1, 32);
      union { unsigned u[4]; bf16x8 v; } P0, P1;
      P0.u[0] = h ? xC0 : A0;  P0.u[1] = h ? xD0 : B0;
      P0.u[2] = h ? C0 : xA0;  P0.u[3] = h ? D0 : xB0;
      P1.u[0] = h ? xC1 : A1;  P1.u[1] = h ? xD1 : B1;
      P1.u[2] = h ? C1 : xA1;  P1.u[3] = h ? D1 : xB1;

      __builtin_amdgcn_s_setprio(1);
      o0 = __builtin_amdgcn_mfma_f32_32x32x16_bf16(v00, P0.v, o0, 0, 0, 0);
      o0 = __builtin_amdgcn_mfma_f32_32x32x16_bf16(v01, P1.v, o0, 0, 0, 0);
      o1 = __builtin_amdgcn_mfma_f32_32x32x16_bf16(v10, P0.v, o1, 0, 0, 0);
      o1 = __builtin_amdgcn_mfma_f32_32x32x16_bf16(v11, P1.v, o1, 0, 0, 0);
      __builtin_amdgcn_s_setprio(0);
    }
  }

  float* ot = &Ot[w][0][0];
  float* orow;
  if (z == 0) orow = Ob + ((size_t)h2*S + qbase)*HD;
  else orow = (h2 < 16) ? Ob1a + ((size_t)h2*S + qbase)*HD
                        : Ob1b + ((size_t)(h2 - 16)*S + qbase)*HD;
#pragma unroll
  for (int r = 0; r < 16; ++r) {
    int dl = (r & 3) + ((r >> 2) << 3) + (h << 2);
    ot[ql*36 + dl] = o0[r];
  }
#pragma unroll
  for (int it = 0; it < 4; ++it) {
    int idx = lane + (it << 6);
    int row = idx >> 3, c4 = (idx & 7) << 2;
    float4 v = *reinterpret_cast<float4*>(&ot[row*36 + c4]);
    *reinterpret_cast<float4*>(&orow[(size_t)row*HD + c4]) = v;
  }
#pragma unroll
  for (int r = 0; r < 16; ++r) {
    int dl = (r & 3) + ((r >> 2) << 3) + (h << 2);
    ot[ql*36 + dl] = o1[r];
  }
#pragma unroll
  for (int it = 0; it < 4; ++it) {
    int idx = lane + (it << 6);
    int row = idx >> 3, c4 = (idx & 7) << 2;
    float4 v = *reinterpret_cast<float4*>(&ot[row*36 + c4]);
    *reinterpret_cast<float4*>(&orow[(size_t)row*HD + 32 + c4]) = v;
  }
  if (lane < 32) {
    if (z == 0) { rowm[h2*S + qbase + lane] = m; rowl[h2*S + qbase + lane] = l; }
    else        { rm1[h2*S + qbase + lane] = m;  rl1[h2*S + qbase + lane] = l; }
  }
}

// -- merge partial (m,l) -> merged rowm/rowl + weights a0,a1; block0: lambda --
__global__ __launch_bounds__(256) void merge_ml(float* __restrict__ rowm,
    float* __restrict__ rowl, float* __restrict__ rm1, float* __restrict__ rl1,
    const float* __restrict__ lq1, const float* __restrict__ lk1,
    const float* __restrict__ lq2, const float* __restrict__ lk2,
    float* __restrict__ lamp) {
  const int gid = blockIdx.x * 256 + threadIdx.x;   // over H2N*S
  float m0 = rowm[gid], l0 = rowl[gid], m1 = rm1[gid], l1 = rl1[gid];
  float m = fmaxf(m0, m1);
  float w0 = __expf(m0 - m), w1 = __expf(m1 - m);
  float L = l0*w0 + l1*w1;
  float linv = 1.0f / L;
  rowm[gid] = m; rowl[gid] = L;
  rm1[gid] = w0 * linv; rl1[gid] = w1 * linv;
  if (blockIdx.x == 0 && threadIdx.x < 32) {
    int t = threadIdx.x;
    float a = lq1[t]*lk1[t];
    float b = lq2[t]*lk2[t];
#pragma unroll
    for (int mm = 1; mm < 32; mm <<= 1) { a += __shfl_xor(a, mm, 32); b += __shfl_xor(b, mm, 32); }
    if (t == 0) lamp[0] = expf(a) - expf(b) + 0.2f;
  }
}

// ---------------- colsum via MFMA (bf16 inputs) ----------------
__global__ __launch_bounds__(256) void colsum_mfma(const short* __restrict__ Qb,
    const short* __restrict__ Kb, const float* __restrict__ rowm,
    const float* __restrict__ rowl, float* __restrict__ gcol) {
  const int jt = blockIdx.x;
  const int hh = blockIdx.y, h2 = hh << 1;
  const int cK = jt / 12, jr32 = jt % 12;
  const int jr = jr32 << 5;
  const int j0 = cK*SPP + jr;
  const int tid = threadIdx.x;
  const int w = tid >> 6, lane = tid & 63;
  const int ql = lane & 31, h = lane >> 5;

  bf16x8 kf0, kf1, kf2;
  {
    const short* kp = Kb + ((size_t)h2*S + j0 + ql)*DQK + (h << 3);
    kf0 = *reinterpret_cast<const bf16x8*>(kp);
    kf1 = *reinterpret_cast<const bf16x8*>(kp + 16);
    kf2 = *reinterpret_cast<const bf16x8*>(kp + 32);
  }
  const int nt = 12 - jr32;
  const int T = nt << 2;
  float gs[16];
#pragma unroll
  for (int r = 0; r < 16; ++r) gs[r] = 0.f;

  for (int tt = w; tt < T; tt += 4) {
    int cq = tt / nt, qrem = tt - cq*nt;
    int qi = jr32 + qrem;
    int i0 = cq*SPP + (qi << 5);
    const bool diag = (qrem == 0);
    const short* qp = Qb + ((size_t)h2*S + i0 + ql)*DQK + (h << 3);
    bf16x8 qf0 = *reinterpret_cast<const bf16x8*>(qp);
    bf16x8 qf1 = *reinterpret_cast<const bf16x8*>(qp + 16);
    bf16x8 qf2 = *reinterpret_cast<const bf16x8*>(qp + 32);
    f32x16 st;
#pragma unroll
    for (int r = 0; r < 16; ++r) st[r] = 0.f;
    __builtin_amdgcn_s_setprio(1);
    st = __builtin_amdgcn_mfma_f32_32x32x16_bf16(kf0, qf0, st, 0, 0, 0);
    st = __builtin_amdgcn_mfma_f32_32x32x16_bf16(kf1, qf1, st, 0, 0, 0);
    st = __builtin_amdgcn_mfma_f32_32x32x16_bf16(kf2, qf2, st, 0, 0, 0);
    __builtin_amdgcn_s_setprio(0);
    float Mq = rowm[h2*S + i0 + ql];
    float Lq = 1.0f / rowl[h2*S + i0 + ql];
    if (diag) {
#pragma unroll
      for (int r = 0; r < 16; ++r) {
        int kl = (r & 3) + ((r >> 2) << 3) + (h << 2);
        if (kl <= ql) gs[r] += __expf(st[r]*SCALING - Mq) * Lq;
      }
    } else {
#pragma unroll
      for (int r = 0; r < 16; ++r) gs[r] += __expf(st[r]*SCALING - Mq) * Lq;
    }
  }
  __shared__ float gw[4][32];
#pragma unroll
  for (int r = 0; r < 16; ++r) {
    float v = gs[r];
#pragma unroll
    for (int mm = 1; mm < 32; mm <<= 1) v += __shfl_xor(v, mm, 32);
    if (ql == 0) gw[w][(r & 3) + ((r >> 2) << 3) + (h << 2)] = v;
  }
  __syncthreads();
  if (tid < 32) {
    float s = gw[0][tid] + gw[1][tid] + gw[2][tid] + gw[3][tid];
    gcol[hh*S + j0 + tid] = s * (1.0f / (float)S);
  }
}

// -- wpre_cvt: blocks 0..63 build_wpre; 64..4671 cvt(ffiw,ow) -> ffiw_bf -----
__global__ __launch_bounds__(256) void wpre_cvt(const float* __restrict__ gcol,
    const float* __restrict__ kvb, float* __restrict__ Wpre,
    const float* __restrict__ ffiw, const float* __restrict__ ow,
    short* __restrict__ ffiw_bf) {
  const int bx = blockIdx.x;
  if (bx >= 64) {
    long base = (long)(bx - 64) * 2048 + (long)threadIdx.x * 8;
    const float* src; long off;
    if (base < 8388608L) { src = ffiw; off = base; }
    else { src = ow; off = base - 8388608L; }
    float4 a = *reinterpret_cast<const float4*>(src + off);
    float4 b = *reinterpret_cast<const float4*>(src + off + 4);
    *reinterpret_cast<bf16x8*>(ffiw_bf + base) = cvt8(a, b);
    return;
  }
  const int hh = bx >> 2;
  const int dq = (bx & 3) << 4;
  __shared__ float Wt[SPP][16];
  const int tid = threadIdx.x;
  for (int idx = tid; idx < SPP*16; idx += 256) {
    int r = idx >> 4, dd = idx & 15;
    float val = 0.f;
#pragma unroll
    for (int b2 = 0; b2 < 4; ++b2) {
      int j = b2*SPP + r;
      val = fmaf(gcol[hh*S + j], kvb[(size_t)j*2048 + hh*128 + 64 + dq + dd], val);
    }
    Wt[r][dd] = val;
  }
  __syncthreads();
  if (tid < 16) {
    float run = 0.f;
    for (int r = 0; r < SPP; ++r) { run += Wt[r][tid]; Wt[r][tid] = run; }
  }
  __syncthreads();
  for (int idx = tid; idx < SPP*16; idx += 256) {
    int r = idx >> 4, dd = idx & 15;
    Wpre[((size_t)hh*SPP + r)*HD + dq + dd] = Wt[r][dd];
  }
}

// -- combine: merge O partials inline + diff-attn + RMSNorm + reshape -> bf16 --
__global__ __launch_bounds__(256) void combine_rms(const float* __restrict__ Ob,
    const float* __restrict__ Ob1a, const float* __restrict__ Ob1b,
    const float* __restrict__ a0v, const float* __restrict__ a1v,
    const float* __restrict__ Wpre, const float* __restrict__ lamp,
    const float* __restrict__ anw, short* __restrict__ attno) {
  const int t = blockIdx.x * 4 + (threadIdx.x >> 6);
  const int h = blockIdx.y;
  const int d = threadIdx.x & 63;
  const float lam = lamp[0];
  const int g1 = (2*h)*S + t, g2 = (2*h+1)*S + t;
  const float* p1 = (h < 8) ? (Ob1a + (size_t)g1*HD) : (Ob1b + ((size_t)g1 - (size_t)16*S)*HD);
  const float* p2 = (h < 8) ? (Ob1a + (size_t)g2*HD) : (Ob1b + ((size_t)g2 - (size_t)16*S)*HD);
  float o1 = Ob[(size_t)g1*HD + d] * a0v[g1] + p1[d] * a1v[g1];
  float o2 = Ob[(size_t)g2*HD + d] * a0v[g2] + p2[d] * a1v[g2];
  const float w3 = Wpre[((size_t)h*SPP + (t % SPP))*HD + d];
  float val = o1 - lam*o2 + lam*w3;
  float ss = val*val;
#pragma unroll
  for (int mm = 1; mm < 64; mm <<= 1) ss += __shfl_xor(ss, mm, 64);
  float scale = rsqrtf(ss * (1.0f/HD) + ATTN_EPS) * anw[d];
  int tn = h*96 + (t >> 4);
  int cn = ((t & 15) << 6) + d;
  attno[(size_t)tn*DM + cn] = cvt_bf16(val * scale);
}

// =========================== launch ===========================
extern "C" void kernel_launch(void* const* d_in, const int* in_sizes, int n_in,
                              void* d_out, int out_size, void* d_ws, size_t ws_size,
                              hipStream_t stream) {
  (void)in_sizes; (void)n_in; (void)out_size;
  const float* x    = (const float*)d_in[0];
  const float* fc   = (const float*)d_in[1];
  const float* fs   = (const float*)d_in[2];
  const float* n1w  = (const float*)d_in[3];
  const float* n2w  = (const float*)d_in[4];
  const float* kvdw = (const float*)d_in[5];
  const float* qdw  = (const float*)d_in[6];
  const float* kvnw = (const float*)d_in[7];
  const float* qnw  = (const float*)d_in[8];
  const float* kvuw = (const float*)d_in[9];
  const float* quw  = (const float*)d_in[10];
  const float* lq1  = (const float*)d_in[11];
  const float* lk1  = (const float*)d_in[12];
  const float* lq2  = (const float*)d_in[13];
  const float* lk2  = (const float*)d_in[14];
  const float* anw  = (const float*)d_in[15];
  const float* ow   = (const float*)d_in[16];
  const float* ffiw = (const float*)d_in[17];
  const float* ffow = (const float*)d_in[18];
  float* out = (float*)d_out;
  float* ws  = (float*)d_ws;

  float* xin   = ws;
  float* ckv   = xin   + (size_t)S*DM;        // fused [S][672] down-proj output
  float* qmid  = ckv   + (size_t)S*288;
  float* kvb   = qmid  + (size_t)S*QC;
  float* qf    = kvb   + (size_t)S*2048;
  float* Qb    = qf    + (size_t)S*1536;
  float* Kb    = Qb    + (size_t)H2N*S*DQK;
  float* Obuf  = Kb    + (size_t)H2N*S*DQK;
  float* rowm  = Obuf  + (size_t)H2N*S*HD;
  float* rowl  = rowm  + (size_t)H2N*S;
  float* gcol  = rowl  + (size_t)H2N*S;
  float* Wpre  = gcol  + (size_t)NH*S;
  float* attno = Wpre  + (size_t)NH*SPP*HD;
  float* lamp  = attno + (size_t)S*DM;
  short* fbufs = (short*)kvb;     // bf16 FFN activation overlays kv region
  float* Ob1a = xin;
  float* Ob1b = qf;
  float* rm1  = qf + (size_t)16*S*HD;
  float* rl1  = rm1 + (size_t)H2N*S;
  short* Qb_bf = (short*)Qb;
  short* Kb_bf = (short*)Kb;
  short* Vt_bf = (short*)Qb + 2359296;
  short* xin_bf  = (short*)xin;
  short* ckv_bf  = (short*)Obuf;
  short* qmid_bf = ckv_bf + (size_t)S*KVC;
  short* h_bf    = (short*)ckv;   // rmsnorm2 out: fused-buffer region (dead by then)
  short* attno_bf = (short*)attno;
  short* kvdw_bf = (short*)attno;
  short* qdw_bf  = kvdw_bf + 294912;        // contiguous: fused B (672x1024)
  short* kvuw_bf = qdw_bf  + 393216;
  short* quw_bf  = kvuw_bf + 524288;
  short* ffiw_bf = (short*)Qb;
  short* ow_bf   = ffiw_bf + 8388608;
  short* ffow_bf = (short*)Obuf;
  float* psum0 = xin;             // split-K partials: dead windows at call sites
  float* psum1 = qf;
  if (ws_size < (size_t)18063376 * sizeof(float)) return;

  rms1_cvt<<<S + 880, 256, 0, stream>>>(x, n1w, xin_bf,
      kvdw, 294912, qdw, 393216, kvuw, 524288, quw, kvdw_bf);
  { dim3 g(11, 24); mgemm_nt<0><<<g, 256, 0, stream>>>(xin_bf, kvdw_bf, nullptr, ckv, S, CKW, DM, DM, DM, CKW); }
  { dim3 g(S, 2);   rmsnorm2_bf<<<g, 256, 0, stream>>>(ckv, kvnw, qnw, ckv_bf, qmid_bf, EPS_RMS); }
  mgemm_dual<<<1344, 256, 0, stream>>>(ckv_bf, kvuw_bf, kvb, qmid_bf, quw_bf, qf);
  prep_attn<<<384, 256, 0, stream>>>(qf, kvb, ckv, fc, fs, Qb_bf, Kb_bf, Vt_bf);
  { dim3 g(12, 32, 2); flash_mfma<<<g, 256, 0, stream>>>(Qb_bf, Kb_bf, Vt_bf, Obuf, rowm, rowl,
                                                         Ob1a, Ob1b, rm1, rl1); }
  merge_ml<<<(H2N*S)/256, 256, 0, stream>>>(rowm, rowl, rm1, rl1, lq1, lk1, lq2, lk2, lamp);
  { dim3 g(48, 16); colsum_mfma<<<g, 256, 0, stream>>>(Qb_bf, Kb_bf, rowm, rowl, gcol); }
  wpre_cvt<<<64 + 4608, 256, 0, stream>>>(gcol, kvb, Wpre, ffiw, ow, ffiw_bf);
  { dim3 g(S/4, 16); combine_rms<<<g, 256, 0, stream>>>(Obuf, Ob1a, Ob1b, rm1, rl1,
                                                        Wpre, lamp, anw, attno_bf); }
  oproj_cvt<<<768 + 2048, 256, 0, stream>>>(attno_bf, ow_bf, psum0, psum1, ffow, ffow_bf);
  rmsnorm_sum_bf<<<S, 256, 0, stream>>>(psum0, psum1, x, n2w, out, h_bf, EPS_RMS);
  { dim3 g(64, 12); mgemm_glu<<<g, 256, 0, stream>>>(h_bf, ffiw_bf, fbufs, S, DFF, DM, DM, DM, DFF); }
  { dim3 g(16, 24, 2); mgemm_sk<<<g, 256, 0, stream>>>(fbufs, ffow_bf, psum0, psum1, S, DM, 2048, DFF, DFF, DM); }
  fadd2<<<1536, 256, 0, stream>>>(out, psum0, psum1);
}

// Round 19
// 200.899 us; speedup vs baseline: 11.8172x; 1.0087x over previous
//
#include <hip/hip_runtime.h>
#include <math.h>

#define S     1536
#define DM    1024
#define NH    16
#define H2N   32
#define HD    64
#define KVC   256
#define QC    384
#define DFF   4096
#define SPP   384
#define DQK   48
#define CKW   672   /* fused down-proj width: 288 (kv) + 384 (q) */
#define EPS_RMS  1.1920929e-07f
#define ATTN_EPS 1e-5f
#define SCALING  0.14433756729740643f   /* 48^-0.5 */

typedef float f32x4 __attribute__((ext_vector_type(4)));
typedef float f32x16 __attribute__((ext_vector_type(16)));
typedef short bf16x8 __attribute__((ext_vector_type(8)));

__device__ __forceinline__ short cvt_bf16(float f) {
  union { float f; unsigned u; } x; x.f = f;
  unsigned r = x.u + 0x7FFFu + ((x.u >> 16) & 1u);
  return (short)(r >> 16);
}
__device__ __forceinline__ unsigned pk2(float a, float b) { // HW RNE pack
  unsigned r;
  asm("v_cvt_pk_bf16_f32 %0, %1, %2" : "=v"(r) : "v"(a), "v"(b));
  return r;
}
__device__ __forceinline__ bf16x8 cvt8(float4 a, float4 b) {
  union { unsigned u[4]; bf16x8 v; } r;
  r.u[0] = pk2(a.x, a.y); r.u[1] = pk2(a.z, a.w);
  r.u[2] = pk2(b.x, b.y); r.u[3] = pk2(b.z, b.w);
  return r.v;
}
// XCD-aware bijective block swizzle (T1); identity when nwg%8 != 0
__device__ __forceinline__ int swz8(int flat, int nwg) {
  if (nwg & 7) return flat;
  return (flat & 7) * (nwg >> 3) + (flat >> 3);
}

// ---------------- RMSNorm -> bf16 out ----------------
__device__ __forceinline__ void rms_body(const float* xr, const float* w,
    short* yr, int cols, float eps) {
  const int tid = threadIdx.x;
  float ss = 0.f;
  for (int c = tid << 2; c < cols; c += 1024) {
    float4 v = *reinterpret_cast<const float4*>(xr + c);
    ss += v.x*v.x + v.y*v.y + v.z*v.z + v.w*v.w;
  }
#pragma unroll
  for (int mm = 1; mm < 64; mm <<= 1) ss += __shfl_xor(ss, mm, 64);
  __shared__ float red[4];
  if ((tid & 63) == 0) red[tid >> 6] = ss;
  __syncthreads();
  float tot = red[0] + red[1] + red[2] + red[3];
  float scale = rsqrtf(tot / (float)cols + eps);
  for (int c = tid << 2; c < cols; c += 1024) {
    float4 v = *reinterpret_cast<const float4*>(xr + c);
    float4 wv = *reinterpret_cast<const float4*>(w + c);
    uint2 p;
    p.x = pk2(v.x*scale*wv.x, v.y*scale*wv.y);
    p.y = pk2(v.z*scale*wv.z, v.w*scale*wv.w);
    *reinterpret_cast<uint2*>(yr + c) = p;
  }
}

// ---- rms1_cvt: blocks 0..1535 rmsnorm1; 1536..2415 early-weight cvt -------
__global__ __launch_bounds__(256) void rms1_cvt(const float* __restrict__ x,
    const float* __restrict__ n1w, short* __restrict__ xin_bf,
    const float* __restrict__ s0, int n0, const float* __restrict__ s1, int n1,
    const float* __restrict__ s2, int n2, const float* __restrict__ s3,
    short* __restrict__ dst) {
  const int bx = blockIdx.x;
  if (bx < S) {
    rms_body(x + (size_t)bx * DM, n1w, xin_bf + (size_t)bx * DM, DM, EPS_RMS);
  } else {
    long base = (long)(bx - S) * 2048 + (long)threadIdx.x * 8;
    const float* src; long off;
    if (base < n0) { src = s0; off = base; }
    else if (base < (long)n0 + n1) { src = s1; off = base - n0; }
    else if (base < (long)n0 + n1 + n2) { src = s2; off = base - n0 - n1; }
    else { src = s3; off = base - n0 - n1 - n2; }
    float4 a = *reinterpret_cast<const float4*>(src + off);
    float4 b = *reinterpret_cast<const float4*>(src + off + 4);
    *reinterpret_cast<bf16x8*>(dst + base) = cvt8(a, b);
  }
}

// ---- dual RMSNorm over fused [S][672] buffer: y=0 -> kv(256), y=1 -> q(384) --
__global__ __launch_bounds__(256) void rmsnorm2_bf(const float* __restrict__ comb,
    const float* __restrict__ w0, const float* __restrict__ w1,
    short* __restrict__ o0, short* __restrict__ o1, float eps) {
  const int row = blockIdx.x;
  const int seg = blockIdx.y;
  const float* xr = comb + (size_t)row * CKW + (seg ? 288 : 0);
  rms_body(xr, seg ? w1 : w0,
           seg ? (o1 + (size_t)row * QC) : (o0 + (size_t)row * KVC),
           seg ? QC : KVC, eps);
}

// ------ RMSNorm over (p0+p1+xres), writes residual fp32 AND bf16 norm -------
__global__ __launch_bounds__(256) void rmsnorm_sum_bf(const float* __restrict__ p0,
    const float* __restrict__ p1, const float* __restrict__ xres,
    const float* __restrict__ w, float* __restrict__ outw, short* __restrict__ yb,
    float eps) {
  const int row = blockIdx.x;
  const int c = threadIdx.x << 2;
  const size_t base = (size_t)row * DM + c;
  float4 a = *reinterpret_cast<const float4*>(p0 + base);
  float4 b = *reinterpret_cast<const float4*>(p1 + base);
  float4 xv = *reinterpret_cast<const float4*>(xres + base);
  float4 v = make_float4(a.x+b.x+xv.x, a.y+b.y+xv.y, a.z+b.z+xv.z, a.w+b.w+xv.w);
  *reinterpret_cast<float4*>(outw + base) = v;
  float ss = v.x*v.x + v.y*v.y + v.z*v.z + v.w*v.w;
#pragma unroll
  for (int mm = 1; mm < 64; mm <<= 1) ss += __shfl_xor(ss, mm, 64);
  __shared__ float red[4];
  if ((threadIdx.x & 63) == 0) red[threadIdx.x >> 6] = ss;
  __syncthreads();
  float tot = red[0] + red[1] + red[2] + red[3];
  float scale = rsqrtf(tot * (1.0f / (float)DM) + eps);
  float4 wv = *reinterpret_cast<const float4*>(w + c);
  uint2 p;
  p.x = pk2(v.x*scale*wv.x, v.y*scale*wv.y);
  p.y = pk2(v.z*scale*wv.z, v.w*scale*wv.w);
  *reinterpret_cast<uint2*>(yb + base) = p;
}

// ---------------- out += p0 + p1 (grid: S*DM/1024) ----------------
__global__ __launch_bounds__(256) void fadd2(float* __restrict__ out,
    const float* __restrict__ p0, const float* __restrict__ p1) {
  size_t i = ((size_t)blockIdx.x * 256 + threadIdx.x) << 2;
  float4 o = *reinterpret_cast<float4*>(out + i);
  float4 a = *reinterpret_cast<const float4*>(p0 + i);
  float4 b = *reinterpret_cast<const float4*>(p1 + i);
  o.x += a.x + b.x; o.y += a.y + b.y; o.z += a.z + b.z; o.w += a.w + b.w;
  *reinterpret_cast<float4*>(out + i) = o;
}

// ------------- bf16 MFMA GEMM, BK=64, register-prefetch; A,B bf16 ----------
template<int ADD>
__global__ __launch_bounds__(256) void mgemm_nt(const short* __restrict__ A,
    const short* __restrict__ B, const float* __restrict__ src, float* __restrict__ C,
    int M, int N, int K, int lda, int ldb, int ldc) {
  __shared__ short As[64][72];
  __shared__ short Bs[64][72];
  const int nwg = gridDim.x * gridDim.y;
  const int sfl = swz8(blockIdx.y * gridDim.x + blockIdx.x, nwg);
  const int bxs = sfl % gridDim.x, bys = sfl / gridDim.x;
  const int bm = bys * 64, bn = bxs * 64;
  const int tid = threadIdx.x;
  const int w = tid >> 6, lane = tid & 63;
  const int wr = (w >> 1) << 5, wc = (w & 1) << 5;
  const int srow = tid >> 2, sk = (tid & 3) << 4;
  const int lrow = lane & 15, lk8 = (lane >> 4) << 3;
  const int arow = bm + srow, brow = bn + srow;
  const bool bvalid = brow < N;
  f32x4 acc[2][2];
#pragma unroll
  for (int i = 0; i < 2; ++i)
#pragma unroll
    for (int j = 0; j < 2; ++j) acc[i][j] = (f32x4){0.f, 0.f, 0.f, 0.f};

  bf16x8 rah0, rah1, rbh0, rbh1;
  {
    const short* ap = A + (size_t)arow * lda + sk;
    rah0 = *reinterpret_cast<const bf16x8*>(ap);
    rah1 = *reinterpret_cast<const bf16x8*>(ap + 8);
  }
  rbh0 = (bf16x8){0,0,0,0,0,0,0,0}; rbh1 = rbh0;
  if (bvalid) {
    const short* bp = B + (size_t)brow * ldb + sk;
    rbh0 = *reinterpret_cast<const bf16x8*>(bp);
    rbh1 = *reinterpret_cast<const bf16x8*>(bp + 8);
  }

  for (int k0 = 0; k0 < K; k0 += 64) {
    bf16x8 va0 = rah0, va1 = rah1, vb0 = rbh0, vb1 = rbh1;
    __syncthreads();
    *reinterpret_cast<bf16x8*>(&As[srow][sk])     = va0;
    *reinterpret_cast<bf16x8*>(&As[srow][sk + 8]) = va1;
    *reinterpret_cast<bf16x8*>(&Bs[srow][sk])     = vb0;
    *reinterpret_cast<bf16x8*>(&Bs[srow][sk + 8]) = vb1;
    __syncthreads();
    const int kn = k0 + 64;
    if (kn < K) {
      const short* ap = A + (size_t)arow * lda + kn + sk;
      rah0 = *reinterpret_cast<const bf16x8*>(ap);
      rah1 = *reinterpret_cast<const bf16x8*>(ap + 8);
      if (bvalid) {
        const short* bp = B + (size_t)brow * ldb + kn + sk;
        rbh0 = *reinterpret_cast<const bf16x8*>(bp);
        rbh1 = *reinterpret_cast<const bf16x8*>(bp + 8);
      }
    }
#pragma unroll
    for (int kk = 0; kk < 2; ++kk) {
      bf16x8 af0 = *reinterpret_cast<bf16x8*>(&As[wr + lrow][(kk << 5) + lk8]);
      bf16x8 af1 = *reinterpret_cast<bf16x8*>(&As[wr + 16 + lrow][(kk << 5) + lk8]);
      bf16x8 bf0 = *reinterpret_cast<bf16x8*>(&Bs[wc + lrow][(kk << 5) + lk8]);
      bf16x8 bf1 = *reinterpret_cast<bf16x8*>(&Bs[wc + 16 + lrow][(kk << 5) + lk8]);
      acc[0][0] = __builtin_amdgcn_mfma_f32_16x16x32_bf16(af0, bf0, acc[0][0], 0, 0, 0);
      acc[0][1] = __builtin_amdgcn_mfma_f32_16x16x32_bf16(af0, bf1, acc[0][1], 0, 0, 0);
      acc[1][0] = __builtin_amdgcn_mfma_f32_16x16x32_bf16(af1, bf0, acc[1][0], 0, 0, 0);
      acc[1][1] = __builtin_amdgcn_mfma_f32_16x16x32_bf16(af1, bf1, acc[1][1], 0, 0, 0);
    }
  }
  const int crow0 = bm + wr + ((lane >> 4) << 2);
  const int ccol0 = bn + wc + lrow;
#pragma unroll
  for (int mi = 0; mi < 2; ++mi)
#pragma unroll
    for (int ni = 0; ni < 2; ++ni) {
      int colc = ccol0 + (ni << 4);
      if (colc < N) {
#pragma unroll
        for (int r = 0; r < 4; ++r) {
          int rowc = crow0 + (mi << 4) + r;
          float v = acc[mi][ni][r];
          if (ADD) v += src[(size_t)rowc * ldc + colc];
          C[(size_t)rowc * ldc + colc] = v;
        }
      }
    }
}

// ------ dual GEMM: kv_up (768 tiles) + q_up (576 tiles) in one launch -------
__global__ __launch_bounds__(256) void mgemm_dual(const short* __restrict__ A0,
    const short* __restrict__ B0, float* __restrict__ C0,
    const short* __restrict__ A1, const short* __restrict__ B1, float* __restrict__ C1) {
  __shared__ short As[64][72];
  __shared__ short Bs[64][72];
  const int flat = blockIdx.x;
  const short *A, *B; float* C;
  int K, lda, ldb, ldc, bm, bn;
  if (flat < 768) {
    const int sfl = swz8(flat, 768);
    bm = (sfl / 32) * 64; bn = (sfl % 32) * 64;
    A = A0; B = B0; C = C0; K = KVC; lda = KVC; ldb = KVC; ldc = 2048;
  } else {
    const int sfl = swz8(flat - 768, 576);
    bm = (sfl / 24) * 64; bn = (sfl % 24) * 64;
    A = A1; B = B1; C = C1; K = QC; lda = QC; ldb = QC; ldc = 1536;
  }
  const int tid = threadIdx.x;
  const int w = tid >> 6, lane = tid & 63;
  const int wr = (w >> 1) << 5, wc = (w & 1) << 5;
  const int srow = tid >> 2, sk = (tid & 3) << 4;
  const int lrow = lane & 15, lk8 = (lane >> 4) << 3;
  const int arow = bm + srow, brow = bn + srow;
  f32x4 acc[2][2];
#pragma unroll
  for (int i = 0; i < 2; ++i)
#pragma unroll
    for (int j = 0; j < 2; ++j) acc[i][j] = (f32x4){0.f, 0.f, 0.f, 0.f};

  bf16x8 rah0, rah1, rbh0, rbh1;
  {
    const short* ap = A + (size_t)arow * lda + sk;
    rah0 = *reinterpret_cast<const bf16x8*>(ap);
    rah1 = *reinterpret_cast<const bf16x8*>(ap + 8);
    const short* bp = B + (size_t)brow * ldb + sk;
    rbh0 = *reinterpret_cast<const bf16x8*>(bp);
    rbh1 = *reinterpret_cast<const bf16x8*>(bp + 8);
  }
  for (int k0 = 0; k0 < K; k0 += 64) {
    bf16x8 va0 = rah0, va1 = rah1, vb0 = rbh0, vb1 = rbh1;
    __syncthreads();
    *reinterpret_cast<bf16x8*>(&As[srow][sk])     = va0;
    *reinterpret_cast<bf16x8*>(&As[srow][sk + 8]) = va1;
    *reinterpret_cast<bf16x8*>(&Bs[srow][sk])     = vb0;
    *reinterpret_cast<bf16x8*>(&Bs[srow][sk + 8]) = vb1;
    __syncthreads();
    const int kn = k0 + 64;
    if (kn < K) {
      const short* ap = A + (size_t)arow * lda + kn + sk;
      rah0 = *reinterpret_cast<const bf16x8*>(ap);
      rah1 = *reinterpret_cast<const bf16x8*>(ap + 8);
      const short* bp = B + (size_t)brow * ldb + kn + sk;
      rbh0 = *reinterpret_cast<const bf16x8*>(bp);
      rbh1 = *reinterpret_cast<const bf16x8*>(bp + 8);
    }
#pragma unroll
    for (int kk = 0; kk < 2; ++kk) {
      bf16x8 af0 = *reinterpret_cast<bf16x8*>(&As[wr + lrow][(kk << 5) + lk8]);
      bf16x8 af1 = *reinterpret_cast<bf16x8*>(&As[wr + 16 + lrow][(kk << 5) + lk8]);
      bf16x8 bf0 = *reinterpret_cast<bf16x8*>(&Bs[wc + lrow][(kk << 5) + lk8]);
      bf16x8 bf1 = *reinterpret_cast<bf16x8*>(&Bs[wc + 16 + lrow][(kk << 5) + lk8]);
      acc[0][0] = __builtin_amdgcn_mfma_f32_16x16x32_bf16(af0, bf0, acc[0][0], 0, 0, 0);
      acc[0][1] = __builtin_amdgcn_mfma_f32_16x16x32_bf16(af0, bf1, acc[0][1], 0, 0, 0);
      acc[1][0] = __builtin_amdgcn_mfma_f32_16x16x32_bf16(af1, bf0, acc[1][0], 0, 0, 0);
      acc[1][1] = __builtin_amdgcn_mfma_f32_16x16x32_bf16(af1, bf1, acc[1][1], 0, 0, 0);
    }
  }
  const int crow0 = bm + wr + ((lane >> 4) << 2);
  const int ccol0 = bn + wc + lrow;
#pragma unroll
  for (int mi = 0; mi < 2; ++mi)
#pragma unroll
    for (int ni = 0; ni < 2; ++ni) {
      int colc = ccol0 + (ni << 4);
#pragma unroll
      for (int r = 0; r < 4; ++r) {
        int rowc = crow0 + (mi << 4) + r;
        C[(size_t)rowc * ldc + colc] = acc[mi][ni][r];
      }
    }
}

// ---- split-K=2 GEMM body (bm,bn,koff given) -> fp32 partial ----
__device__ __forceinline__ void sk_body(const short* __restrict__ A,
    const short* __restrict__ B, float* __restrict__ C,
    int bm, int bn, int koff, int K2, int lda, int ldb, int ldc) {
  __shared__ short As[64][72];
  __shared__ short Bs[64][72];
  const int tid = threadIdx.x;
  const int w = tid >> 6, lane = tid & 63;
  const int wr = (w >> 1) << 5, wc = (w & 1) << 5;
  const int srow = tid >> 2, sk = (tid & 3) << 4;
  const int lrow = lane & 15, lk8 = (lane >> 4) << 3;
  const int arow = bm + srow, brow = bn + srow;
  f32x4 acc[2][2];
#pragma unroll
  for (int i = 0; i < 2; ++i)
#pragma unroll
    for (int j = 0; j < 2; ++j) acc[i][j] = (f32x4){0.f, 0.f, 0.f, 0.f};

  bf16x8 rah0, rah1, rbh0, rbh1;
  {
    const short* ap = A + (size_t)arow * lda + koff + sk;
    rah0 = *reinterpret_cast<const bf16x8*>(ap);
    rah1 = *reinterpret_cast<const bf16x8*>(ap + 8);
    const short* bp = B + (size_t)brow * ldb + koff + sk;
    rbh0 = *reinterpret_cast<const bf16x8*>(bp);
    rbh1 = *reinterpret_cast<const bf16x8*>(bp + 8);
  }
  const int kend = koff + K2;
  for (int k0 = koff; k0 < kend; k0 += 64) {
    bf16x8 va0 = rah0, va1 = rah1, vb0 = rbh0, vb1 = rbh1;
    __syncthreads();
    *reinterpret_cast<bf16x8*>(&As[srow][sk])     = va0;
    *reinterpret_cast<bf16x8*>(&As[srow][sk + 8]) = va1;
    *reinterpret_cast<bf16x8*>(&Bs[srow][sk])     = vb0;
    *reinterpret_cast<bf16x8*>(&Bs[srow][sk + 8]) = vb1;
    __syncthreads();
    const int kn = k0 + 64;
    if (kn < kend) {
      const short* ap = A + (size_t)arow * lda + kn + sk;
      rah0 = *reinterpret_cast<const bf16x8*>(ap);
      rah1 = *reinterpret_cast<const bf16x8*>(ap + 8);
      const short* bp = B + (size_t)brow * ldb + kn + sk;
      rbh0 = *reinterpret_cast<const bf16x8*>(bp);
      rbh1 = *reinterpret_cast<const bf16x8*>(bp + 8);
    }
#pragma unroll
    for (int kk = 0; kk < 2; ++kk) {
      bf16x8 af0 = *reinterpret_cast<bf16x8*>(&As[wr + lrow][(kk << 5) + lk8]);
      bf16x8 af1 = *reinterpret_cast<bf16x8*>(&As[wr + 16 + lrow][(kk << 5) + lk8]);
      bf16x8 bf0 = *reinterpret_cast<bf16x8*>(&Bs[wc + lrow][(kk << 5) + lk8]);
      bf16x8 bf1 = *reinterpret_cast<bf16x8*>(&Bs[wc + 16 + lrow][(kk << 5) + lk8]);
      acc[0][0] = __builtin_amdgcn_mfma_f32_16x16x32_bf16(af0, bf0, acc[0][0], 0, 0, 0);
      acc[0][1] = __builtin_amdgcn_mfma_f32_16x16x32_bf16(af0, bf1, acc[0][1], 0, 0, 0);
      acc[1][0] = __builtin_amdgcn_mfma_f32_16x16x32_bf16(af1, bf0, acc[1][0], 0, 0, 0);
      acc[1][1] = __builtin_amdgcn_mfma_f32_16x16x32_bf16(af1, bf1, acc[1][1], 0, 0, 0);
    }
  }
  const int crow0 = bm + wr + ((lane >> 4) << 2);
  const int ccol0 = bn + wc + lrow;
#pragma unroll
  for (int mi = 0; mi < 2; ++mi)
#pragma unroll
    for (int ni = 0; ni < 2; ++ni) {
      int colc = ccol0 + (ni << 4);
#pragma unroll
      for (int r = 0; r < 4; ++r) {
        int rowc = crow0 + (mi << 4) + r;
        C[(size_t)rowc * ldc + colc] = acc[mi][ni][r];
      }
    }
}

// ------- split-K=2 bf16 GEMM (ff_out): z-half of K -> fp32 partial ----------
__global__ __launch_bounds__(256) void mgemm_sk(const short* __restrict__ A,
    const short* __restrict__ B, float* __restrict__ P0, float* __restrict__ P1,
    int M, int N, int K2, int lda, int ldb, int ldc) {
  const int nwg = gridDim.x * gridDim.y;
  const int sfl = swz8(blockIdx.y * gridDim.x + blockIdx.x, nwg);
  sk_body(A, B, blockIdx.z ? P1 : P0, (sfl / gridDim.x) * 64,
          (sfl % gridDim.x) * 64, blockIdx.z * K2, K2, lda, ldb, ldc);
}

// -- oproj_cvt: blocks 0..767 o-proj split-K; 768..2815 ffow cvt ------------
__global__ __launch_bounds__(256) void oproj_cvt(const short* __restrict__ A,
    const short* __restrict__ B, float* __restrict__ P0, float* __restrict__ P1,
    const float* __restrict__ ffow, short* __restrict__ ffow_bf) {
  const int bx = blockIdx.x;
  if (bx < 768) {
    const int z = bx >= 384;
    const int sfl = swz8(bx - (z ? 384 : 0), 384);
    sk_body(A, B, z ? P1 : P0, (sfl / 16) * 64, (sfl % 16) * 64,
            z * 512, 512, DM, DM, DM);
  } else {
    long base = (long)(bx - 768) * 2048 + (long)threadIdx.x * 8;
    float4 a = *reinterpret_cast<const float4*>(ffow + base);
    float4 b = *reinterpret_cast<const float4*>(ffow + base + 4);
    *reinterpret_cast<bf16x8*>(ffow_bf + base) = cvt8(a, b);
  }
}

// ------- 128(M)x64(N) bf16 SwiGLU GEMM: 4 waves, per-wave 64x32 u AND v -----
__global__ __launch_bounds__(256) void mgemm_glu(const short* __restrict__ A,
    const short* __restrict__ Bw, short* __restrict__ C,
    int M, int N, int K, int lda, int ldb, int ldc) {
  __shared__ short As[128][72];
  __shared__ short Bu[64][72];
  __shared__ short Bv[64][72];
  const int nwg = gridDim.x * gridDim.y;
  const int sfl = swz8(blockIdx.y * gridDim.x + blockIdx.x, nwg);
  const int bxs = sfl % gridDim.x, bys = sfl / gridDim.x;
  const int bm = bys * 128, bn = bxs * 64;
  const int tid = threadIdx.x;
  const int w = tid >> 6, lane = tid & 63;
  const int wr = (w >> 1) << 6, wc = (w & 1) << 5;
  const int arow = bm + (tid >> 1), ac = (tid & 1) << 5;
  const int brow = bn + (tid >> 2), bc = (tid & 3) << 4;
  const int lrow = lane & 15, lk8 = (lane >> 4) << 3;
  f32x4 au[4][2], av[4][2];
#pragma unroll
  for (int i = 0; i < 4; ++i)
#pragma unroll
    for (int j = 0; j < 2; ++j) {
      au[i][j] = (f32x4){0.f, 0.f, 0.f, 0.f};
      av[i][j] = (f32x4){0.f, 0.f, 0.f, 0.f};
    }
  bf16x8 ra[4], ru[2], rv[2];
  {
    const short* ap = A + (size_t)arow * lda + ac;
    const short* up = Bw + (size_t)brow * ldb + bc;
    const short* vp = Bw + (size_t)(N + brow) * ldb + bc;
#pragma unroll
    for (int e = 0; e < 4; ++e) ra[e] = *reinterpret_cast<const bf16x8*>(ap + (e << 3));
    ru[0] = *reinterpret_cast<const bf16x8*>(up);
    ru[1] = *reinterpret_cast<const bf16x8*>(up + 8);
    rv[0] = *reinterpret_cast<const bf16x8*>(vp);
    rv[1] = *reinterpret_cast<const bf16x8*>(vp + 8);
  }
  for (int k0 = 0; k0 < K; k0 += 64) {
    __syncthreads();
#pragma unroll
    for (int e = 0; e < 4; ++e)
      *reinterpret_cast<bf16x8*>(&As[tid >> 1][ac + (e << 3)]) = ra[e];
    *reinterpret_cast<bf16x8*>(&Bu[tid >> 2][bc])     = ru[0];
    *reinterpret_cast<bf16x8*>(&Bu[tid >> 2][bc + 8]) = ru[1];
    *reinterpret_cast<bf16x8*>(&Bv[tid >> 2][bc])     = rv[0];
    *reinterpret_cast<bf16x8*>(&Bv[tid >> 2][bc + 8]) = rv[1];
    __syncthreads();
    const int kn = k0 + 64;
    if (kn < K) {
      const short* ap = A + (size_t)arow * lda + kn + ac;
      const short* up = Bw + (size_t)brow * ldb + kn + bc;
      const short* vp = Bw + (size_t)(N + brow) * ldb + kn + bc;
#pragma unroll
      for (int e = 0; e < 4; ++e) ra[e] = *reinterpret_cast<const bf16x8*>(ap + (e << 3));
      ru[0] = *reinterpret_cast<const bf16x8*>(up);
      ru[1] = *reinterpret_cast<const bf16x8*>(up + 8);
      rv[0] = *reinterpret_cast<const bf16x8*>(vp);
      rv[1] = *reinterpret_cast<const bf16x8*>(vp + 8);
    }
#pragma unroll
    for (int kk = 0; kk < 2; ++kk) {
      bf16x8 af[4], uf[2], vf[2];
#pragma unroll
      for (int i = 0; i < 4; ++i)
        af[i] = *reinterpret_cast<bf16x8*>(&As[wr + (i << 4) + lrow][(kk << 5) + lk8]);
#pragma unroll
      for (int j = 0; j < 2; ++j) {
        uf[j] = *reinterpret_cast<bf16x8*>(&Bu[wc + (j << 4) + lrow][(kk << 5) + lk8]);
        vf[j] = *reinterpret_cast<bf16x8*>(&Bv[wc + (j << 4) + lrow][(kk << 5) + lk8]);
      }
      __builtin_amdgcn_s_setprio(1);
#pragma unroll
      for (int i = 0; i < 4; ++i)
#pragma unroll
        for (int j = 0; j < 2; ++j) {
          au[i][j] = __builtin_amdgcn_mfma_f32_16x16x32_bf16(af[i], uf[j], au[i][j], 0, 0, 0);
          av[i][j] = __builtin_amdgcn_mfma_f32_16x16x32_bf16(af[i], vf[j], av[i][j], 0, 0, 0);
        }
      __builtin_amdgcn_s_setprio(0);
    }
  }
  const int crow0 = bm + wr + ((lane >> 4) << 2);
  const int ccol0 = bn + wc + lrow;
#pragma unroll
  for (int mi = 0; mi < 4; ++mi)
#pragma unroll
    for (int ni = 0; ni < 2; ++ni) {
      int colc = ccol0 + (ni << 4);
#pragma unroll
      for (int r = 0; r < 4; ++r) {
        int rowc = crow0 + (mi << 4) + r;
        float uu = au[mi][ni][r], vg = av[mi][ni][r];
        float sig = 1.0f / (1.0f + __expf(-vg));
        C[(size_t)rowc * ldc + colc] = cvt_bf16(uu * vg * sig);
      }
    }
}

// -------- prep_attn: build_qk (0..191, Q pre-scaled) + V transpose (192..383)
// ------------------- + lambda (block 384) ----------------------------------
__global__ __launch_bounds__(256) void prep_attn(const float* __restrict__ qf,
    const float* __restrict__ kvb, const float* __restrict__ ckv,
    const float* __restrict__ fc, const float* __restrict__ fs,
    short* __restrict__ Qb, short* __restrict__ Kb, short* __restrict__ Vt,
    const float* __restrict__ lq1, const float* __restrict__ lk1,
    const float* __restrict__ lq2, const float* __restrict__ lk2,
    float* __restrict__ lamp) {
  __shared__ short Ts[128][74];
  const int bx = blockIdx.x;
  if (bx < 192) {
    const int t = (bx % 6) * 256 + threadIdx.x;
    const int h2 = bx / 6;
    const int hh = h2 >> 1, par = h2 & 1;
    const float* qrow = qf + (size_t)t*1536 + hh*96;
    const float* krow = kvb + (size_t)t*2048 + hh*128;
    unsigned qu[24], ku[24];
#pragma unroll
    for (int xq = 0; xq < 8; ++xq) {
      float4 qv = *reinterpret_cast<const float4*>(qrow + par*32 + (xq<<2));
      float4 kv = *reinterpret_cast<const float4*>(krow + par*32 + (xq<<2));
      qu[xq*2]   = pk2(qv.x*SCALING, qv.y*SCALING);
      qu[xq*2+1] = pk2(qv.z*SCALING, qv.w*SCALING);
      ku[xq*2]   = pk2(kv.x, kv.y); ku[xq*2+1] = pk2(kv.z, kv.w);
    }
    int p = t >> 2;
    const float* qr = qrow + 64 + par*16;
    const float* kr = ckv + (size_t)t*CKW + 256 + par*16;
#pragma unroll
    for (int mq = 0; mq < 8; ++mq) {
      float c = 1.f, sn = 0.f;
      if (p > 0) { c = fc[(p-1)*8 + mq]; sn = fs[(p-1)*8 + mq]; }
      float q0 = qr[2*mq], q1 = qr[2*mq+1];
      qu[16 + mq] = pk2((q0*c - q1*sn)*SCALING, (q0*sn + q1*c)*SCALING);
      float k0 = kr[2*mq], k1 = kr[2*mq+1];
      ku[16 + mq] = pk2(k0*c - k1*sn, k0*sn + k1*c);
    }
    unsigned* qo = (unsigned*)(Qb + ((size_t)h2*S + t)*DQK);
    unsigned* ko = (unsigned*)(Kb + ((size_t)h2*S + t)*DQK);
#pragma unroll
    for (int e = 0; e < 6; ++e) {
      *reinterpret_cast<uint4*>(qo + (e<<2)) = make_uint4(qu[e*4], qu[e*4+1], qu[e*4+2], qu[e*4+3]);
      *reinterpret_cast<uint4*>(ko + (e<<2)) = make_uint4(ku[e*4], ku[e*4+1], ku[e*4+2], ku[e*4+3]);
    }
  } else if (bx < 384) {
    const int f2 = bx - 192;
    const int hh = f2 % 16;
    const int t0 = (f2 / 16) << 7;
    const int tl = threadIdx.x >> 3, dp = (threadIdx.x & 7) << 3;
#pragma unroll
    for (int pass = 0; pass < 4; ++pass) {
      int t = t0 + (pass << 5) + tl;
      const float* vp = kvb + (size_t)t*2048 + hh*128 + 64 + dp;
      float4 a = *reinterpret_cast<const float4*>(vp);
      float4 b = *reinterpret_cast<const float4*>(vp + 4);
      *reinterpret_cast<bf16x8*>(&Ts[(pass << 5) + tl][dp]) = cvt8(a, b);
    }
    __syncthreads();
    for (int idx = threadIdx.x; idx < 1024; idx += 256) {
      int d = idx >> 4, tseg = (idx & 15) << 3;
      bf16x8 v;
#pragma unroll
      for (int e = 0; e < 8; ++e) v[e] = Ts[tseg + e][d];
      *reinterpret_cast<bf16x8*>(Vt + ((size_t)hh*HD + d)*S + t0 + tseg) = v;
    }
  } else if (threadIdx.x < 32) {
    int t = threadIdx.x;
    float a = lq1[t]*lk1[t];
    float b = lq2[t]*lk2[t];
#pragma unroll
    for (int mm = 1; mm < 32; mm <<= 1) { a += __shfl_xor(a, mm, 32); b += __shfl_xor(b, mm, 32); }
    if (t == 0) lamp[0] = expf(a) - expf(b) + 0.2f;
  }
}

// ------- MFMA flash attention: NO-LDS fragments direct from L2 ----------
// Q pre-scaled by SCALING; writes UNNORMALIZED partials + per-z (m,l).
__global__ __launch_bounds__(256) void flash_mfma(const short* __restrict__ Qb,
    const short* __restrict__ Kb, const short* __restrict__ Vg,
    float* __restrict__ Ob, float* __restrict__ rowm, float* __restrict__ rowl,
    float* __restrict__ Ob1a, float* __restrict__ Ob1b,
    float* __restrict__ rm1, float* __restrict__ rl1) {
  const int h2 = blockIdx.y;
  const int hh = h2 >> 1;
  const int z  = blockIdx.z;
  const int tid = threadIdx.x;
  const int w = tid >> 6, lane = tid & 63;
  const int ql = lane & 31, h = lane >> 5;
  const int cq = blockIdx.x / 3, k = blockIdx.x % 3;
  const int qi = k + 3*w;
  const int qbase = cq*SPP + (qi << 5);
  const int ri0w = qi << 5;

  __shared__ __align__(16) float Ot[4][32][36];

  bf16x8 qf0, qf1, qf2;
  {
    const short* qp = Qb + ((size_t)h2*S + qbase + ql)*DQK + (h << 3);
    qf0 = *reinterpret_cast<const bf16x8*>(qp);
    qf1 = *reinterpret_cast<const bf16x8*>(qp + 16);
    qf2 = *reinterpret_cast<const bf16x8*>(qp + 32);
  }
  const short* Kbase = Kb + (size_t)h2*S*DQK + (h << 3);
  const short* V0 = Vg + ((size_t)hh*HD + ql)*S + (h << 3);
  const short* V1 = Vg + ((size_t)hh*HD + 32 + ql)*S + (h << 3);

  float m = -1e30f, l = 0.f;
  f32x16 o0, o1;
#pragma unroll
  for (int r = 0; r < 16; ++r) { o0[r] = 0.f; o1[r] = 0.f; }

  for (int c = (z << 1); c < (z << 1) + 2; ++c) {
    for (int jr = 0; jr <= ri0w; jr += 32) {
      const int j0 = c*SPP + jr;
      const bool diag = (jr == ri0w);
      const short* kp = Kbase + (size_t)(j0 + ql)*DQK;
      bf16x8 kf0 = *reinterpret_cast<const bf16x8*>(kp);
      bf16x8 kf1 = *reinterpret_cast<const bf16x8*>(kp + 16);
      bf16x8 kf2 = *reinterpret_cast<const bf16x8*>(kp + 32);
      bf16x8 v00 = *reinterpret_cast<const bf16x8*>(V0 + j0);
      bf16x8 v01 = *reinterpret_cast<const bf16x8*>(V0 + j0 + 16);
      bf16x8 v10 = *reinterpret_cast<const bf16x8*>(V1 + j0);
      bf16x8 v11 = *reinterpret_cast<const bf16x8*>(V1 + j0 + 16);

      f32x16 st;
#pragma unroll
      for (int r = 0; r < 16; ++r) st[r] = 0.f;
      __builtin_amdgcn_s_setprio(1);
      st = __builtin_amdgcn_mfma_f32_32x32x16_bf16(kf0, qf0, st, 0, 0, 0);
      st = __builtin_amdgcn_mfma_f32_32x32x16_bf16(kf1, qf1, st, 0, 0, 0);
      st = __builtin_amdgcn_mfma_f32_32x32x16_bf16(kf2, qf2, st, 0, 0, 0);
      __builtin_amdgcn_s_setprio(0);

      if (diag) {
#pragma unroll
        for (int r = 0; r < 16; ++r) {
          int kl = (r & 3) + ((r >> 2) << 3) + (h << 2);
          if (kl > ql) st[r] = -1e30f;
        }
      }

      float tm = st[0];
#pragma unroll
      for (int r = 1; r < 16; ++r) tm = fmaxf(tm, st[r]);
      tm = fmaxf(tm, __shfl_xor(tm, 32));
      if (__any(tm > m + 8.0f)) {
        float mnew = fmaxf(m, tm);
        float sc = __expf(m - mnew);
        m = mnew;
        l *= sc;
#pragma unroll
        for (int r = 0; r < 16; ++r) { o0[r] *= sc; o1[r] *= sc; }
      }
      float ps = 0.f;
#pragma unroll
      for (int r = 0; r < 16; ++r) { float p = __expf(st[r] - m); st[r] = p; ps += p; }
      ps += __shfl_xor(ps, 32);
      l += ps;

      unsigned A0 = pk2(st[0],  st[1]),  B0 = pk2(st[2],  st[3]);
      unsigned C0 = pk2(st[4],  st[5]),  D0 = pk2(st[6],  st[7]);
      unsigned A1 = pk2(st[8],  st[9]),  B1 = pk2(st[10], st[11]);
      unsigned C1 = pk2(st[12], st[13]), D1 = pk2(st[14], st[15]);
      unsigned xA0 = (unsigned)__shfl_xor((int)A0, 32), xB0 = (unsigned)__shfl_xor((int)B0, 32);
      unsigned xC0 = (unsigned)__shfl_xor((int)C0, 32), xD0 = (unsigned)__shfl_xor((int)D0, 32);
      unsigned xA1 = (unsigned)__shfl_xor((int)A1, 32), xB1 = (unsigned)__shfl_xor((int)B1, 32);
      unsigned xC1 = (unsigned)__shfl_xor((int)C1, 32), xD1 = (unsigned)__shfl_xor((int)D1, 32);
      union { unsigned u[4]; bf16x8 v; } P0, P1;
      P0.u[0] = h ? xC0 : A0;  P0.u[1] = h ? xD0 : B0;
      P0.u[2] = h ? C0 : xA0;  P0.u[3] = h ? D0 : xB0;
      P1.u[0] = h ? xC1 : A1;  P1.u[1] = h ? xD1 : B1;
      P1.u[2] = h ? C1 : xA1;  P1.u[3] = h ? D1 : xB1;

      __builtin_amdgcn_s_setprio(1);
      o0 = __builtin_amdgcn_mfma_f32_32x32x16_bf16(v00, P0.v, o0, 0, 0, 0);
      o0 = __builtin_amdgcn_mfma_f32_32x32x16_bf16(v01, P1.v, o0, 0, 0, 0);
      o1 = __builtin_amdgcn_mfma_f32_32x32x16_bf16(v10, P0.v, o1, 0, 0, 0);
      o1 = __builtin_amdgcn_mfma_f32_32x32x16_bf16(v11, P1.v, o1, 0, 0, 0);
      __builtin_amdgcn_s_setprio(0);
    }
  }

  float* ot = &Ot[w][0][0];
  float* orow;
  if (z == 0) orow = Ob + ((size_t)h2*S + qbase)*HD;
  else orow = (h2 < 16) ? Ob1a + ((size_t)h2*S + qbase)*HD
                        : Ob1b + ((size_t)(h2 - 16)*S + qbase)*HD;
#pragma unroll
  for (int r = 0; r < 16; ++r) {
    int dl = (r & 3) + ((r >> 2) << 3) + (h << 2);
    ot[ql*36 + dl] = o0[r];
  }
#pragma unroll
  for (int it = 0; it < 4; ++it) {
    int idx = lane + (it << 6);
    int row = idx >> 3, c4 = (idx & 7) << 2;
    float4 v = *reinterpret_cast<float4*>(&ot[row*36 + c4]);
    *reinterpret_cast<float4*>(&orow[(size_t)row*HD + c4]) = v;
  }
#pragma unroll
  for (int r = 0; r < 16; ++r) {
    int dl = (r & 3) + ((r >> 2) << 3) + (h << 2);
    ot[ql*36 + dl] = o1[r];
  }
#pragma unroll
  for (int it = 0; it < 4; ++it) {
    int idx = lane + (it << 6);
    int row = idx >> 3, c4 = (idx & 7) << 2;
    float4 v = *reinterpret_cast<float4*>(&ot[row*36 + c4]);
    *reinterpret_cast<float4*>(&orow[(size_t)row*HD + 32 + c4]) = v;
  }
  if (lane < 32) {
    if (z == 0) { rowm[h2*S + qbase + lane] = m; rowl[h2*S + qbase + lane] = l; }
    else        { rm1[h2*S + qbase + lane] = m;  rl1[h2*S + qbase + lane] = l; }
  }
}

// ------ colsum via MFMA; merged (m,L) reconstructed inline from partials ----
__global__ __launch_bounds__(256) void colsum_mfma(const short* __restrict__ Qb,
    const short* __restrict__ Kb, const float* __restrict__ rowm,
    const float* __restrict__ rowl, const float* __restrict__ rm1,
    const float* __restrict__ rl1, float* __restrict__ gcol) {
  const int jt = blockIdx.x;
  const int hh = blockIdx.y, h2 = hh << 1;
  const int cK = jt / 12, jr32 = jt % 12;
  const int jr = jr32 << 5;
  const int j0 = cK*SPP + jr;
  const int tid = threadIdx.x;
  const int w = tid >> 6, lane = tid & 63;
  const int ql = lane & 31, h = lane >> 5;

  bf16x8 kf0, kf1, kf2;
  {
    const short* kp = Kb + ((size_t)h2*S + j0 + ql)*DQK + (h << 3);
    kf0 = *reinterpret_cast<const bf16x8*>(kp);
    kf1 = *reinterpret_cast<const bf16x8*>(kp + 16);
    kf2 = *reinterpret_cast<const bf16x8*>(kp + 32);
  }
  const int nt = 12 - jr32;
  const int T = nt << 2;
  float gs[16];
#pragma unroll
  for (int r = 0; r < 16; ++r) gs[r] = 0.f;

  for (int tt = w; tt < T; tt += 4) {
    int cq = tt / nt, qrem = tt - cq*nt;
    int qi = jr32 + qrem;
    int i0 = cq*SPP + (qi << 5);
    const bool diag = (qrem == 0);
    const short* qp = Qb + ((size_t)h2*S + i0 + ql)*DQK + (h << 3);
    bf16x8 qf0 = *reinterpret_cast<const bf16x8*>(qp);
    bf16x8 qf1 = *reinterpret_cast<const bf16x8*>(qp + 16);
    bf16x8 qf2 = *reinterpret_cast<const bf16x8*>(qp + 32);
    f32x16 st;
#pragma unroll
    for (int r = 0; r < 16; ++r) st[r] = 0.f;
    __builtin_amdgcn_s_setprio(1);
    st = __builtin_amdgcn_mfma_f32_32x32x16_bf16(kf0, qf0, st, 0, 0, 0);
    st = __builtin_amdgcn_mfma_f32_32x32x16_bf16(kf1, qf1, st, 0, 0, 0);
    st = __builtin_amdgcn_mfma_f32_32x32x16_bf16(kf2, qf2, st, 0, 0, 0);
    __builtin_amdgcn_s_setprio(0);
    // merged (m, L) inline from the two partials
    const int gidx = h2*S + i0 + ql;
    float m0 = rowm[gidx], l0 = rowl[gidx], m1 = rm1[gidx], l1 = rl1[gidx];
    float Mq = fmaxf(m0, m1);
    float Lm = l0*__expf(m0 - Mq) + l1*__expf(m1 - Mq);
    float Lq = 1.0f / Lm;
    if (diag) {
#pragma unroll
      for (int r = 0; r < 16; ++r) {
        int kl = (r & 3) + ((r >> 2) << 3) + (h << 2);
        if (kl <= ql) gs[r] += __expf(st[r] - Mq) * Lq;
      }
    } else {
#pragma unroll
      for (int r = 0; r < 16; ++r) gs[r] += __expf(st[r] - Mq) * Lq;
    }
  }
  __shared__ float gw[4][32];
#pragma unroll
  for (int r = 0; r < 16; ++r) {
    float v = gs[r];
#pragma unroll
    for (int mm = 1; mm < 32; mm <<= 1) v += __shfl_xor(v, mm, 32);
    if (ql == 0) gw[w][(r & 3) + ((r >> 2) << 3) + (h << 2)] = v;
  }
  __syncthreads();
  if (tid < 32) {
    float s = gw[0][tid] + gw[1][tid] + gw[2][tid] + gw[3][tid];
    gcol[hh*S + j0 + tid] = s * (1.0f / (float)S);
  }
}

// -- wpre_cvt: blocks 0..63 build_wpre; 64..4671 cvt(ffiw,ow) -> ffiw_bf -----
__global__ __launch_bounds__(256) void wpre_cvt(const float* __restrict__ gcol,
    const float* __restrict__ kvb, float* __restrict__ Wpre,
    const float* __restrict__ ffiw, const float* __restrict__ ow,
    short* __restrict__ ffiw_bf) {
  const int bx = blockIdx.x;
  if (bx >= 64) {
    long base = (long)(bx - 64) * 2048 + (long)threadIdx.x * 8;
    const float* src; long off;
    if (base < 8388608L) { src = ffiw; off = base; }
    else { src = ow; off = base - 8388608L; }
    float4 a = *reinterpret_cast<const float4*>(src + off);
    float4 b = *reinterpret_cast<const float4*>(src + off + 4);
    *reinterpret_cast<bf16x8*>(ffiw_bf + base) = cvt8(a, b);
    return;
  }
  const int hh = bx >> 2;
  const int dq = (bx & 3) << 4;
  __shared__ float Wt[SPP][16];
  const int tid = threadIdx.x;
  for (int idx = tid; idx < SPP*16; idx += 256) {
    int r = idx >> 4, dd = idx & 15;
    float val = 0.f;
#pragma unroll
    for (int b2 = 0; b2 < 4; ++b2) {
      int j = b2*SPP + r;
      val = fmaf(gcol[hh*S + j], kvb[(size_t)j*2048 + hh*128 + 64 + dq + dd], val);
    }
    Wt[r][dd] = val;
  }
  __syncthreads();
  if (tid < 16) {
    float run = 0.f;
    for (int r = 0; r < SPP; ++r) { run += Wt[r][tid]; Wt[r][tid] = run; }
  }
  __syncthreads();
  for (int idx = tid; idx < SPP*16; idx += 256) {
    int r = idx >> 4, dd = idx & 15;
    Wpre[((size_t)hh*SPP + r)*HD + dq + dd] = Wt[r][dd];
  }
}

// -- combine: merge O partials inline (from raw m,l) + diff-attn + RMSNorm ----
__global__ __launch_bounds__(256) void combine_rms(const float* __restrict__ Ob,
    const float* __restrict__ Ob1a, const float* __restrict__ Ob1b,
    const float* __restrict__ rowm, const float* __restrict__ rowl,
    const float* __restrict__ rm1, const float* __restrict__ rl1,
    const float* __restrict__ Wpre, const float* __restrict__ lamp,
    const float* __restrict__ anw, short* __restrict__ attno) {
  const int t = blockIdx.x * 4 + (threadIdx.x >> 6);
  const int h = blockIdx.y;
  const int d = threadIdx.x & 63;
  const float lam = lamp[0];
  const int g1 = (2*h)*S + t, g2 = (2*h+1)*S + t;
  const float* p1 = (h < 8) ? (Ob1a + (size_t)g1*HD) : (Ob1b + ((size_t)g1 - (size_t)16*S)*HD);
  const float* p2 = (h < 8) ? (Ob1a + (size_t)g2*HD) : (Ob1b + ((size_t)g2 - (size_t)16*S)*HD);
  float m10 = rowm[g1], l10 = rowl[g1], m11 = rm1[g1], l11 = rl1[g1];
  float M1 = fmaxf(m10, m11);
  float w10 = __expf(m10 - M1), w11 = __expf(m11 - M1);
  float li1 = 1.0f / (l10*w10 + l11*w11);
  float m20 = rowm[g2], l20 = rowl[g2], m21 = rm1[g2], l21 = rl1[g2];
  float M2 = fmaxf(m20, m21);
  float w20 = __expf(m20 - M2), w21 = __expf(m21 - M2);
  float li2 = 1.0f / (l20*w20 + l21*w21);
  float o1 = (Ob[(size_t)g1*HD + d] * w10 + p1[d] * w11) * li1;
  float o2 = (Ob[(size_t)g2*HD + d] * w20 + p2[d] * w21) * li2;
  const float w3 = Wpre[((size_t)h*SPP + (t % SPP))*HD + d];
  float val = o1 - lam*o2 + lam*w3;
  float ss = val*val;
#pragma unroll
  for (int mm = 1; mm < 64; mm <<= 1) ss += __shfl_xor(ss, mm, 64);
  float scale = rsqrtf(ss * (1.0f/HD) + ATTN_EPS) * anw[d];
  int tn = h*96 + (t >> 4);
  int cn = ((t & 15) << 6) + d;
  attno[(size_t)tn*DM + cn] = cvt_bf16(val * scale);
}

// =========================== launch ===========================
extern "C" void kernel_launch(void* const* d_in, const int* in_sizes, int n_in,
                              void* d_out, int out_size, void* d_ws, size_t ws_size,
                              hipStream_t stream) {
  (void)in_sizes; (void)n_in; (void)out_size;
  const float* x    = (const float*)d_in[0];
  const float* fc   = (const float*)d_in[1];
  const float* fs   = (const float*)d_in[2];
  const float* n1w  = (const float*)d_in[3];
  const float* n2w  = (const float*)d_in[4];
  const float* kvdw = (const float*)d_in[5];
  const float* qdw  = (const float*)d_in[6];
  const float* kvnw = (const float*)d_in[7];
  const float* qnw  = (const float*)d_in[8];
  const float* kvuw = (const float*)d_in[9];
  const float* quw  = (const float*)d_in[10];
  const float* lq1  = (const float*)d_in[11];
  const float* lk1  = (const float*)d_in[12];
  const float* lq2  = (const float*)d_in[13];
  const float* lk2  = (const float*)d_in[14];
  const float* anw  = (const float*)d_in[15];
  const float* ow   = (const float*)d_in[16];
  const float* ffiw = (const float*)d_in[17];
  const float* ffow = (const float*)d_in[18];
  float* out = (float*)d_out;
  float* ws  = (float*)d_ws;

  float* xin   = ws;
  float* ckv   = xin   + (size_t)S*DM;        // fused [S][672] down-proj output
  float* qmid  = ckv   + (size_t)S*288;
  float* kvb   = qmid  + (size_t)S*QC;
  float* qf    = kvb   + (size_t)S*2048;
  float* Qb    = qf    + (size_t)S*1536;
  float* Kb    = Qb    + (size_t)H2N*S*DQK;
  float* Obuf  = Kb    + (size_t)H2N*S*DQK;
  float* rowm  = Obuf  + (size_t)H2N*S*HD;
  float* rowl  = rowm  + (size_t)H2N*S;
  float* gcol  = rowl  + (size_t)H2N*S;
  float* Wpre  = gcol  + (size_t)NH*S;
  float* attno = Wpre  + (size_t)NH*SPP*HD;
  float* lamp  = attno + (size_t)S*DM;
  short* fbufs = (short*)kvb;     // bf16 FFN activation overlays kv region
  float* Ob1a = xin;
  float* Ob1b = qf;
  float* rm1  = qf + (size_t)16*S*HD;
  float* rl1  = rm1 + (size_t)H2N*S;
  short* Qb_bf = (short*)Qb;
  short* Kb_bf = (short*)Kb;
  short* Vt_bf = (short*)Qb + 2359296;
  short* xin_bf  = (short*)xin;
  short* ckv_bf  = (short*)Obuf;
  short* qmid_bf = ckv_bf + (size_t)S*KVC;
  short* h_bf    = (short*)ckv;   // rmsnorm2 out: fused-buffer region (dead by then)
  short* attno_bf = (short*)attno;
  short* kvdw_bf = (short*)attno;
  short* qdw_bf  = kvdw_bf + 294912;        // contiguous: fused B (672x1024)
  short* kvuw_bf = qdw_bf  + 393216;
  short* quw_bf  = kvuw_bf + 524288;
  short* ffiw_bf = (short*)Qb;
  short* ow_bf   = ffiw_bf + 8388608;
  short* ffow_bf = (short*)Obuf;
  float* psum0 = xin;             // split-K partials: dead windows at call sites
  float* psum1 = qf;
  if (ws_size < (size_t)18063376 * sizeof(float)) return;

  rms1_cvt<<<S + 880, 256, 0, stream>>>(x, n1w, xin_bf,
      kvdw, 294912, qdw, 393216, kvuw, 524288, quw, kvdw_bf);
  { dim3 g(11, 24); mgemm_nt<0><<<g, 256, 0, stream>>>(xin_bf, kvdw_bf, nullptr, ckv, S, CKW, DM, DM, DM, CKW); }
  { dim3 g(S, 2);   rmsnorm2_bf<<<g, 256, 0, stream>>>(ckv, kvnw, qnw, ckv_bf, qmid_bf, EPS_RMS); }
  mgemm_dual<<<1344, 256, 0, stream>>>(ckv_bf, kvuw_bf, kvb, qmid_bf, quw_bf, qf);
  prep_attn<<<385, 256, 0, stream>>>(qf, kvb, ckv, fc, fs, Qb_bf, Kb_bf, Vt_bf,
                                     lq1, lk1, lq2, lk2, lamp);
  { dim3 g(12, 32, 2); flash_mfma<<<g, 256, 0, stream>>>(Qb_bf, Kb_bf, Vt_bf, Obuf, rowm, rowl,
                                                         Ob1a, Ob1b, rm1, rl1); }
  { dim3 g(48, 16); colsum_mfma<<<g, 256, 0, stream>>>(Qb_bf, Kb_bf, rowm, rowl, rm1, rl1, gcol); }
  wpre_cvt<<<64 + 4608, 256, 0, stream>>>(gcol, kvb, Wpre, ffiw, ow, ffiw_bf);
  { dim3 g(S/4, 16); combine_rms<<<g, 256, 0, stream>>>(Obuf, Ob1a, Ob1b, rowm, rowl, rm1, rl1,
                                                        Wpre, lamp, anw, attno_bf); }
  oproj_cvt<<<768 + 2048, 256, 0, stream>>>(attno_bf, ow_bf, psum0, psum1, ffow, ffow_bf);
  rmsnorm_sum_bf<<<S, 256, 0, stream>>>(psum0, psum1, x, n2w, out, h_bf, EPS_RMS);
  { dim3 g(64, 12); mgemm_glu<<<g, 256, 0, stream>>>(h_bf, ffiw_bf, fbufs, S, DFF, DM, DM, DM, DFF); }
  { dim3 g(16, 24, 2); mgemm_sk<<<g, 256, 0, stream>>>(fbufs, ffow_bf, psum0, psum1, S, DM, 2048, DFF, DFF, DM); }
  fadd2<<<1536, 256, 0, stream>>>(out, psum0, psum1);
}